// Round 1
// baseline (18297.101 us; speedup 1.0000x reference)
//
#include <hip/hip_runtime.h>

// DescrptDPA1: NF=1, NLOC=4096, NNEI=120, TEBD=8, NTYPES=4, M=100, ATTN=128,
// NLAYER=2, AXIS=16. One block per atom, 256 threads (4 waves).

#define NNEI 120
#define MDIM 100
#define ADIM 128
#define AXISD 16
#define GS   101   // f32 stride for g (coprime-ish with 32 banks)
#define KS   130   // ushort stride for k/v (even -> word stride 65, conflict-free)
#define CH   10    // rows per chunk in the per-wave row loop
#define OUTD 1608  // 100*16 + 8

__device__ __forceinline__ float bf2f(unsigned short u){
    return __uint_as_float(((unsigned int)u) << 16);
}
__device__ __forceinline__ unsigned short f2bf(float f){
    unsigned int x = __float_as_uint(f);
    return (unsigned short)((x + 0x7fffu + ((x >> 16) & 1u)) >> 16);
}
__device__ __forceinline__ float ftanh(float x){
    // tanh(x) = 1 - 2/(exp(2x)+1); saturates correctly for |x| large
    return 1.0f - 2.0f / (__expf(2.0f * x) + 1.0f);
}

// nmask storage detection: 1 = int32 {0,1}, 2 = f32 {0.0,1.0}, 0 = byte bool
__global__ void detect_mask_kernel(const unsigned char* __restrict__ p,
                                   int* __restrict__ flag){
    if (blockIdx.x == 0 && threadIdx.x == 0){
        const unsigned int* u = (const unsigned int*)p;
        int alli = 1, allf = 1;
        for (int i = 0; i < 64; ++i){
            unsigned int w = u[i];
            if (!(w == 0u || w == 1u)) alli = 0;
            if (!(w == 0u || w == 0x3f800000u)) allf = 0;
        }
        flag[0] = alli ? 1 : (allf ? 2 : 0);
    }
}

__global__ __launch_bounds__(256, 1) void dpa1_kernel(
    const float* __restrict__ rij, const void* __restrict__ nmask,
    const int* __restrict__ atype, const int* __restrict__ ntype,
    const float* __restrict__ tebd,
    const float* __restrict__ ew0, const float* __restrict__ eb0,
    const float* __restrict__ ew1, const float* __restrict__ eb1,
    const float* __restrict__ ew2, const float* __restrict__ eb2,
    const float* __restrict__ wq, const float* __restrict__ bq,
    const float* __restrict__ wk, const float* __restrict__ bk,
    const float* __restrict__ wv, const float* __restrict__ bv,
    const float* __restrict__ wo, const float* __restrict__ bo,
    const float* __restrict__ lng, const float* __restrict__ lnb,
    float* __restrict__ out, const int* __restrict__ flagp)
{
    __shared__ float g_s[NNEI * GS];                       // 48,480 B
    __shared__ __align__(16) unsigned short k_s[NNEI * KS]; // 31,200 B (bf16)
    __shared__ __align__(16) unsigned short v_s[NNEI * KS]; // 31,200 B (bf16)
    __shared__ float env_s[NNEI * 4];
    __shared__ float rhat_s[NNEI * 4];
    __shared__ float swm_s[NNEI];
    __shared__ float msk_s[NNEI];
    __shared__ __align__(16) float qbuf[4][CH][ADIM];      // q then o rows, 20,480 B
    __shared__ __align__(16) float pbuf[4][ADIM];          // attn weights staging
    __shared__ float gr_s[4 * MDIM];
    __shared__ float tebd_s[32];

    const int n    = blockIdx.x;
    const int tid  = threadIdx.x;
    const int lane = tid & 63;
    const int wid  = tid >> 6;
    const int flag = flagp[0];

    if (tid < 32) tebd_s[tid] = tebd[tid];
    __syncthreads();

    // ---------------- Phase 0: geometry + embedding MLP (thread = neighbor) ----
    if (tid < NNEI){
        const int k = tid;
        const int base = n * NNEI + k;
        const float rx = rij[base * 3 + 0];
        const float ry = rij[base * 3 + 1];
        const float rz = rij[base * 3 + 2];
        const float r  = sqrtf(rx * rx + ry * ry + rz * rz);
        float mval;
        if (flag == 1)      mval = (((const int*)nmask)[base] != 0) ? 1.0f : 0.0f;
        else if (flag == 2) mval = ((const float*)nmask)[base];
        else                mval = (((const unsigned char*)nmask)[base] != 0) ? 1.0f : 0.0f;
        float uu = (r - 0.5f) * (1.0f / 5.5f);
        uu = fminf(fmaxf(uu, 0.0f), 1.0f);
        const float sw   = uu * uu * uu * (-6.0f * uu * uu + 15.0f * uu - 10.0f) + 1.0f;
        const float invr = 1.0f / r;
        const float sr   = sw * invr * mval;
        const float hx = rx * invr, hy = ry * invr, hz = rz * invr;
        env_s[k * 4 + 0] = sr;
        env_s[k * 4 + 1] = sr * hx;
        env_s[k * 4 + 2] = sr * hy;
        env_s[k * 4 + 3] = sr * hz;
        rhat_s[k * 4 + 0] = hx; rhat_s[k * 4 + 1] = hy; rhat_s[k * 4 + 2] = hz;
        rhat_s[k * 4 + 3] = 0.0f;
        swm_s[k] = sw * mval;
        msk_s[k] = mval;

        // x = [sr, tebd[ntype], tebd[atype]]  (17)
        float x[17];
        x[0] = sr;
        const int tn = ntype[base] * 8;
        const int ta = atype[n] * 8;
        #pragma unroll
        for (int i = 0; i < 8; ++i){ x[1 + i] = tebd_s[tn + i]; x[9 + i] = tebd_s[ta + i]; }

        float h1[25];
        #pragma unroll
        for (int j = 0; j < 25; ++j){
            float a = eb0[j];
            #pragma unroll
            for (int i = 0; i < 17; ++i) a = fmaf(x[i], ew0[i * 25 + j], a);
            h1[j] = ftanh(a);
        }
        float h2[50];
        #pragma unroll
        for (int j = 0; j < 50; ++j){
            float a = eb1[j];
            #pragma unroll
            for (int i = 0; i < 25; ++i) a = fmaf(h1[i], ew1[i * 50 + j], a);
            h2[j] = ftanh(a) + h1[j % 25];
        }
        #pragma unroll
        for (int j = 0; j < 100; ++j){
            float a = eb2[j];
            #pragma unroll
            for (int i = 0; i < 50; ++i) a = fmaf(h2[i], ew2[i * 100 + j], a);
            g_s[k * GS + j] = (ftanh(a) + h2[j % 50]) * mval;
        }
    }
    __syncthreads();

    // ---------------- Attention layers ----------------
    for (int l = 0; l < 2; ++l){
        // ---- K and V matmuls -> bf16 LDS (raw, pre-norm) ----
        {
            const float* Wm0 = wk + l * MDIM * ADIM;
            const float* Wm1 = wv + l * MDIM * ADIM;
            const float* Bm0 = bk + l * ADIM;
            const float* Bm1 = bv + l * ADIM;
            const int r0a = lane, r0b = lane + 64;
            const bool hb = (r0b < NNEI);
            for (int mat = 0; mat < 2; ++mat){
                const float* Wm = mat ? Wm1 : Wm0;
                const float* Bm = mat ? Bm1 : Bm0;
                unsigned short* dst = mat ? v_s : k_s;
                for (int cc = 0; cc < 4; ++cc){
                    const int c0 = wid * 32 + cc * 8;
                    float a0[8], a1[8];
                    #pragma unroll
                    for (int c = 0; c < 8; ++c){ float b = Bm[c0 + c]; a0[c] = b; a1[c] = b; }
                    for (int i = 0; i < MDIM; ++i){
                        const float g0 = g_s[r0a * GS + i];
                        const float g1 = hb ? g_s[r0b * GS + i] : 0.0f;
                        #pragma unroll
                        for (int c = 0; c < 8; ++c){
                            const float w = Wm[i * ADIM + c0 + c];
                            a0[c] = fmaf(g0, w, a0[c]);
                            a1[c] = fmaf(g1, w, a1[c]);
                        }
                    }
                    #pragma unroll
                    for (int c = 0; c < 8; ++c){
                        dst[r0a * KS + c0 + c] = f2bf(a0[c]);
                        if (hb) dst[r0b * KS + c0 + c] = f2bf(a1[c]);
                    }
                }
            }
        }
        __syncthreads();

        // ---- l2norm K rows, V rows in place ----
        {
            int task = tid;
            if (task < 240){
                unsigned short* buf = (task < NNEI) ? k_s : v_s;
                const int row = (task < NNEI) ? task : task - NNEI;
                float ss = 0.0f;
                for (int d = 0; d < ADIM; ++d){
                    const float x = bf2f(buf[row * KS + d]);
                    ss = fmaf(x, x, ss);
                }
                const float inv = 1.0f / fmaxf(sqrtf(ss), 1e-12f);
                for (int d = 0; d < ADIM; ++d)
                    buf[row * KS + d] = f2bf(bf2f(buf[row * KS + d]) * inv);
            }
        }
        __syncthreads();

        // ---- per-wave fused rows: q -> scores -> softmax -> PV -> @wo -> LN -> g += ----
        const float* WQ = wq + l * MDIM * ADIM;
        const float* BQ = bq + l * ADIM;
        const float* WO = wo + l * ADIM * MDIM;
        const float* BO = bo + l * MDIM;
        const float* LG = lng + l * MDIM;
        const float* LB = lnb + l * MDIM;
        const int j0 = lane, j1 = lane + 64;
        const bool hasj1 = (j1 < MDIM);

        for (int chunk = 0; chunk < 3; ++chunk){
            const int r0 = wid * 30 + chunk * CH;

            // q rows r0..r0+CH-1 ; lane owns dims 2*lane, 2*lane+1
            float qa[CH], qb[CH];
            {
                const float bq0 = BQ[2 * lane], bq1 = BQ[2 * lane + 1];
                #pragma unroll
                for (int r = 0; r < CH; ++r){ qa[r] = bq0; qb[r] = bq1; }
                for (int i = 0; i < MDIM; ++i){
                    const float2 w2 = *(const float2*)&WQ[i * ADIM + 2 * lane];
                    #pragma unroll
                    for (int r = 0; r < CH; ++r){
                        const float gv = g_s[(r0 + r) * GS + i];
                        qa[r] = fmaf(gv, w2.x, qa[r]);
                        qb[r] = fmaf(gv, w2.y, qb[r]);
                    }
                }
                #pragma unroll
                for (int r = 0; r < CH; ++r){
                    float ss = qa[r] * qa[r] + qb[r] * qb[r];
                    #pragma unroll
                    for (int off = 32; off; off >>= 1) ss += __shfl_xor(ss, off, 64);
                    const float inv = 1.0f / fmaxf(sqrtf(ss), 1e-12f);
                    qa[r] *= inv; qb[r] *= inv;
                    *(float2*)&qbuf[wid][r][2 * lane] = make_float2(qa[r], qb[r]);
                }
            }
            __threadfence_block();

            for (int r = 0; r < CH; ++r){
                const int row = r0 + r;
                const float mrow = msk_s[row];
                const float swr  = swm_s[row];
                const float rx = rhat_s[row * 4 + 0];
                const float ry = rhat_s[row * 4 + 1];
                const float rz = rhat_s[row * 4 + 2];
                const int k1 = lane;
                const int k2 = lane + 64;
                const int k2r = (k2 < NNEI) ? k2 : 0;
                float s0 = 0.0f, s1 = 0.0f;
                for (int dd = 0; dd < 64; ++dd){
                    const float2 q2 = *(const float2*)&qbuf[wid][r][2 * dd];
                    const unsigned int kw1 = *(const unsigned int*)&k_s[k1 * KS + 2 * dd];
                    const unsigned int kw2 = *(const unsigned int*)&k_s[k2r * KS + 2 * dd];
                    s0 = fmaf(q2.x, bf2f((unsigned short)kw1), s0);
                    s0 = fmaf(q2.y, bf2f((unsigned short)(kw1 >> 16)), s0);
                    s1 = fmaf(q2.x, bf2f((unsigned short)kw2), s1);
                    s1 = fmaf(q2.y, bf2f((unsigned short)(kw2 >> 16)), s1);
                }
                const float tinv = 0.08838834764831845f;  // 1/sqrt(128)
                s0 *= tinv; s1 *= tinv;
                const bool vld1 = (mrow != 0.0f) && (msk_s[k1] != 0.0f);
                const bool vld2 = (k2 < NNEI) && (mrow != 0.0f) && (msk_s[k2r] != 0.0f);
                const float NEG = -3.402823466e38f;
                const float sc0 = vld1 ? s0 : NEG;
                const float sc1 = vld2 ? s1 : NEG;
                float mx = fmaxf(sc0, sc1);
                #pragma unroll
                for (int off = 32; off; off >>= 1) mx = fmaxf(mx, __shfl_xor(mx, off, 64));
                const float e0 = __expf(sc0 - mx);
                const float e1 = __expf(sc1 - mx);
                float sum = e0 + e1;
                #pragma unroll
                for (int off = 32; off; off >>= 1) sum += __shfl_xor(sum, off, 64);
                const float rs = 1.0f / sum;
                const float gat1 = rx * rhat_s[k1 * 4 + 0] + ry * rhat_s[k1 * 4 + 1] + rz * rhat_s[k1 * 4 + 2];
                const float gat2 = rx * rhat_s[k2r * 4 + 0] + ry * rhat_s[k2r * 4 + 1] + rz * rhat_s[k2r * 4 + 2];
                const float p0 = vld1 ? (e0 * rs * swr * swm_s[k1]  * gat1) : 0.0f;
                const float p1 = vld2 ? (e1 * rs * swr * swm_s[k2r] * gat2) : 0.0f;
                pbuf[wid][k1] = p0;
                pbuf[wid][k2] = p1;
                __threadfence_block();
                // o row: lane owns dims 2*lane, 2*lane+1
                float o0 = 0.0f, o1 = 0.0f;
                for (int k = 0; k < NNEI; k += 4){
                    const float4 p4 = *(const float4*)&pbuf[wid][k];
                    unsigned int vw;
                    vw = *(const unsigned int*)&v_s[(k + 0) * KS + 2 * lane];
                    o0 = fmaf(p4.x, bf2f((unsigned short)vw), o0);
                    o1 = fmaf(p4.x, bf2f((unsigned short)(vw >> 16)), o1);
                    vw = *(const unsigned int*)&v_s[(k + 1) * KS + 2 * lane];
                    o0 = fmaf(p4.y, bf2f((unsigned short)vw), o0);
                    o1 = fmaf(p4.y, bf2f((unsigned short)(vw >> 16)), o1);
                    vw = *(const unsigned int*)&v_s[(k + 2) * KS + 2 * lane];
                    o0 = fmaf(p4.z, bf2f((unsigned short)vw), o0);
                    o1 = fmaf(p4.z, bf2f((unsigned short)(vw >> 16)), o1);
                    vw = *(const unsigned int*)&v_s[(k + 3) * KS + 2 * lane];
                    o0 = fmaf(p4.w, bf2f((unsigned short)vw), o0);
                    o1 = fmaf(p4.w, bf2f((unsigned short)(vw >> 16)), o1);
                }
                *(float2*)&qbuf[wid][r][2 * lane] = make_float2(o0, o1);  // overwrite q with o
            }
            __threadfence_block();

            // o2 = O @ WO + BO ; LayerNorm ; residual into g
            float oa[CH], ob[CH];
            {
                const float bo0 = BO[j0];
                const float bo1 = hasj1 ? BO[j1] : 0.0f;
                #pragma unroll
                for (int r = 0; r < CH; ++r){ oa[r] = bo0; ob[r] = bo1; }
                for (int d = 0; d < ADIM; ++d){
                    const float w0 = WO[d * MDIM + j0];
                    const float w1 = hasj1 ? WO[d * MDIM + j1] : 0.0f;
                    #pragma unroll
                    for (int r = 0; r < CH; ++r){
                        const float od = qbuf[wid][r][d];
                        oa[r] = fmaf(od, w0, oa[r]);
                        ob[r] = fmaf(od, w1, ob[r]);
                    }
                }
            }
            #pragma unroll
            for (int r = 0; r < CH; ++r){
                const int row = r0 + r;
                const float va = oa[r];
                const float vb = hasj1 ? ob[r] : 0.0f;
                float s  = va + vb;
                float s2 = va * va + vb * vb;
                #pragma unroll
                for (int off = 32; off; off >>= 1){
                    s  += __shfl_xor(s,  off, 64);
                    s2 += __shfl_xor(s2, off, 64);
                }
                const float mu   = s * 0.01f;
                const float var  = s2 * 0.01f - mu * mu;
                const float rstd = rsqrtf(var + 1e-5f);
                g_s[row * GS + j0] += (va - mu) * rstd * LG[j0] + LB[j0];
                if (hasj1) g_s[row * GS + j1] += (ob[r] - mu) * rstd * LG[j1] + LB[j1];
            }
        }
        __syncthreads();
    }

    // ---------------- Final: gr = env^T g / NNEI ; d = gr^T gr[:, :16] ----------
    for (int idx = tid; idx < 4 * MDIM; idx += 256){
        const int c = idx / MDIM, mm = idx - c * MDIM;
        float a = 0.0f;
        for (int k = 0; k < NNEI; ++k)
            a = fmaf(env_s[k * 4 + c], g_s[k * GS + mm], a);
        gr_s[c * MDIM + mm] = a * (1.0f / 120.0f);
    }
    __syncthreads();

    float* outp = out + (size_t)n * OUTD;
    for (int idx = tid; idx < MDIM * AXISD; idx += 256){
        const int mm = idx >> 4, aa = idx & 15;
        float acc = 0.0f;
        #pragma unroll
        for (int c = 0; c < 4; ++c)
            acc = fmaf(gr_s[c * MDIM + mm], gr_s[c * MDIM + aa], acc);
        outp[idx] = acc;
    }
    if (tid < 8) outp[1600 + tid] = tebd_s[atype[n] * 8 + tid];
}

extern "C" void kernel_launch(void* const* d_in, const int* in_sizes, int n_in,
                              void* d_out, int out_size, void* d_ws, size_t ws_size,
                              hipStream_t stream) {
    const float* rij   = (const float*)d_in[0];
    const void*  nmask = d_in[1];
    const int*   atype = (const int*)d_in[2];
    const int*   ntype = (const int*)d_in[3];
    const float* tebd  = (const float*)d_in[4];
    const float* ew0 = (const float*)d_in[5];
    const float* eb0 = (const float*)d_in[6];
    const float* ew1 = (const float*)d_in[7];
    const float* eb1 = (const float*)d_in[8];
    const float* ew2 = (const float*)d_in[9];
    const float* eb2 = (const float*)d_in[10];
    const float* wq = (const float*)d_in[11];
    const float* bq = (const float*)d_in[12];
    const float* wk = (const float*)d_in[13];
    const float* bk = (const float*)d_in[14];
    const float* wv = (const float*)d_in[15];
    const float* bv = (const float*)d_in[16];
    const float* wo = (const float*)d_in[17];
    const float* bo = (const float*)d_in[18];
    const float* lng = (const float*)d_in[19];
    const float* lnb = (const float*)d_in[20];
    float* out = (float*)d_out;
    int* flag = (int*)d_ws;

    detect_mask_kernel<<<1, 64, 0, stream>>>((const unsigned char*)nmask, flag);
    dpa1_kernel<<<4096, 256, 0, stream>>>(rij, nmask, atype, ntype, tebd,
                                          ew0, eb0, ew1, eb1, ew2, eb2,
                                          wq, bq, wk, bk, wv, bv, wo, bo,
                                          lng, lnb, out, flag);
}

// Round 2
// 4319.114 us; speedup vs baseline: 4.2363x; 4.2363x over previous
//
#include <hip/hip_runtime.h>

// DescrptDPA1: NF=1, NLOC=4096, NNEI=120, TEBD=8, NTYPES=4, M=100, ATTN=128,
// NLAYER=2, AXIS=16. One block per atom, 768 threads (12 waves, 10 rows/wave).
// LDS-resident per-atom state; 155 KB LDS -> 1 block/CU, 3 waves/SIMD.

#define NNEI 120
#define MDIM 100
#define ADIM 128
#define AXISD 16
#define GS   102   // f32 stride for g (even -> aligned float2 reads)
#define KS   130   // f16 stride for k/v (word stride 65 -> conflict-free)
#define NW   12    // waves per block
#define RPW  10    // attention rows per wave
#define OUTD 1608  // 100*16 + 8

typedef _Float16 h2_t __attribute__((ext_vector_type(2)));
union UH2 { unsigned int u; h2_t h; };

__device__ __forceinline__ unsigned int packh2(float a, float b){
    UH2 x; x.h[0] = (_Float16)a; x.h[1] = (_Float16)b; return x.u;
}
__device__ __forceinline__ float ftanh(float x){
    // tanh(x) = 1 - 2/(exp(2x)+1); saturates correctly for |x| large
    return 1.0f - 2.0f / (__expf(2.0f * x) + 1.0f);
}

// nmask storage detection: 1 = int32 {0,1}, 2 = f32 {0.0,1.0}, 0 = byte bool
__global__ void detect_mask_kernel(const unsigned char* __restrict__ p,
                                   int* __restrict__ flag){
    if (blockIdx.x == 0 && threadIdx.x == 0){
        const unsigned int* u = (const unsigned int*)p;
        int alli = 1, allf = 1;
        for (int i = 0; i < 64; ++i){
            unsigned int w = u[i];
            if (!(w == 0u || w == 1u)) alli = 0;
            if (!(w == 0u || w == 0x3f800000u)) allf = 0;
        }
        flag[0] = alli ? 1 : (allf ? 2 : 0);
    }
}

__global__ __launch_bounds__(768, 3) void dpa1_kernel(
    const float* __restrict__ rij, const void* __restrict__ nmask,
    const int* __restrict__ atype, const int* __restrict__ ntype,
    const float* __restrict__ tebd,
    const float* __restrict__ ew0, const float* __restrict__ eb0,
    const float* __restrict__ ew1, const float* __restrict__ eb1,
    const float* __restrict__ ew2, const float* __restrict__ eb2,
    const float* __restrict__ wq, const float* __restrict__ bq,
    const float* __restrict__ wk, const float* __restrict__ bk,
    const float* __restrict__ wv, const float* __restrict__ bv,
    const float* __restrict__ wo, const float* __restrict__ bo,
    const float* __restrict__ lng, const float* __restrict__ lnb,
    float* __restrict__ out, const int* __restrict__ flagp)
{
    __shared__ __align__(16) float g_s[NNEI * GS];            // 48,960 B
    __shared__ __align__(16) unsigned short k_s[NNEI * KS];   // 31,200 B (f16)
    __shared__ __align__(16) unsigned short v_s[NNEI * KS];   // 31,200 B (f16)
    __shared__ float env_s[NNEI * 4];
    __shared__ float rhat_s[NNEI * 4];
    __shared__ float swm_s[NNEI];
    __shared__ float msk_s[NNEI];
    __shared__ int   ntype_s[NNEI];
    __shared__ __align__(16) unsigned short qo_s[NW][RPW][ADIM]; // 30,720 B (f16)
    __shared__ __align__(16) float pbuf[NW][ADIM];               // 6,144 B
    __shared__ float gr_s[4 * MDIM];
    __shared__ float tebd_s[32];
    __shared__ int ta_sh;

    const int n    = blockIdx.x;
    const int tid  = threadIdx.x;
    const int lane = tid & 63;
    const int wid  = tid >> 6;
    const int flag = flagp[0];

    if (tid < 32) tebd_s[tid] = tebd[tid];
    if (tid == 0) ta_sh = atype[n];

    // ---------------- Phase 0a: geometry (thread = neighbor) -------------------
    if (tid < NNEI){
        const int k = tid;
        const int base = n * NNEI + k;
        const float rx = rij[base * 3 + 0];
        const float ry = rij[base * 3 + 1];
        const float rz = rij[base * 3 + 2];
        const float r  = sqrtf(rx * rx + ry * ry + rz * rz);
        float mval;
        if (flag == 1)      mval = (((const int*)nmask)[base] != 0) ? 1.0f : 0.0f;
        else if (flag == 2) mval = ((const float*)nmask)[base];
        else                mval = (((const unsigned char*)nmask)[base] != 0) ? 1.0f : 0.0f;
        float uu = (r - 0.5f) * (1.0f / 5.5f);
        uu = fminf(fmaxf(uu, 0.0f), 1.0f);
        const float sw   = uu * uu * uu * (-6.0f * uu * uu + 15.0f * uu - 10.0f) + 1.0f;
        const float invr = 1.0f / r;
        const float sr   = sw * invr * mval;
        const float hx = rx * invr, hy = ry * invr, hz = rz * invr;
        env_s[k * 4 + 0] = sr;
        env_s[k * 4 + 1] = sr * hx;
        env_s[k * 4 + 2] = sr * hy;
        env_s[k * 4 + 3] = sr * hz;
        rhat_s[k * 4 + 0] = hx; rhat_s[k * 4 + 1] = hy; rhat_s[k * 4 + 2] = hz;
        rhat_s[k * 4 + 3] = 0.0f;
        swm_s[k] = sw * mval;
        msk_s[k] = mval;
        ntype_s[k] = ntype[base];
    }
    __syncthreads();

    // ---------------- Phase 0b: embedding MLP, output-parallel ----------------
    // h1 [120][25] staged in k_s, h2 [120][50] staged in v_s (both free now).
    {
        float* h1buf = (float*)k_s;
        float* h2buf = (float*)v_s;
        const int ta = ta_sh;

        for (int idx = tid; idx < NNEI * 25; idx += 768){
            const int k = idx / 25, j = idx - k * 25;
            const float sr = env_s[k * 4];
            const float* tn = &tebd_s[ntype_s[k] * 8];
            const float* tc = &tebd_s[ta * 8];
            float a = eb0[j] + sr * ew0[j];
            #pragma unroll
            for (int i = 0; i < 8; ++i){
                a = fmaf(tn[i], ew0[(1 + i) * 25 + j], a);
                a = fmaf(tc[i], ew0[(9 + i) * 25 + j], a);
            }
            h1buf[k * 25 + j] = ftanh(a);
        }
        __syncthreads();

        for (int idx = tid; idx < NNEI * 50; idx += 768){
            const int k = idx / 50, j = idx - k * 50;
            float a = eb1[j];
            const float* h1r = &h1buf[k * 25];
            #pragma unroll
            for (int i = 0; i < 25; ++i) a = fmaf(h1r[i], ew1[i * 50 + j], a);
            h2buf[k * 50 + j] = ftanh(a) + h1r[j >= 25 ? j - 25 : j];
        }
        __syncthreads();

        for (int idx = tid; idx < NNEI * MDIM; idx += 768){
            const int k = idx / MDIM, j = idx - k * MDIM;
            float a = eb2[j];
            const float* h2r = &h2buf[k * 50];
            #pragma unroll
            for (int i = 0; i < 50; ++i) a = fmaf(h2r[i], ew2[i * MDIM + j], a);
            g_s[k * GS + j] = (ftanh(a) + h2r[j >= 50 ? j - 50 : j]) * msk_s[k];
        }
        __syncthreads();
    }

    // ---------------- Attention layers ----------------
    const int r0 = wid * RPW;
    const int c0 = 2 * lane;
    const int j0 = lane, j1 = lane + 64;
    const bool hasj1 = (j1 < MDIM);

    for (int l = 0; l < 2; ++l){
        const float* WQ = wq + l * MDIM * ADIM;  const float* BQ = bq + l * ADIM;
        const float* WK = wk + l * MDIM * ADIM;  const float* BK = bk + l * ADIM;
        const float* WV = wv + l * MDIM * ADIM;  const float* BV = bv + l * ADIM;
        const float* WO = wo + l * ADIM * MDIM;  const float* BO = bo + l * MDIM;
        const float* LG = lng + l * MDIM;        const float* LB = lnb + l * MDIM;

        // ---- fused Q/K/V matmul for this wave's 10 rows; lane owns cols c0,c0+1
        {
            float kk0[RPW], kk1[RPW], vv0[RPW], vv1[RPW], qq0[RPW], qq1[RPW];
            const float bk0 = BK[c0], bk1 = BK[c0 + 1];
            const float bv0 = BV[c0], bv1 = BV[c0 + 1];
            const float bq0 = BQ[c0], bq1 = BQ[c0 + 1];
            #pragma unroll
            for (int r = 0; r < RPW; ++r){
                kk0[r] = bk0; kk1[r] = bk1; vv0[r] = bv0; vv1[r] = bv1;
                qq0[r] = bq0; qq1[r] = bq1;
            }
            for (int i = 0; i < MDIM; i += 2){
                const float2 wkA = *(const float2*)&WK[i * ADIM + c0];
                const float2 wkB = *(const float2*)&WK[(i + 1) * ADIM + c0];
                const float2 wvA = *(const float2*)&WV[i * ADIM + c0];
                const float2 wvB = *(const float2*)&WV[(i + 1) * ADIM + c0];
                const float2 wqA = *(const float2*)&WQ[i * ADIM + c0];
                const float2 wqB = *(const float2*)&WQ[(i + 1) * ADIM + c0];
                #pragma unroll
                for (int r = 0; r < RPW; ++r){
                    const float2 g2 = *(const float2*)&g_s[(r0 + r) * GS + i];
                    kk0[r] = fmaf(g2.x, wkA.x, kk0[r]); kk1[r] = fmaf(g2.x, wkA.y, kk1[r]);
                    vv0[r] = fmaf(g2.x, wvA.x, vv0[r]); vv1[r] = fmaf(g2.x, wvA.y, vv1[r]);
                    qq0[r] = fmaf(g2.x, wqA.x, qq0[r]); qq1[r] = fmaf(g2.x, wqA.y, qq1[r]);
                    kk0[r] = fmaf(g2.y, wkB.x, kk0[r]); kk1[r] = fmaf(g2.y, wkB.y, kk1[r]);
                    vv0[r] = fmaf(g2.y, wvB.x, vv0[r]); vv1[r] = fmaf(g2.y, wvB.y, vv1[r]);
                    qq0[r] = fmaf(g2.y, wqB.x, qq0[r]); qq1[r] = fmaf(g2.y, wqB.y, qq1[r]);
                }
            }
            // l2norm each row via shuffle reduce, store f16 to LDS
            #pragma unroll
            for (int r = 0; r < RPW; ++r){
                const int row = r0 + r;
                float sk = kk0[r] * kk0[r] + kk1[r] * kk1[r];
                float sv = vv0[r] * vv0[r] + vv1[r] * vv1[r];
                float sq = qq0[r] * qq0[r] + qq1[r] * qq1[r];
                #pragma unroll
                for (int off = 32; off; off >>= 1){
                    sk += __shfl_xor(sk, off, 64);
                    sv += __shfl_xor(sv, off, 64);
                    sq += __shfl_xor(sq, off, 64);
                }
                const float ik = 1.0f / fmaxf(sqrtf(sk), 1e-12f);
                const float iv = 1.0f / fmaxf(sqrtf(sv), 1e-12f);
                const float iq = 1.0f / fmaxf(sqrtf(sq), 1e-12f);
                *(unsigned int*)&k_s[row * KS + c0] = packh2(kk0[r] * ik, kk1[r] * ik);
                *(unsigned int*)&v_s[row * KS + c0] = packh2(vv0[r] * iv, vv1[r] * iv);
                *(unsigned int*)&qo_s[wid][r][c0]   = packh2(qq0[r] * iq, qq1[r] * iq);
            }
        }
        __syncthreads();

        // ---- per row: scores -> softmax -> weights -> PV (o overwrites q) ----
        for (int r = 0; r < RPW; ++r){
            const int row = r0 + r;
            const float mrow = msk_s[row];
            const float swr  = swm_s[row];
            const float rx = rhat_s[row * 4 + 0];
            const float ry = rhat_s[row * 4 + 1];
            const float rz = rhat_s[row * 4 + 2];
            const int k1 = lane;
            const int k2 = lane + 64;
            const int k2r = (k2 < NNEI) ? k2 : (NNEI - 1);
            float s0 = 0.0f, s1 = 0.0f;
            for (int dd = 0; dd < 64; ++dd){
                UH2 q, ka, kb;
                q.u  = *(const unsigned int*)&qo_s[wid][r][2 * dd];
                ka.u = *(const unsigned int*)&k_s[k1 * KS + 2 * dd];
                kb.u = *(const unsigned int*)&k_s[k2r * KS + 2 * dd];
#if __has_builtin(__builtin_amdgcn_fdot2)
                s0 = __builtin_amdgcn_fdot2(q.h, ka.h, s0, false);
                s1 = __builtin_amdgcn_fdot2(q.h, kb.h, s1, false);
#else
                s0 = fmaf((float)q.h[0], (float)ka.h[0], s0);
                s0 = fmaf((float)q.h[1], (float)ka.h[1], s0);
                s1 = fmaf((float)q.h[0], (float)kb.h[0], s1);
                s1 = fmaf((float)q.h[1], (float)kb.h[1], s1);
#endif
            }
            const float tinv = 0.08838834764831845f;  // 1/sqrt(128)
            s0 *= tinv; s1 *= tinv;
            const bool vld1 = (mrow != 0.0f) && (msk_s[k1] != 0.0f);
            const bool vld2 = (k2 < NNEI) && (mrow != 0.0f) && (msk_s[k2r] != 0.0f);
            const float NEG = -3.402823466e38f;
            const float sc0 = vld1 ? s0 : NEG;
            const float sc1 = vld2 ? s1 : NEG;
            float mx = fmaxf(sc0, sc1);
            #pragma unroll
            for (int off = 32; off; off >>= 1) mx = fmaxf(mx, __shfl_xor(mx, off, 64));
            const float e0 = __expf(sc0 - mx);
            const float e1 = __expf(sc1 - mx);
            float sum = e0 + e1;
            #pragma unroll
            for (int off = 32; off; off >>= 1) sum += __shfl_xor(sum, off, 64);
            const float rs = 1.0f / sum;
            const float gat1 = rx * rhat_s[k1 * 4 + 0] + ry * rhat_s[k1 * 4 + 1] + rz * rhat_s[k1 * 4 + 2];
            const float gat2 = rx * rhat_s[k2r * 4 + 0] + ry * rhat_s[k2r * 4 + 1] + rz * rhat_s[k2r * 4 + 2];
            const float p0 = vld1 ? (e0 * rs * swr * swm_s[k1]  * gat1) : 0.0f;
            const float p1 = vld2 ? (e1 * rs * swr * swm_s[k2r] * gat2) : 0.0f;
            pbuf[wid][k1] = p0;
            pbuf[wid][k2] = p1;
            __threadfence_block();
            // o row: lane owns dims c0, c0+1
            float o0 = 0.0f, o1 = 0.0f;
            for (int k = 0; k < NNEI; k += 4){
                const float4 p4 = *(const float4*)&pbuf[wid][k];
                UH2 v0, v1, v2, v3;
                v0.u = *(const unsigned int*)&v_s[(k + 0) * KS + c0];
                v1.u = *(const unsigned int*)&v_s[(k + 1) * KS + c0];
                v2.u = *(const unsigned int*)&v_s[(k + 2) * KS + c0];
                v3.u = *(const unsigned int*)&v_s[(k + 3) * KS + c0];
                o0 = fmaf(p4.x, (float)v0.h[0], o0); o1 = fmaf(p4.x, (float)v0.h[1], o1);
                o0 = fmaf(p4.y, (float)v1.h[0], o0); o1 = fmaf(p4.y, (float)v1.h[1], o1);
                o0 = fmaf(p4.z, (float)v2.h[0], o0); o1 = fmaf(p4.z, (float)v2.h[1], o1);
                o0 = fmaf(p4.w, (float)v3.h[0], o0); o1 = fmaf(p4.w, (float)v3.h[1], o1);
            }
            *(unsigned int*)&qo_s[wid][r][c0] = packh2(o0, o1);  // overwrite q with o
        }
        __threadfence_block();

        // ---- o2 = O @ WO + BO ; LayerNorm ; residual into g (own rows) -------
        {
            float oa[RPW], ob[RPW];
            const float bo0 = BO[j0];
            const float bo1 = hasj1 ? BO[j1] : 0.0f;
            #pragma unroll
            for (int r = 0; r < RPW; ++r){ oa[r] = bo0; ob[r] = bo1; }
            for (int d = 0; d < ADIM; d += 2){
                const float w00 = WO[d * MDIM + j0];
                const float w01 = hasj1 ? WO[d * MDIM + j1] : 0.0f;
                const float w10 = WO[(d + 1) * MDIM + j0];
                const float w11 = hasj1 ? WO[(d + 1) * MDIM + j1] : 0.0f;
                #pragma unroll
                for (int r = 0; r < RPW; ++r){
                    UH2 ow; ow.u = *(const unsigned int*)&qo_s[wid][r][d];
                    const float od0 = (float)ow.h[0], od1 = (float)ow.h[1];
                    oa[r] = fmaf(od0, w00, oa[r]); ob[r] = fmaf(od0, w01, ob[r]);
                    oa[r] = fmaf(od1, w10, oa[r]); ob[r] = fmaf(od1, w11, ob[r]);
                }
            }
            #pragma unroll
            for (int r = 0; r < RPW; ++r){
                const int row = r0 + r;
                const float va = oa[r];
                const float vb = hasj1 ? ob[r] : 0.0f;
                float s  = va + vb;
                float s2 = va * va + vb * vb;
                #pragma unroll
                for (int off = 32; off; off >>= 1){
                    s  += __shfl_xor(s,  off, 64);
                    s2 += __shfl_xor(s2, off, 64);
                }
                const float mu   = s * 0.01f;
                const float var  = s2 * 0.01f - mu * mu;
                const float rstd = rsqrtf(var + 1e-5f);
                g_s[row * GS + j0] += (va - mu) * rstd * LG[j0] + LB[j0];
                if (hasj1) g_s[row * GS + j1] += (vb - mu) * rstd * LG[j1] + LB[j1];
            }
        }
        __syncthreads();
    }

    // ---------------- Final: gr = env^T g / NNEI ; d = gr^T gr[:, :16] ----------
    for (int idx = tid; idx < 4 * MDIM; idx += 768){
        const int c = idx / MDIM, mm = idx - c * MDIM;
        float a = 0.0f;
        for (int k = 0; k < NNEI; ++k)
            a = fmaf(env_s[k * 4 + c], g_s[k * GS + mm], a);
        gr_s[c * MDIM + mm] = a * (1.0f / 120.0f);
    }
    __syncthreads();

    float* outp = out + (size_t)n * OUTD;
    for (int idx = tid; idx < MDIM * AXISD; idx += 768){
        const int mm = idx >> 4, aa = idx & 15;
        float acc = 0.0f;
        #pragma unroll
        for (int c = 0; c < 4; ++c)
            acc = fmaf(gr_s[c * MDIM + mm], gr_s[c * MDIM + aa], acc);
        outp[idx] = acc;
    }
    if (tid < 8) outp[1600 + tid] = tebd_s[ta_sh * 8 + tid];
}

extern "C" void kernel_launch(void* const* d_in, const int* in_sizes, int n_in,
                              void* d_out, int out_size, void* d_ws, size_t ws_size,
                              hipStream_t stream) {
    const float* rij   = (const float*)d_in[0];
    const void*  nmask = d_in[1];
    const int*   atype = (const int*)d_in[2];
    const int*   ntype = (const int*)d_in[3];
    const float* tebd  = (const float*)d_in[4];
    const float* ew0 = (const float*)d_in[5];
    const float* eb0 = (const float*)d_in[6];
    const float* ew1 = (const float*)d_in[7];
    const float* eb1 = (const float*)d_in[8];
    const float* ew2 = (const float*)d_in[9];
    const float* eb2 = (const float*)d_in[10];
    const float* wq = (const float*)d_in[11];
    const float* bq = (const float*)d_in[12];
    const float* wk = (const float*)d_in[13];
    const float* bk = (const float*)d_in[14];
    const float* wv = (const float*)d_in[15];
    const float* bv = (const float*)d_in[16];
    const float* wo = (const float*)d_in[17];
    const float* bo = (const float*)d_in[18];
    const float* lng = (const float*)d_in[19];
    const float* lnb = (const float*)d_in[20];
    float* out = (float*)d_out;
    int* flag = (int*)d_ws;

    detect_mask_kernel<<<1, 64, 0, stream>>>((const unsigned char*)nmask, flag);
    dpa1_kernel<<<4096, 768, 0, stream>>>(rij, nmask, atype, ntype, tebd,
                                          ew0, eb0, ew1, eb1, ew2, eb2,
                                          wq, bq, wk, bk, wv, bv, wo, bo,
                                          lng, lnb, out, flag);
}

// Round 3
// 1419.596 us; speedup vs baseline: 12.8889x; 3.0425x over previous
//
#include <hip/hip_runtime.h>

// DescrptDPA1 on gfx950 — MFMA version.
// NF=1, NLOC=4096, NNEI=120, TEBD=8, NTYPES=4, M=100, ATTN=128, NLAYER=2, AXIS=16.
// One block per atom, 768 threads (12 waves). All big matmuls on
// v_mfma_f32_16x16x32_bf16. Weights pre-packed into B-fragment order in d_ws.

#define NNEI 120
#define MDIM 100
#define ADIM 128
#define GS   100   // f32 pitch of g master
#define BP   136   // bf16 pitch (272B rows: 16B-aligned, 68 dw = 4 mod 32 banks)
#define OUTD 1608

typedef __attribute__((ext_vector_type(8))) short bf16x8;
typedef __attribute__((ext_vector_type(4))) float f32x4;

__device__ __forceinline__ float bf2f(unsigned short u){
    return __uint_as_float(((unsigned int)u) << 16);
}
__device__ __forceinline__ unsigned short f2bf(float f){
    unsigned int x = __float_as_uint(f);
    return (unsigned short)((x + 0x7fffu + ((x >> 16) & 1u)) >> 16);
}
__device__ __forceinline__ float ftanh(float x){
    return 1.0f - 2.0f / (__expf(2.0f * x) + 1.0f);
}

// nmask storage detection: 1 = int32 {0,1}, 2 = f32 {0.0,1.0}, 0 = byte bool
__global__ void detect_mask_kernel(const unsigned char* __restrict__ p,
                                   int* __restrict__ flag){
    if (blockIdx.x == 0 && threadIdx.x == 0){
        const unsigned int* u = (const unsigned int*)p;
        int alli = 1, allf = 1;
        for (int i = 0; i < 64; ++i){
            unsigned int w = u[i];
            if (!(w == 0u || w == 1u)) alli = 0;
            if (!(w == 0u || w == 0x3f800000u)) allf = 0;
        }
        flag[0] = alli ? 1 : (allf ? 2 : 0);
    }
}

// Pack weights into B-fragment order (bf16). Frag = [64 lanes][8 bf16] = 1024B.
// QKV frags: fid = ((l*3+mat)*8+nt)*4+ks, 192 total. WO frags: 192 + (l*7+nt)*4+ks, 56.
// B-frag element (lane, i): n = nt*16+(lane&15), kk = ks*32+(lane>>4)*8+i, val = W[kk][n].
__global__ void prep_weights(const float* __restrict__ wq, const float* __restrict__ wk,
                             const float* __restrict__ wv, const float* __restrict__ wo,
                             unsigned short* __restrict__ wsb){
    const int fid = blockIdx.x;
    const int lane = threadIdx.x;  // 64
    unsigned short* dst = wsb + (size_t)fid * 512 + lane * 8;
    if (fid < 192){
        const int l = fid / 96, rem = fid % 96, mat = rem / 32;
        const int r2 = rem % 32, nt = r2 / 4, ks = r2 % 4;
        const float* W = (mat == 0 ? wq : mat == 1 ? wk : wv) + l * MDIM * ADIM;
        const int n = nt * 16 + (lane & 15);
        const int k0 = ks * 32 + (lane >> 4) * 8;
        #pragma unroll
        for (int i = 0; i < 8; ++i){
            const int kk = k0 + i;
            dst[i] = (kk < MDIM) ? f2bf(W[kk * ADIM + n]) : (unsigned short)0;
        }
    } else {
        const int f2 = fid - 192, l = f2 / 28, rem = f2 % 28, nt = rem / 4, ks = rem % 4;
        const float* W = wo + l * ADIM * MDIM;
        const int n = nt * 16 + (lane & 15);
        const int k0 = ks * 32 + (lane >> 4) * 8;
        #pragma unroll
        for (int i = 0; i < 8; ++i){
            const int kk = k0 + i;
            dst[i] = (n < MDIM) ? f2bf(W[kk * MDIM + n]) : (unsigned short)0;
        }
    }
}

__global__ __launch_bounds__(768) void dpa1_kernel(
    const float* __restrict__ rij, const void* __restrict__ nmask,
    const int* __restrict__ atype, const int* __restrict__ ntype,
    const float* __restrict__ tebd,
    const float* __restrict__ ew0, const float* __restrict__ eb0,
    const float* __restrict__ ew1, const float* __restrict__ eb1,
    const float* __restrict__ ew2, const float* __restrict__ eb2,
    const float* __restrict__ bq, const float* __restrict__ bk,
    const float* __restrict__ bv, const float* __restrict__ bo,
    const float* __restrict__ lng, const float* __restrict__ lnb,
    float* __restrict__ out, const int* __restrict__ flagp,
    const unsigned short* __restrict__ wsb)
{
    __shared__ __align__(16) float g_s[NNEI * GS];            // 48,000 B (f32 master)
    __shared__ __align__(16) unsigned short buf1[128 * BP];   // 34,816 B: gb -> Qn -> P -> O
    __shared__ __align__(16) unsigned short kn_s[128 * BP];   // 34,816 B: Kraw (B of scores)
    __shared__ __align__(16) unsigned short vT_s[128 * BP];   // 34,816 B: V^T (B of PV)
    __shared__ float sums_s[384];                             // qss|kss|vss
    __shared__ __align__(16) float env_s[NNEI * 4];
    __shared__ __align__(16) float rhat_s[NNEI * 4];
    __shared__ float swm_s[NNEI];
    __shared__ float msk_s[NNEI];
    __shared__ int   ntype_s[NNEI];
    __shared__ float tebd_s[32];
    __shared__ float gr_s[4 * MDIM];
    __shared__ int ta_sh;

    const int n    = blockIdx.x;
    const int tid  = threadIdx.x;
    const int lane = tid & 63;
    const int wid  = tid >> 6;
    const int flag = flagp[0];

    if (tid < 32) tebd_s[tid] = tebd[tid];
    if (tid == 0) ta_sh = atype[n];

    // ---------------- Phase 0a: geometry (thread = neighbor) -------------------
    if (tid < NNEI){
        const int k = tid;
        const int base = n * NNEI + k;
        const float rx = rij[base * 3 + 0];
        const float ry = rij[base * 3 + 1];
        const float rz = rij[base * 3 + 2];
        const float r  = sqrtf(rx * rx + ry * ry + rz * rz);
        float mval;
        if (flag == 1)      mval = (((const int*)nmask)[base] != 0) ? 1.0f : 0.0f;
        else if (flag == 2) mval = ((const float*)nmask)[base];
        else                mval = (((const unsigned char*)nmask)[base] != 0) ? 1.0f : 0.0f;
        float uu = (r - 0.5f) * (1.0f / 5.5f);
        uu = fminf(fmaxf(uu, 0.0f), 1.0f);
        const float sw   = uu * uu * uu * (-6.0f * uu * uu + 15.0f * uu - 10.0f) + 1.0f;
        const float invr = 1.0f / r;
        const float sr   = sw * invr * mval;
        const float hx = rx * invr, hy = ry * invr, hz = rz * invr;
        env_s[k * 4 + 0] = sr;
        env_s[k * 4 + 1] = sr * hx;
        env_s[k * 4 + 2] = sr * hy;
        env_s[k * 4 + 3] = sr * hz;
        rhat_s[k * 4 + 0] = hx; rhat_s[k * 4 + 1] = hy; rhat_s[k * 4 + 2] = hz;
        rhat_s[k * 4 + 3] = 0.0f;
        swm_s[k] = sw * mval;
        msk_s[k] = mval;
        ntype_s[k] = ntype[base];
    }
    __syncthreads();

    // ---------------- Phase 0b: embedding MLP, output-parallel ----------------
    {
        float* h1buf = (float*)vT_s;  // [120][25]
        float* h2buf = (float*)kn_s;  // [120][50]
        const int ta = ta_sh;

        for (int idx = tid; idx < NNEI * 25; idx += 768){
            const int k = idx / 25, j = idx - k * 25;
            const float sr = env_s[k * 4];
            const float* tn = &tebd_s[ntype_s[k] * 8];
            const float* tc = &tebd_s[ta * 8];
            float a = eb0[j] + sr * ew0[j];
            #pragma unroll
            for (int i = 0; i < 8; ++i){
                a = fmaf(tn[i], ew0[(1 + i) * 25 + j], a);
                a = fmaf(tc[i], ew0[(9 + i) * 25 + j], a);
            }
            h1buf[k * 25 + j] = ftanh(a);
        }
        __syncthreads();

        for (int idx = tid; idx < NNEI * 50; idx += 768){
            const int k = idx / 50, j = idx - k * 50;
            float a = eb1[j];
            const float* h1r = &h1buf[k * 25];
            #pragma unroll
            for (int i = 0; i < 25; ++i) a = fmaf(h1r[i], ew1[i * 50 + j], a);
            h2buf[k * 50 + j] = ftanh(a) + h1r[j >= 25 ? j - 25 : j];
        }
        __syncthreads();

        for (int idx = tid; idx < NNEI * MDIM; idx += 768){
            const int k = idx / MDIM, j = idx - k * MDIM;
            float a = eb2[j];
            const float* h2r = &h2buf[k * 50];
            #pragma unroll
            for (int i = 0; i < 50; ++i) a = fmaf(h2r[i], ew2[i * MDIM + j], a);
            g_s[k * GS + j] = (ftanh(a) + h2r[j >= 50 ? j - 50 : j]) * msk_s[k];
        }
        __syncthreads();
    }

    // ---------------- Attention layers (MFMA) ----------------
    const float tinv = 0.08838834764831845f;  // 1/sqrt(128)

    for (int l = 0; l < 2; ++l){
        // ---- P1: build bf16 g-panel into buf1 (zero-padded), zero sums ----
        {
            unsigned int* gb32 = (unsigned int*)buf1;
            for (int idx = tid; idx < 128 * (BP/2); idx += 768){
                const int row = idx / (BP/2), cu = idx - row * (BP/2);
                const int c0 = 2 * cu;
                unsigned int lo = 0, hi = 0;
                if (row < NNEI){
                    if (c0     < MDIM) lo = f2bf(g_s[row * GS + c0]);
                    if (c0 + 1 < MDIM) hi = f2bf(g_s[row * GS + c0 + 1]);
                }
                gb32[idx] = lo | (hi << 16);
            }
            if (tid < 384) sums_s[tid] = 0.0f;
        }
        __syncthreads();  // b1

        // ---- QKV: all 12 waves. wave w -> mat = w>>2, tile-cols 2w,2w+1 (mod 8) ----
        {
            const int mat = wid >> 2;
            bf16x8 Bf[2][4];
            #pragma unroll
            for (int c = 0; c < 2; ++c){
                const int nt = (2 * wid + c) & 7;
                #pragma unroll
                for (int ks = 0; ks < 4; ++ks){
                    const int fid = ((l * 3 + mat) * 8 + nt) * 4 + ks;
                    Bf[c][ks] = *(const bf16x8*)(wsb + (size_t)fid * 512 + lane * 8);
                }
            }
            f32x4 Cq[8][2];
            #pragma unroll
            for (int mt = 0; mt < 8; ++mt)
                #pragma unroll
                for (int c = 0; c < 2; ++c)
                    Cq[mt][c] = (f32x4){0.f, 0.f, 0.f, 0.f};
            #pragma unroll
            for (int mt = 0; mt < 8; ++mt){
                bf16x8 a[4];
                #pragma unroll
                for (int ks = 0; ks < 4; ++ks)
                    a[ks] = *(const bf16x8*)&buf1[(mt*16 + (lane & 15)) * BP + ks*32 + (lane >> 4) * 8];
                #pragma unroll
                for (int c = 0; c < 2; ++c)
                    #pragma unroll
                    for (int ks = 0; ks < 4; ++ks)
                        Cq[mt][c] = __builtin_amdgcn_mfma_f32_16x16x32_bf16(a[ks], Bf[c][ks], Cq[mt][c], 0, 0, 0);
            }
            __syncthreads();  // b2: gb dead; store C-tiles

            const float* BIAS = (mat == 0 ? bq : mat == 1 ? bk : bv) + l * ADIM;
            float bias_c[2];
            #pragma unroll
            for (int c = 0; c < 2; ++c)
                bias_c[c] = BIAS[((2 * wid + c) & 7) * 16 + (lane & 15)];

            #pragma unroll
            for (int mt = 0; mt < 8; ++mt){
                #pragma unroll
                for (int c = 0; c < 2; ++c){
                    const int nt = (2 * wid + c) & 7;
                    const int d  = nt * 16 + (lane & 15);
                    const int qb = mt * 16 + (lane >> 4) * 4;
                    float v[4]; unsigned short vb[4];
                    #pragma unroll
                    for (int r = 0; r < 4; ++r){
                        v[r]  = Cq[mt][c][r] + bias_c[c];
                        vb[r] = f2bf(v[r]);
                        float sq = v[r] * v[r];
                        sq += __shfl_xor(sq, 1, 64); sq += __shfl_xor(sq, 2, 64);
                        sq += __shfl_xor(sq, 4, 64); sq += __shfl_xor(sq, 8, 64);
                        if ((lane & 15) == 0) atomicAdd(&sums_s[mat * 128 + qb + r], sq);
                    }
                    if (mat == 2){
                        const unsigned int lo = (unsigned int)vb[0] | ((unsigned int)vb[1] << 16);
                        const unsigned int hi = (unsigned int)vb[2] | ((unsigned int)vb[3] << 16);
                        *(uint2*)&vT_s[d * BP + qb] = make_uint2(lo, hi);
                    } else {
                        unsigned short* dstb = (mat == 0) ? buf1 : kn_s;
                        #pragma unroll
                        for (int r = 0; r < 4; ++r) dstb[(qb + r) * BP + d] = vb[r];
                    }
                }
            }
        }
        __syncthreads();  // b3

        // ---- core attention: 8 waves own 16 q-rows each ----
        if (wid < 8){
            const int qrow = wid * 16;
            // scores: A = Q own rows, B = Kraw
            bf16x8 aq[4];
            #pragma unroll
            for (int ks = 0; ks < 4; ++ks)
                aq[ks] = *(const bf16x8*)&buf1[(qrow + (lane & 15)) * BP + ks*32 + (lane >> 4) * 8];
            f32x4 Cs[8];
            #pragma unroll
            for (int nt = 0; nt < 8; ++nt) Cs[nt] = (f32x4){0.f, 0.f, 0.f, 0.f};
            #pragma unroll
            for (int nt = 0; nt < 8; ++nt)
                #pragma unroll
                for (int ks = 0; ks < 4; ++ks){
                    bf16x8 b = *(const bf16x8*)&kn_s[(nt*16 + (lane & 15)) * BP + ks*32 + (lane >> 4) * 8];
                    Cs[nt] = __builtin_amdgcn_mfma_f32_16x16x32_bf16(aq[ks], b, Cs[nt], 0, 0, 0);
                }

            // softmax in regs. row quantities:
            float qi[4], mrow[4], swr[4], rqx[4], rqy[4], rqz[4];
            #pragma unroll
            for (int r = 0; r < 4; ++r){
                const int q = qrow + (lane >> 4) * 4 + r;
                const bool ok = (q < NNEI);
                mrow[r] = ok ? msk_s[q] : 0.0f;
                swr[r]  = ok ? swm_s[q] : 0.0f;
                float4 rh = ok ? *(const float4*)&rhat_s[q * 4] : make_float4(0, 0, 0, 0);
                rqx[r] = rh.x; rqy[r] = rh.y; rqz[r] = rh.z;
                const float ss = ok ? sums_s[q] : 1.0f;
                qi[r] = 1.0f / fmaxf(sqrtf(ss), 1e-12f);
            }
            float mx[4] = {-3.4e38f, -3.4e38f, -3.4e38f, -3.4e38f};
            #pragma unroll
            for (int nt = 0; nt < 8; ++nt){
                const int k = nt * 16 + (lane & 15);
                const float mc = (k < NNEI) ? msk_s[k] : 0.0f;
                const float ki = 1.0f / fmaxf(sqrtf(sums_s[128 + k]), 1e-12f);
                #pragma unroll
                for (int r = 0; r < 4; ++r){
                    const float sc = (mrow[r] != 0.0f && mc != 0.0f)
                                     ? Cs[nt][r] * tinv * qi[r] * ki : -3.4e38f;
                    Cs[nt][r] = sc;
                    mx[r] = fmaxf(mx[r], sc);
                }
            }
            #pragma unroll
            for (int r = 0; r < 4; ++r){
                mx[r] = fmaxf(mx[r], __shfl_xor(mx[r], 1, 64));
                mx[r] = fmaxf(mx[r], __shfl_xor(mx[r], 2, 64));
                mx[r] = fmaxf(mx[r], __shfl_xor(mx[r], 4, 64));
                mx[r] = fmaxf(mx[r], __shfl_xor(mx[r], 8, 64));
            }
            float sum[4] = {0.f, 0.f, 0.f, 0.f};
            #pragma unroll
            for (int nt = 0; nt < 8; ++nt)
                #pragma unroll
                for (int r = 0; r < 4; ++r){
                    const float e = (Cs[nt][r] > -1e37f) ? __expf(Cs[nt][r] - mx[r]) : 0.0f;
                    Cs[nt][r] = e;
                    sum[r] += e;
                }
            #pragma unroll
            for (int r = 0; r < 4; ++r){
                sum[r] += __shfl_xor(sum[r], 1, 64); sum[r] += __shfl_xor(sum[r], 2, 64);
                sum[r] += __shfl_xor(sum[r], 4, 64); sum[r] += __shfl_xor(sum[r], 8, 64);
                sum[r] = (sum[r] > 0.0f) ? swr[r] / sum[r] : 0.0f;  // fold row smooth
            }
            #pragma unroll
            for (int nt = 0; nt < 8; ++nt){
                const int k = nt * 16 + (lane & 15);
                float colf = 0.f, gkx = 0.f, gky = 0.f, gkz = 0.f;
                if (k < NNEI){
                    const float vi = 1.0f / fmaxf(sqrtf(sums_s[256 + k]), 1e-12f);
                    colf = swm_s[k] * vi;  // fold col smooth + V-norm
                    float4 rh = *(const float4*)&rhat_s[k * 4];
                    gkx = rh.x; gky = rh.y; gkz = rh.z;
                }
                #pragma unroll
                for (int r = 0; r < 4; ++r){
                    const float gate = rqx[r] * gkx + rqy[r] * gky + rqz[r] * gkz;
                    const float p = Cs[nt][r] * sum[r] * colf * gate;
                    const int q = qrow + (lane >> 4) * 4 + r;
                    buf1[q * BP + k] = f2bf(p);  // P overwrites Q rows (own rows only)
                }
            }
            asm volatile("s_waitcnt lgkmcnt(0)" ::: "memory");
            __builtin_amdgcn_sched_barrier(0);

            // PV: A = P own rows, B = V^T
            bf16x8 ap[4];
            #pragma unroll
            for (int ks = 0; ks < 4; ++ks)
                ap[ks] = *(const bf16x8*)&buf1[(qrow + (lane & 15)) * BP + ks*32 + (lane >> 4) * 8];
            f32x4 Co[8];
            #pragma unroll
            for (int nt = 0; nt < 8; ++nt) Co[nt] = (f32x4){0.f, 0.f, 0.f, 0.f};
            #pragma unroll
            for (int nt = 0; nt < 8; ++nt)
                #pragma unroll
                for (int ks = 0; ks < 4; ++ks){
                    bf16x8 b = *(const bf16x8*)&vT_s[(nt*16 + (lane & 15)) * BP + ks*32 + (lane >> 4) * 8];
                    Co[nt] = __builtin_amdgcn_mfma_f32_16x16x32_bf16(ap[ks], b, Co[nt], 0, 0, 0);
                }
            // write O (overwrites P rows, own rows only)
            #pragma unroll
            for (int nt = 0; nt < 8; ++nt)
                #pragma unroll
                for (int r = 0; r < 4; ++r){
                    const int q = qrow + (lane >> 4) * 4 + r;
                    buf1[q * BP + nt * 16 + (lane & 15)] = f2bf(Co[nt][r]);
                }
            asm volatile("s_waitcnt lgkmcnt(0)" ::: "memory");
            __builtin_amdgcn_sched_barrier(0);

            // out-proj: A = O own rows, B = packed WO^T frags
            bf16x8 ao[4];
            #pragma unroll
            for (int ks = 0; ks < 4; ++ks)
                ao[ks] = *(const bf16x8*)&buf1[(qrow + (lane & 15)) * BP + ks*32 + (lane >> 4) * 8];
            f32x4 Cf[7];
            #pragma unroll
            for (int nt = 0; nt < 7; ++nt) Cf[nt] = (f32x4){0.f, 0.f, 0.f, 0.f};
            #pragma unroll
            for (int nt = 0; nt < 7; ++nt)
                #pragma unroll
                for (int ks = 0; ks < 4; ++ks){
                    bf16x8 b = *(const bf16x8*)(wsb + (size_t)(192 + (l * 7 + nt) * 4 + ks) * 512 + lane * 8);
                    Cf[nt] = __builtin_amdgcn_mfma_f32_16x16x32_bf16(ao[ks], b, Cf[nt], 0, 0, 0);
                }

            // LayerNorm + residual into g_s (own rows)
            const float* BO = bo  + l * MDIM;
            const float* LG = lng + l * MDIM;
            const float* LB = lnb + l * MDIM;
            float bov[7], lgv[7], lbv[7]; bool jok[7];
            #pragma unroll
            for (int nt = 0; nt < 7; ++nt){
                const int j = nt * 16 + (lane & 15);
                jok[nt] = (j < MDIM);
                bov[nt] = jok[nt] ? BO[j] : 0.0f;
                lgv[nt] = jok[nt] ? LG[j] : 0.0f;
                lbv[nt] = jok[nt] ? LB[j] : 0.0f;
            }
            #pragma unroll
            for (int r = 0; r < 4; ++r){
                const int q = qrow + (lane >> 4) * 4 + r;
                float sv = 0.f, sv2 = 0.f;
                float val[7];
                #pragma unroll
                for (int nt = 0; nt < 7; ++nt){
                    const float v = Cf[nt][r] + bov[nt];
                    val[nt] = v;
                    if (jok[nt]){ sv += v; sv2 += v * v; }
                }
                sv  += __shfl_xor(sv, 1, 64);  sv  += __shfl_xor(sv, 2, 64);
                sv  += __shfl_xor(sv, 4, 64);  sv  += __shfl_xor(sv, 8, 64);
                sv2 += __shfl_xor(sv2, 1, 64); sv2 += __shfl_xor(sv2, 2, 64);
                sv2 += __shfl_xor(sv2, 4, 64); sv2 += __shfl_xor(sv2, 8, 64);
                const float mu   = sv * 0.01f;
                const float var  = sv2 * 0.01f - mu * mu;
                const float rstd = rsqrtf(var + 1e-5f);
                if (q < NNEI){
                    #pragma unroll
                    for (int nt = 0; nt < 7; ++nt) if (jok[nt]){
                        const int j = nt * 16 + (lane & 15);
                        g_s[q * GS + j] += (val[nt] - mu) * rstd * lgv[nt] + lbv[nt];
                    }
                }
            }
        }
        __syncthreads();  // b4: end of layer
    }

    // ---------------- Final: gr = env^T g / NNEI ; d = gr^T gr[:, :16] ----------
    for (int idx = tid; idx < 4 * MDIM; idx += 768){
        const int c = idx / MDIM, mm = idx - c * MDIM;
        float a = 0.0f;
        for (int k = 0; k < NNEI; ++k)
            a = fmaf(env_s[k * 4 + c], g_s[k * GS + mm], a);
        gr_s[c * MDIM + mm] = a * (1.0f / 120.0f);
    }
    __syncthreads();

    float* outp = out + (size_t)n * OUTD;
    for (int idx = tid; idx < MDIM * 16; idx += 768){
        const int mm = idx >> 4, aa = idx & 15;
        float acc = 0.0f;
        #pragma unroll
        for (int c = 0; c < 4; ++c)
            acc = fmaf(gr_s[c * MDIM + mm], gr_s[c * MDIM + aa], acc);
        outp[idx] = acc;
    }
    if (tid < 8) outp[1600 + tid] = tebd_s[ta_sh * 8 + tid];
}

extern "C" void kernel_launch(void* const* d_in, const int* in_sizes, int n_in,
                              void* d_out, int out_size, void* d_ws, size_t ws_size,
                              hipStream_t stream) {
    const float* rij   = (const float*)d_in[0];
    const void*  nmask = d_in[1];
    const int*   atype = (const int*)d_in[2];
    const int*   ntype = (const int*)d_in[3];
    const float* tebd  = (const float*)d_in[4];
    const float* ew0 = (const float*)d_in[5];
    const float* eb0 = (const float*)d_in[6];
    const float* ew1 = (const float*)d_in[7];
    const float* eb1 = (const float*)d_in[8];
    const float* ew2 = (const float*)d_in[9];
    const float* eb2 = (const float*)d_in[10];
    const float* wq = (const float*)d_in[11];
    const float* bq = (const float*)d_in[12];
    const float* wk = (const float*)d_in[13];
    const float* bk = (const float*)d_in[14];
    const float* wv = (const float*)d_in[15];
    const float* bv = (const float*)d_in[16];
    const float* wo = (const float*)d_in[17];
    const float* bo = (const float*)d_in[18];
    const float* lng = (const float*)d_in[19];
    const float* lnb = (const float*)d_in[20];
    float* out = (float*)d_out;
    int* flag = (int*)d_ws;
    unsigned short* wsb = (unsigned short*)((char*)d_ws + 256);

    detect_mask_kernel<<<1, 64, 0, stream>>>((const unsigned char*)nmask, flag);
    prep_weights<<<248, 64, 0, stream>>>(wq, wk, wv, wo, wsb);
    dpa1_kernel<<<4096, 768, 0, stream>>>(rij, nmask, atype, ntype, tebd,
                                          ew0, eb0, ew1, eb1, ew2, eb2,
                                          bq, bk, bv, bo, lng, lnb,
                                          out, flag, wsb);
}

// Round 4
// 1318.583 us; speedup vs baseline: 13.8763x; 1.0766x over previous
//
#include <hip/hip_runtime.h>

// DescrptDPA1 on gfx950 — MFMA version, 16 waves (1024 thr), no-max softmax,
// bf16 g master, MFMA embedding layer 3.
// NF=1, NLOC=4096, NNEI=120, TEBD=8, NTYPES=4, M=100, ATTN=128, NLAYER=2, AXIS=16.

#define NNEI 120
#define MDIM 100
#define ADIM 128
#define BP   136   // bf16 pitch (272B rows; 68 dw = 4 mod 32 banks, 16B aligned)
#define H2P  72    // bf16 pitch for h2 staging (144B; 36 dw = 4 mod 32)
#define OUTD 1608

typedef __attribute__((ext_vector_type(8))) short bf16x8;
typedef __attribute__((ext_vector_type(4))) float f32x4;

__device__ __forceinline__ float bf2f(unsigned short u){
    return __uint_as_float(((unsigned int)u) << 16);
}
__device__ __forceinline__ unsigned short f2bf(float f){
    unsigned int x = __float_as_uint(f);
    return (unsigned short)((x + 0x7fffu + ((x >> 16) & 1u)) >> 16);
}
__device__ __forceinline__ float ftanh(float x){
    return 1.0f - 2.0f / (__expf(2.0f * x) + 1.0f);
}

// nmask storage detection: 1 = int32 {0,1}, 2 = f32 {0.0,1.0}, 0 = byte bool
__global__ void detect_mask_kernel(const unsigned char* __restrict__ p,
                                   int* __restrict__ flag){
    if (blockIdx.x == 0 && threadIdx.x == 0){
        const unsigned int* u = (const unsigned int*)p;
        int alli = 1, allf = 1;
        for (int i = 0; i < 64; ++i){
            unsigned int w = u[i];
            if (!(w == 0u || w == 1u)) alli = 0;
            if (!(w == 0u || w == 0x3f800000u)) allf = 0;
        }
        flag[0] = alli ? 1 : (allf ? 2 : 0);
    }
}

// Pack weights into B-fragment order (bf16). Frag = [64 lanes][8 bf16] = 1024B.
// QKV: fid = ((l*3+mat)*8+nt)*4+ks (192). WO: 192+(l*7+nt)*4+ks (56).
// ew2: 248 + nt*2 + ks (14). Total 262.
__global__ void prep_weights(const float* __restrict__ wq, const float* __restrict__ wk,
                             const float* __restrict__ wv, const float* __restrict__ wo,
                             const float* __restrict__ ew2,
                             unsigned short* __restrict__ wsb){
    const int fid = blockIdx.x;
    const int lane = threadIdx.x;  // 64
    unsigned short* dst = wsb + (size_t)fid * 512 + lane * 8;
    if (fid < 192){
        const int l = fid / 96, rem = fid % 96, mat = rem / 32;
        const int r2 = rem % 32, nt = r2 / 4, ks = r2 % 4;
        const float* W = (mat == 0 ? wq : mat == 1 ? wk : wv) + l * MDIM * ADIM;
        const int nn = nt * 16 + (lane & 15);
        const int k0 = ks * 32 + (lane >> 4) * 8;
        #pragma unroll
        for (int i = 0; i < 8; ++i){
            const int kk = k0 + i;
            dst[i] = (kk < MDIM) ? f2bf(W[kk * ADIM + nn]) : (unsigned short)0;
        }
    } else if (fid < 248){
        const int f2 = fid - 192, l = f2 / 28, rem = f2 % 28, nt = rem / 4, ks = rem % 4;
        const float* W = wo + l * ADIM * MDIM;
        const int nn = nt * 16 + (lane & 15);
        const int k0 = ks * 32 + (lane >> 4) * 8;
        #pragma unroll
        for (int i = 0; i < 8; ++i){
            const int kk = k0 + i;
            dst[i] = (nn < MDIM) ? f2bf(W[kk * MDIM + nn]) : (unsigned short)0;
        }
    } else {
        const int f3 = fid - 248, nt = f3 >> 1, ks = f3 & 1;
        const int nn = nt * 16 + (lane & 15);
        const int k0 = ks * 32 + (lane >> 4) * 8;
        #pragma unroll
        for (int i = 0; i < 8; ++i){
            const int kk = k0 + i;
            dst[i] = (kk < 50 && nn < MDIM) ? f2bf(ew2[kk * MDIM + nn]) : (unsigned short)0;
        }
    }
}

__global__ __launch_bounds__(1024, 4) void dpa1_kernel(
    const float* __restrict__ rij, const void* __restrict__ nmask,
    const int* __restrict__ atype, const int* __restrict__ ntype,
    const float* __restrict__ tebd,
    const float* __restrict__ ew0, const float* __restrict__ eb0,
    const float* __restrict__ ew1, const float* __restrict__ eb1,
    const float* __restrict__ eb2,
    const float* __restrict__ bq, const float* __restrict__ bk,
    const float* __restrict__ bv, const float* __restrict__ bo,
    const float* __restrict__ lng, const float* __restrict__ lnb,
    float* __restrict__ out, const int* __restrict__ flagp,
    const unsigned short* __restrict__ wsb)
{
    __shared__ __align__(16) unsigned short g16[128 * BP];   // 34,816 B bf16 g master
    __shared__ __align__(16) unsigned short buf1[128 * BP];  // h2 -> Q -> P -> O
    __shared__ __align__(16) unsigned short kn_s[128 * BP];  // K
    __shared__ __align__(16) unsigned short vT_s[128 * BP];  // h1(f32) -> V^T
    __shared__ float sums_s[384];          // |q|^2, |k|^2, |v|^2 per row
    __shared__ float psum_s[128 * 2];      // softmax partial sums per col-half
    __shared__ float lnp_s[128 * 4];       // LN partials (sv, sv2) per col-half
    __shared__ __align__(16) float env_s[128 * 4];
    __shared__ __align__(16) float rhat_s[128 * 4];
    __shared__ float swm_s[128];
    __shared__ float msk_s[128];
    __shared__ int   ntype_s[NNEI];
    __shared__ float tebd_s[32];
    __shared__ float gr_s[4 * MDIM];
    __shared__ int ta_sh;

    const int n    = blockIdx.x;
    const int tid  = threadIdx.x;
    const int lane = tid & 63;
    const int wid  = tid >> 6;
    const int flag = flagp[0];
    const int l15  = lane & 15;
    const int lg4  = lane >> 4;

    if (tid < 32) tebd_s[tid] = tebd[tid];
    if (tid == 0) ta_sh = atype[n];

    // ---------------- P-geom: geometry + zero g/kn/buf1 ----------------------
    {
        unsigned int* z0 = (unsigned int*)g16;
        unsigned int* z1 = (unsigned int*)kn_s;
        unsigned int* z2 = (unsigned int*)buf1;
        for (int i = tid; i < 128 * (BP/2); i += 1024){ z0[i] = 0; z1[i] = 0; z2[i] = 0; }
    }
    if (tid < 128){
        const int k = tid;
        if (k < NNEI){
            const int base = n * NNEI + k;
            const float rx = rij[base * 3 + 0];
            const float ry = rij[base * 3 + 1];
            const float rz = rij[base * 3 + 2];
            const float r  = sqrtf(rx * rx + ry * ry + rz * rz);
            float mval;
            if (flag == 1)      mval = (((const int*)nmask)[base] != 0) ? 1.0f : 0.0f;
            else if (flag == 2) mval = ((const float*)nmask)[base];
            else                mval = (((const unsigned char*)nmask)[base] != 0) ? 1.0f : 0.0f;
            float uu = (r - 0.5f) * (1.0f / 5.5f);
            uu = fminf(fmaxf(uu, 0.0f), 1.0f);
            const float sw   = uu * uu * uu * (-6.0f * uu * uu + 15.0f * uu - 10.0f) + 1.0f;
            const float invr = 1.0f / r;
            const float sr   = sw * invr * mval;
            const float hx = rx * invr, hy = ry * invr, hz = rz * invr;
            env_s[k * 4 + 0] = sr;
            env_s[k * 4 + 1] = sr * hx;
            env_s[k * 4 + 2] = sr * hy;
            env_s[k * 4 + 3] = sr * hz;
            rhat_s[k * 4 + 0] = hx; rhat_s[k * 4 + 1] = hy; rhat_s[k * 4 + 2] = hz;
            rhat_s[k * 4 + 3] = 0.0f;
            swm_s[k] = sw * mval;
            msk_s[k] = mval;
            ntype_s[k] = ntype[base];
        } else {
            env_s[k*4+0] = env_s[k*4+1] = env_s[k*4+2] = env_s[k*4+3] = 0.0f;
            rhat_s[k*4+0] = rhat_s[k*4+1] = rhat_s[k*4+2] = rhat_s[k*4+3] = 0.0f;
            swm_s[k] = 0.0f; msk_s[k] = 0.0f;
        }
    }
    __syncthreads();

    // ---------------- e1: h1 = tanh(x @ ew0 + eb0)  (f32 in vT space) --------
    {
        float* h1buf = (float*)vT_s;
        const int ta = ta_sh;
        for (int idx = tid; idx < NNEI * 25; idx += 1024){
            const int k = idx / 25, j = idx - k * 25;
            const float sr = env_s[k * 4];
            const float* tn = &tebd_s[ntype_s[k] * 8];
            const float* tc = &tebd_s[ta * 8];
            float a = eb0[j] + sr * ew0[j];
            #pragma unroll
            for (int i = 0; i < 8; ++i){
                a = fmaf(tn[i], ew0[(1 + i) * 25 + j], a);
                a = fmaf(tc[i], ew0[(9 + i) * 25 + j], a);
            }
            h1buf[k * 25 + j] = ftanh(a);
        }
    }
    __syncthreads();

    // ---------------- e2: h2 = tanh(h1 @ ew1 + eb1) + [h1,h1]  (bf16, buf1) --
    {
        const float* h1buf = (const float*)vT_s;
        for (int idx = tid; idx < NNEI * 50; idx += 1024){
            const int k = idx / 50, j = idx - k * 50;
            float a = eb1[j];
            const float* h1r = &h1buf[k * 25];
            #pragma unroll
            for (int i = 0; i < 25; ++i) a = fmaf(h1r[i], ew1[i * 50 + j], a);
            buf1[k * H2P + j] = f2bf(ftanh(a) + h1r[j >= 25 ? j - 25 : j]);
        }
    }
    __syncthreads();

    // ---------------- e3: g = (tanh(h2 @ ew2 + eb2) + [h2,h2]) * m  (MFMA) ---
    // also: zero vT (h1 dead), zero sums.
    {
        for (int job = wid; job < 56; job += 16){
            const int mt = job / 7, nt = job - mt * 7;
            bf16x8 a0 = *(const bf16x8*)&buf1[(mt*16 + l15) * H2P + 0*32 + lg4 * 8];
            bf16x8 a1 = *(const bf16x8*)&buf1[(mt*16 + l15) * H2P + 1*32 + lg4 * 8];
            bf16x8 b0 = *(const bf16x8*)(wsb + (size_t)(248 + nt*2 + 0) * 512 + lane * 8);
            bf16x8 b1 = *(const bf16x8*)(wsb + (size_t)(248 + nt*2 + 1) * 512 + lane * 8);
            f32x4 C = (f32x4){0.f, 0.f, 0.f, 0.f};
            C = __builtin_amdgcn_mfma_f32_16x16x32_bf16(a0, b0, C, 0, 0, 0);
            C = __builtin_amdgcn_mfma_f32_16x16x32_bf16(a1, b1, C, 0, 0, 0);
            const int j = nt * 16 + l15;
            if (j < MDIM){
                const float ebj = eb2[j];
                const int jr = (j >= 50) ? j - 50 : j;
                #pragma unroll
                for (int r = 0; r < 4; ++r){
                    const int row = mt * 16 + lg4 * 4 + r;
                    if (row < NNEI){
                        const float h2d = bf2f(buf1[row * H2P + jr]);
                        const float t = ftanh(C[r] + ebj) + h2d;
                        g16[row * BP + j] = f2bf(t * msk_s[row]);
                    }
                }
            }
        }
        unsigned int* zv = (unsigned int*)vT_s;
        for (int i = tid; i < 128 * (BP/2); i += 1024) zv[i] = 0;
        if (tid < 384) sums_s[tid] = 0.0f;
    }
    __syncthreads();

    // ---------------- Attention layers ----------------
    const float tinv = 0.08838834764831845f;  // 1/sqrt(128)
    const int mt_c = wid >> 1;        // core row-tile
    const int hh   = wid & 1;         // core col-half

    for (int l = 0; l < 2; ++l){
        // ---- A1: QKV. 48 jobs = (mat 3) x (nt 8) x (mt-half 2); 3 jobs/wave.
        for (int job = wid; job < 48; job += 16){
            const int mat = job >> 4;
            const int r2  = job & 15;
            const int nt  = r2 >> 1;
            const int mts = (r2 & 1) * 4;
            bf16x8 Bf[4];
            #pragma unroll
            for (int ks = 0; ks < 4; ++ks)
                Bf[ks] = *(const bf16x8*)(wsb + (size_t)(((l*3+mat)*8+nt)*4+ks) * 512 + lane * 8);
            f32x4 C[4];
            #pragma unroll
            for (int m4 = 0; m4 < 4; ++m4) C[m4] = (f32x4){0.f, 0.f, 0.f, 0.f};
            #pragma unroll
            for (int m4 = 0; m4 < 4; ++m4){
                const int mt = mts + m4;
                #pragma unroll
                for (int ks = 0; ks < 4; ++ks){
                    bf16x8 a = *(const bf16x8*)&g16[(mt*16 + l15) * BP + ks*32 + lg4 * 8];
                    C[m4] = __builtin_amdgcn_mfma_f32_16x16x32_bf16(a, Bf[ks], C[m4], 0, 0, 0);
                }
            }
            const int d = nt * 16 + l15;
            const float* BIAS = (mat == 0 ? bq : mat == 1 ? bk : bv) + l * ADIM;
            const float bias = BIAS[d];
            #pragma unroll
            for (int m4 = 0; m4 < 4; ++m4){
                const int qb = (mts + m4) * 16 + lg4 * 4;
                float v[4];
                #pragma unroll
                for (int r = 0; r < 4; ++r){
                    v[r] = C[m4][r] + bias;
                    float sq = v[r] * v[r];
                    sq += __shfl_xor(sq, 1, 64); sq += __shfl_xor(sq, 2, 64);
                    sq += __shfl_xor(sq, 4, 64); sq += __shfl_xor(sq, 8, 64);
                    if (l15 == 0 && qb + r < NNEI) atomicAdd(&sums_s[mat * 128 + qb + r], sq);
                }
                if (mat == 2){
                    if (qb < NNEI){
                        const unsigned int lo = (unsigned int)f2bf(v[0]) | ((unsigned int)f2bf(v[1]) << 16);
                        const unsigned int hi = (unsigned int)f2bf(v[2]) | ((unsigned int)f2bf(v[3]) << 16);
                        *(uint2*)&vT_s[d * BP + qb] = make_uint2(lo, hi);
                    }
                } else {
                    unsigned short* dstb = (mat == 0) ? buf1 : kn_s;
                    #pragma unroll
                    for (int r = 0; r < 4; ++r)
                        if (qb + r < NNEI) dstb[(qb + r) * BP + d] = f2bf(v[r]);
                }
            }
        }
        __syncthreads();  // A1 done: Q, K, V^T, sums ready

        // ---- A2: scores (own row-tile, own col-half) + e + partial row-sums
        float ev[4][4];       // [nt'][r]
        float swr[4], rqx[4], rqy[4], rqz[4];
        float rsum[4];
        {
            bf16x8 aq[4];
            #pragma unroll
            for (int ks = 0; ks < 4; ++ks)
                aq[ks] = *(const bf16x8*)&buf1[(mt_c*16 + l15) * BP + ks*32 + lg4 * 8];
            f32x4 Cs[4];
            #pragma unroll
            for (int t = 0; t < 4; ++t) Cs[t] = (f32x4){0.f, 0.f, 0.f, 0.f};
            #pragma unroll
            for (int t = 0; t < 4; ++t){
                const int nt = hh * 4 + t;
                #pragma unroll
                for (int ks = 0; ks < 4; ++ks){
                    bf16x8 b = *(const bf16x8*)&kn_s[(nt*16 + l15) * BP + ks*32 + lg4 * 8];
                    Cs[t] = __builtin_amdgcn_mfma_f32_16x16x32_bf16(aq[ks], b, Cs[t], 0, 0, 0);
                }
            }
            float mrow[4], qi[4];
            #pragma unroll
            for (int r = 0; r < 4; ++r){
                const int row = mt_c * 16 + lg4 * 4 + r;
                mrow[r] = msk_s[row];
                swr[r]  = swm_s[row];
                rqx[r] = rhat_s[row*4+0]; rqy[r] = rhat_s[row*4+1]; rqz[r] = rhat_s[row*4+2];
                qi[r] = 1.0f / fmaxf(sqrtf(sums_s[row]), 1e-12f);
            }
            float psr[4] = {0.f, 0.f, 0.f, 0.f};
            #pragma unroll
            for (int t = 0; t < 4; ++t){
                const int k = (hh * 4 + t) * 16 + l15;
                const float mk = msk_s[k];
                const float ki = 1.0f / fmaxf(sqrtf(sums_s[128 + k]), 1e-12f);
                #pragma unroll
                for (int r = 0; r < 4; ++r){
                    const float e = (mrow[r] != 0.0f && mk != 0.0f)
                                    ? __expf(Cs[t][r] * tinv * qi[r] * ki) : 0.0f;
                    ev[t][r] = e;
                    psr[r] += e;
                }
            }
            #pragma unroll
            for (int r = 0; r < 4; ++r){
                psr[r] += __shfl_xor(psr[r], 1, 64); psr[r] += __shfl_xor(psr[r], 2, 64);
                psr[r] += __shfl_xor(psr[r], 4, 64); psr[r] += __shfl_xor(psr[r], 8, 64);
                if (l15 == 0) psum_s[(mt_c * 16 + lg4 * 4 + r) * 2 + hh] = psr[r];
            }
        }
        __syncthreads();  // A2 done: partial sums ready

        // ---- A3: P = e * (swr/total) * (swm_k*vinv_k) * gate  -> buf1 -------
        {
            #pragma unroll
            for (int r = 0; r < 4; ++r){
                const int row = mt_c * 16 + lg4 * 4 + r;
                const float total = psum_s[row * 2] + psum_s[row * 2 + 1];
                rsum[r] = (total > 0.0f) ? swr[r] / total : 0.0f;
            }
            #pragma unroll
            for (int t = 0; t < 4; ++t){
                const int k = (hh * 4 + t) * 16 + l15;
                const float vi = 1.0f / fmaxf(sqrtf(sums_s[256 + k]), 1e-12f);
                const float colf = swm_s[k] * vi;
                const float gkx = rhat_s[k*4+0], gky = rhat_s[k*4+1], gkz = rhat_s[k*4+2];
                #pragma unroll
                for (int r = 0; r < 4; ++r){
                    const int row = mt_c * 16 + lg4 * 4 + r;
                    const float gate = rqx[r]*gkx + rqy[r]*gky + rqz[r]*gkz;
                    buf1[row * BP + k] = f2bf(ev[t][r] * rsum[r] * colf * gate);
                }
            }
        }
        __syncthreads();  // A3 done: P complete

        // ---- A4: O = P @ V^T (own rows, own d-half) -> buf1 -----------------
        {
            bf16x8 ap[4];
            #pragma unroll
            for (int ks = 0; ks < 4; ++ks)
                ap[ks] = *(const bf16x8*)&buf1[(mt_c*16 + l15) * BP + ks*32 + lg4 * 8];
            f32x4 Co[4];
            #pragma unroll
            for (int t = 0; t < 4; ++t) Co[t] = (f32x4){0.f, 0.f, 0.f, 0.f};
            #pragma unroll
            for (int t = 0; t < 4; ++t){
                const int nt = hh * 4 + t;
                #pragma unroll
                for (int ks = 0; ks < 4; ++ks){
                    bf16x8 b = *(const bf16x8*)&vT_s[(nt*16 + l15) * BP + ks*32 + lg4 * 8];
                    Co[t] = __builtin_amdgcn_mfma_f32_16x16x32_bf16(ap[ks], b, Co[t], 0, 0, 0);
                }
            }
            #pragma unroll
            for (int t = 0; t < 4; ++t){
                const int d = (hh * 4 + t) * 16 + l15;
                #pragma unroll
                for (int r = 0; r < 4; ++r){
                    const int row = mt_c * 16 + lg4 * 4 + r;
                    buf1[row * BP + d] = f2bf(Co[t][r]);
                }
            }
        }
        __syncthreads();  // A4 done: O complete

        // ---- A5: out-proj (own rows; h=0 -> nt 0..3, h=1 -> nt 4..6) + LN partials
        float val[4][4]; bool jokv[4];
        const int NTN = hh ? 3 : 4;
        {
            bf16x8 ao[4];
            #pragma unroll
            for (int ks = 0; ks < 4; ++ks)
                ao[ks] = *(const bf16x8*)&buf1[(mt_c*16 + l15) * BP + ks*32 + lg4 * 8];
            const float* BO = bo + l * MDIM;
            float sv[4] = {0,0,0,0}, sv2[4] = {0,0,0,0};
            for (int t = 0; t < NTN; ++t){
                const int nt = hh * 4 + t;
                f32x4 Cf = (f32x4){0.f, 0.f, 0.f, 0.f};
                #pragma unroll
                for (int ks = 0; ks < 4; ++ks){
                    bf16x8 b = *(const bf16x8*)(wsb + (size_t)(192 + (l*7+nt)*4 + ks) * 512 + lane * 8);
                    Cf = __builtin_amdgcn_mfma_f32_16x16x32_bf16(ao[ks], b, Cf, 0, 0, 0);
                }
                const int j = nt * 16 + l15;
                const bool jok = (j < MDIM);
                jokv[t] = jok;
                const float boj = jok ? BO[j] : 0.0f;
                #pragma unroll
                for (int r = 0; r < 4; ++r){
                    const float v = Cf[r] + boj;
                    val[t][r] = v;
                    if (jok){ sv[r] += v; sv2[r] += v * v; }
                }
            }
            #pragma unroll
            for (int r = 0; r < 4; ++r){
                sv[r]  += __shfl_xor(sv[r], 1, 64);  sv[r]  += __shfl_xor(sv[r], 2, 64);
                sv[r]  += __shfl_xor(sv[r], 4, 64);  sv[r]  += __shfl_xor(sv[r], 8, 64);
                sv2[r] += __shfl_xor(sv2[r], 1, 64); sv2[r] += __shfl_xor(sv2[r], 2, 64);
                sv2[r] += __shfl_xor(sv2[r], 4, 64); sv2[r] += __shfl_xor(sv2[r], 8, 64);
                if (l15 == 0){
                    const int row = mt_c * 16 + lg4 * 4 + r;
                    lnp_s[row * 4 + hh * 2 + 0] = sv[r];
                    lnp_s[row * 4 + hh * 2 + 1] = sv2[r];
                }
            }
        }
        __syncthreads();  // A5 done: LN partials ready

        // ---- A6: LayerNorm + residual into g16; zero sums for next layer ----
        {
            const float* LG = lng + l * MDIM;
            const float* LB = lnb + l * MDIM;
            #pragma unroll
            for (int r = 0; r < 4; ++r){
                const int row = mt_c * 16 + lg4 * 4 + r;
                const float sv  = lnp_s[row * 4 + 0] + lnp_s[row * 4 + 2];
                const float sv2 = lnp_s[row * 4 + 1] + lnp_s[row * 4 + 3];
                const float mu   = sv * 0.01f;
                const float var  = sv2 * 0.01f - mu * mu;
                const float rstd = rsqrtf(var + 1e-5f);
                if (row < NNEI){
                    for (int t = 0; t < NTN; ++t){
                        if (jokv[t]){
                            const int j = (hh * 4 + t) * 16 + l15;
                            const float go = bf2f(g16[row * BP + j]);
                            g16[row * BP + j] = f2bf(go + (val[t][r] - mu) * rstd * LG[j] + LB[j]);
                        }
                    }
                }
            }
            if (tid < 384) sums_s[tid] = 0.0f;
        }
        __syncthreads();  // end of layer
    }

    // ---------------- Final: gr = env^T g / NNEI ; d = gr^T gr[:, :16] -------
    for (int idx = tid; idx < 4 * MDIM; idx += 1024){
        const int c = idx / MDIM, mm = idx - c * MDIM;
        float a = 0.0f;
        for (int k = 0; k < NNEI; ++k)
            a = fmaf(env_s[k * 4 + c], bf2f(g16[k * BP + mm]), a);
        gr_s[c * MDIM + mm] = a * (1.0f / 120.0f);
    }
    __syncthreads();

    float* outp = out + (size_t)n * OUTD;
    for (int idx = tid; idx < MDIM * 16; idx += 1024){
        const int mm = idx >> 4, aa = idx & 15;
        float acc = 0.0f;
        #pragma unroll
        for (int c = 0; c < 4; ++c)
            acc = fmaf(gr_s[c * MDIM + mm], gr_s[c * MDIM + aa], acc);
        outp[idx] = acc;
    }
    if (tid < 8) outp[1600 + tid] = tebd_s[ta_sh * 8 + tid];
}

extern "C" void kernel_launch(void* const* d_in, const int* in_sizes, int n_in,
                              void* d_out, int out_size, void* d_ws, size_t ws_size,
                              hipStream_t stream) {
    const float* rij   = (const float*)d_in[0];
    const void*  nmask = d_in[1];
    const int*   atype = (const int*)d_in[2];
    const int*   ntype = (const int*)d_in[3];
    const float* tebd  = (const float*)d_in[4];
    const float* ew0 = (const float*)d_in[5];
    const float* eb0 = (const float*)d_in[6];
    const float* ew1 = (const float*)d_in[7];
    const float* eb1 = (const float*)d_in[8];
    const float* ew2 = (const float*)d_in[9];
    const float* eb2 = (const float*)d_in[10];
    const float* wq = (const float*)d_in[11];
    const float* bq = (const float*)d_in[12];
    const float* wk = (const float*)d_in[13];
    const float* bk = (const float*)d_in[14];
    const float* wv = (const float*)d_in[15];
    const float* bv = (const float*)d_in[16];
    const float* wo = (const float*)d_in[17];
    const float* bo = (const float*)d_in[18];
    const float* lng = (const float*)d_in[19];
    const float* lnb = (const float*)d_in[20];
    float* out = (float*)d_out;
    int* flag = (int*)d_ws;
    unsigned short* wsb = (unsigned short*)((char*)d_ws + 256);

    detect_mask_kernel<<<1, 64, 0, stream>>>((const unsigned char*)nmask, flag);
    prep_weights<<<262, 64, 0, stream>>>(wq, wk, wv, wo, ew2, wsb);
    dpa1_kernel<<<4096, 1024, 0, stream>>>(rij, nmask, atype, ntype, tebd,
                                           ew0, eb0, ew1, eb1, eb2,
                                           bq, bk, bv, bo, lng, lnb,
                                           out, flag, wsb);
}

// Round 5
// 1215.140 us; speedup vs baseline: 15.0576x; 1.0851x over previous
//
#include <hip/hip_runtime.h>

// DescrptDPA1 on gfx950 — MFMA version, 16 waves (1024 thr), no-max softmax,
// bf16 g master, MFMA embedding layer 3. R5: de-spilled A5/A6 (constant-bound
// unrolled loops + padded WO frags), relaxed launch bounds.
// NF=1, NLOC=4096, NNEI=120, TEBD=8, NTYPES=4, M=100, ATTN=128, NLAYER=2, AXIS=16.

#define NNEI 120
#define MDIM 100
#define ADIM 128
#define BP   136   // bf16 pitch (272B rows; 68 dw = 4 mod 32 banks, 16B aligned)
#define H2P  72    // bf16 pitch for h2 staging (144B; 36 dw = 4 mod 32)
#define OUTD 1608

typedef __attribute__((ext_vector_type(8))) short bf16x8;
typedef __attribute__((ext_vector_type(4))) float f32x4;

__device__ __forceinline__ float bf2f(unsigned short u){
    return __uint_as_float(((unsigned int)u) << 16);
}
__device__ __forceinline__ unsigned short f2bf(float f){
    unsigned int x = __float_as_uint(f);
    return (unsigned short)((x + 0x7fffu + ((x >> 16) & 1u)) >> 16);
}
__device__ __forceinline__ float ftanh(float x){
    return 1.0f - 2.0f / (__expf(2.0f * x) + 1.0f);
}

// nmask storage detection: 1 = int32 {0,1}, 2 = f32 {0.0,1.0}, 0 = byte bool
__global__ void detect_mask_kernel(const unsigned char* __restrict__ p,
                                   int* __restrict__ flag){
    if (blockIdx.x == 0 && threadIdx.x == 0){
        const unsigned int* u = (const unsigned int*)p;
        int alli = 1, allf = 1;
        for (int i = 0; i < 64; ++i){
            unsigned int w = u[i];
            if (!(w == 0u || w == 1u)) alli = 0;
            if (!(w == 0u || w == 0x3f800000u)) allf = 0;
        }
        flag[0] = alli ? 1 : (allf ? 2 : 0);
    }
}

// Pack weights into B-fragment order (bf16). Frag = [64 lanes][8 bf16] = 1024B.
// QKV: fid = ((l*3+mat)*8+nt)*4+ks               (0..191)
// WO:  fid = 192 + (l*8+nt)*4+ks, nt=0..7 padded (192..255)
// ew2: fid = 256 + nt*2 + ks                     (256..269)
__global__ void prep_weights(const float* __restrict__ wq, const float* __restrict__ wk,
                             const float* __restrict__ wv, const float* __restrict__ wo,
                             const float* __restrict__ ew2,
                             unsigned short* __restrict__ wsb){
    const int fid = blockIdx.x;
    const int lane = threadIdx.x;  // 64
    unsigned short* dst = wsb + (size_t)fid * 512 + lane * 8;
    if (fid < 192){
        const int l = fid / 96, rem = fid % 96, mat = rem / 32;
        const int r2 = rem % 32, nt = r2 / 4, ks = r2 % 4;
        const float* W = (mat == 0 ? wq : mat == 1 ? wk : wv) + l * MDIM * ADIM;
        const int nn = nt * 16 + (lane & 15);
        const int k0 = ks * 32 + (lane >> 4) * 8;
        #pragma unroll
        for (int i = 0; i < 8; ++i){
            const int kk = k0 + i;
            dst[i] = (kk < MDIM) ? f2bf(W[kk * ADIM + nn]) : (unsigned short)0;
        }
    } else if (fid < 256){
        const int f2 = fid - 192, l = f2 / 32, rem = f2 % 32, nt = rem / 4, ks = rem % 4;
        const float* W = wo + l * ADIM * MDIM;
        const int nn = nt * 16 + (lane & 15);
        const int k0 = ks * 32 + (lane >> 4) * 8;
        #pragma unroll
        for (int i = 0; i < 8; ++i){
            const int kk = k0 + i;
            dst[i] = (nn < MDIM) ? f2bf(W[kk * MDIM + nn]) : (unsigned short)0;
        }
    } else {
        const int f3 = fid - 256, nt = f3 >> 1, ks = f3 & 1;
        const int nn = nt * 16 + (lane & 15);
        const int k0 = ks * 32 + (lane >> 4) * 8;
        #pragma unroll
        for (int i = 0; i < 8; ++i){
            const int kk = k0 + i;
            dst[i] = (kk < 50 && nn < MDIM) ? f2bf(ew2[kk * MDIM + nn]) : (unsigned short)0;
        }
    }
}

__global__ __launch_bounds__(1024) void dpa1_kernel(
    const float* __restrict__ rij, const void* __restrict__ nmask,
    const int* __restrict__ atype, const int* __restrict__ ntype,
    const float* __restrict__ tebd,
    const float* __restrict__ ew0, const float* __restrict__ eb0,
    const float* __restrict__ ew1, const float* __restrict__ eb1,
    const float* __restrict__ eb2,
    const float* __restrict__ bq, const float* __restrict__ bk,
    const float* __restrict__ bv, const float* __restrict__ bo,
    const float* __restrict__ lng, const float* __restrict__ lnb,
    float* __restrict__ out, const int* __restrict__ flagp,
    const unsigned short* __restrict__ wsb)
{
    __shared__ __align__(16) unsigned short g16[128 * BP];   // 34,816 B bf16 g master
    __shared__ __align__(16) unsigned short buf1[128 * BP];  // h2 -> Q -> P -> O
    __shared__ __align__(16) unsigned short kn_s[128 * BP];  // K
    __shared__ __align__(16) unsigned short vT_s[128 * BP];  // h1(f32) -> V^T
    __shared__ float sums_s[384];          // |q|^2, |k|^2, |v|^2 per row
    __shared__ float psum_s[128 * 2];      // softmax partial sums per col-half
    __shared__ float lnp_s[128 * 4];       // LN partials (sv, sv2) per col-half
    __shared__ __align__(16) float env_s[128 * 4];
    __shared__ __align__(16) float rhat_s[128 * 4];
    __shared__ float swm_s[128];
    __shared__ float msk_s[128];
    __shared__ int   ntype_s[NNEI];
    __shared__ float tebd_s[32];
    __shared__ float gr_s[4 * MDIM];
    __shared__ int ta_sh;

    const int n    = blockIdx.x;
    const int tid  = threadIdx.x;
    const int lane = tid & 63;
    const int wid  = tid >> 6;
    const int flag = flagp[0];
    const int l15  = lane & 15;
    const int lg4  = lane >> 4;

    if (tid < 32) tebd_s[tid] = tebd[tid];
    if (tid == 0) ta_sh = atype[n];

    // ---------------- P-geom: geometry + zero g/kn/buf1 ----------------------
    {
        unsigned int* z0 = (unsigned int*)g16;
        unsigned int* z1 = (unsigned int*)kn_s;
        unsigned int* z2 = (unsigned int*)buf1;
        for (int i = tid; i < 128 * (BP/2); i += 1024){ z0[i] = 0; z1[i] = 0; z2[i] = 0; }
    }
    if (tid < 128){
        const int k = tid;
        if (k < NNEI){
            const int base = n * NNEI + k;
            const float rx = rij[base * 3 + 0];
            const float ry = rij[base * 3 + 1];
            const float rz = rij[base * 3 + 2];
            const float r  = sqrtf(rx * rx + ry * ry + rz * rz);
            float mval;
            if (flag == 1)      mval = (((const int*)nmask)[base] != 0) ? 1.0f : 0.0f;
            else if (flag == 2) mval = ((const float*)nmask)[base];
            else                mval = (((const unsigned char*)nmask)[base] != 0) ? 1.0f : 0.0f;
            float uu = (r - 0.5f) * (1.0f / 5.5f);
            uu = fminf(fmaxf(uu, 0.0f), 1.0f);
            const float sw   = uu * uu * uu * (-6.0f * uu * uu + 15.0f * uu - 10.0f) + 1.0f;
            const float invr = 1.0f / r;
            const float sr   = sw * invr * mval;
            const float hx = rx * invr, hy = ry * invr, hz = rz * invr;
            env_s[k * 4 + 0] = sr;
            env_s[k * 4 + 1] = sr * hx;
            env_s[k * 4 + 2] = sr * hy;
            env_s[k * 4 + 3] = sr * hz;
            rhat_s[k * 4 + 0] = hx; rhat_s[k * 4 + 1] = hy; rhat_s[k * 4 + 2] = hz;
            rhat_s[k * 4 + 3] = 0.0f;
            swm_s[k] = sw * mval;
            msk_s[k] = mval;
            ntype_s[k] = ntype[base];
        } else {
            env_s[k*4+0] = env_s[k*4+1] = env_s[k*4+2] = env_s[k*4+3] = 0.0f;
            rhat_s[k*4+0] = rhat_s[k*4+1] = rhat_s[k*4+2] = rhat_s[k*4+3] = 0.0f;
            swm_s[k] = 0.0f; msk_s[k] = 0.0f;
        }
    }
    __syncthreads();

    // ---------------- e1: h1 = tanh(x @ ew0 + eb0)  (f32 in vT space) --------
    {
        float* h1buf = (float*)vT_s;
        const int ta = ta_sh;
        for (int idx = tid; idx < NNEI * 25; idx += 1024){
            const int k = idx / 25, j = idx - k * 25;
            const float sr = env_s[k * 4];
            const float* tn = &tebd_s[ntype_s[k] * 8];
            const float* tc = &tebd_s[ta * 8];
            float a = eb0[j] + sr * ew0[j];
            #pragma unroll
            for (int i = 0; i < 8; ++i){
                a = fmaf(tn[i], ew0[(1 + i) * 25 + j], a);
                a = fmaf(tc[i], ew0[(9 + i) * 25 + j], a);
            }
            h1buf[k * 25 + j] = ftanh(a);
        }
    }
    __syncthreads();

    // ---------------- e2: h2 = tanh(h1 @ ew1 + eb1) + [h1,h1]  (bf16, buf1) --
    {
        const float* h1buf = (const float*)vT_s;
        for (int idx = tid; idx < NNEI * 50; idx += 1024){
            const int k = idx / 50, j = idx - k * 50;
            float a = eb1[j];
            const float* h1r = &h1buf[k * 25];
            #pragma unroll
            for (int i = 0; i < 25; ++i) a = fmaf(h1r[i], ew1[i * 50 + j], a);
            buf1[k * H2P + j] = f2bf(ftanh(a) + h1r[j >= 25 ? j - 25 : j]);
        }
    }
    __syncthreads();

    // ---------------- e3: g = (tanh(h2 @ ew2 + eb2) + [h2,h2]) * m  (MFMA) ---
    // also: zero vT (h1 dead), zero sums.
    {
        for (int job = wid; job < 56; job += 16){
            const int mt = job / 7, nt = job - mt * 7;
            bf16x8 a0 = *(const bf16x8*)&buf1[(mt*16 + l15) * H2P + 0*32 + lg4 * 8];
            bf16x8 a1 = *(const bf16x8*)&buf1[(mt*16 + l15) * H2P + 1*32 + lg4 * 8];
            bf16x8 b0 = *(const bf16x8*)(wsb + (size_t)(256 + nt*2 + 0) * 512 + lane * 8);
            bf16x8 b1 = *(const bf16x8*)(wsb + (size_t)(256 + nt*2 + 1) * 512 + lane * 8);
            f32x4 C = (f32x4){0.f, 0.f, 0.f, 0.f};
            C = __builtin_amdgcn_mfma_f32_16x16x32_bf16(a0, b0, C, 0, 0, 0);
            C = __builtin_amdgcn_mfma_f32_16x16x32_bf16(a1, b1, C, 0, 0, 0);
            const int j = nt * 16 + l15;
            if (j < MDIM){
                const float ebj = eb2[j];
                const int jr = (j >= 50) ? j - 50 : j;
                #pragma unroll
                for (int r = 0; r < 4; ++r){
                    const int row = mt * 16 + lg4 * 4 + r;
                    if (row < NNEI){
                        const float h2d = bf2f(buf1[row * H2P + jr]);
                        const float t = ftanh(C[r] + ebj) + h2d;
                        g16[row * BP + j] = f2bf(t * msk_s[row]);
                    }
                }
            }
        }
        unsigned int* zv = (unsigned int*)vT_s;
        for (int i = tid; i < 128 * (BP/2); i += 1024) zv[i] = 0;
        if (tid < 384) sums_s[tid] = 0.0f;
    }
    __syncthreads();

    // ---------------- Attention layers ----------------
    const float tinv = 0.08838834764831845f;  // 1/sqrt(128)
    const int mt_c = wid >> 1;        // core row-tile
    const int hh   = wid & 1;         // core col-half

    for (int l = 0; l < 2; ++l){
        // ---- A1: QKV. 48 jobs = (mat 3) x (nt 8) x (mt-half 2); 3 jobs/wave.
        for (int job = wid; job < 48; job += 16){
            const int mat = job >> 4;
            const int r2  = job & 15;
            const int nt  = r2 >> 1;
            const int mts = (r2 & 1) * 4;
            bf16x8 Bf[4];
            #pragma unroll
            for (int ks = 0; ks < 4; ++ks)
                Bf[ks] = *(const bf16x8*)(wsb + (size_t)(((l*3+mat)*8+nt)*4+ks) * 512 + lane * 8);
            f32x4 C[4];
            #pragma unroll
            for (int m4 = 0; m4 < 4; ++m4) C[m4] = (f32x4){0.f, 0.f, 0.f, 0.f};
            #pragma unroll
            for (int m4 = 0; m4 < 4; ++m4){
                const int mt = mts + m4;
                #pragma unroll
                for (int ks = 0; ks < 4; ++ks){
                    bf16x8 a = *(const bf16x8*)&g16[(mt*16 + l15) * BP + ks*32 + lg4 * 8];
                    C[m4] = __builtin_amdgcn_mfma_f32_16x16x32_bf16(a, Bf[ks], C[m4], 0, 0, 0);
                }
            }
            const int d = nt * 16 + l15;
            const float* BIAS = (mat == 0 ? bq : mat == 1 ? bk : bv) + l * ADIM;
            const float bias = BIAS[d];
            #pragma unroll
            for (int m4 = 0; m4 < 4; ++m4){
                const int qb = (mts + m4) * 16 + lg4 * 4;
                float v[4];
                #pragma unroll
                for (int r = 0; r < 4; ++r){
                    v[r] = C[m4][r] + bias;
                    float sq = v[r] * v[r];
                    sq += __shfl_xor(sq, 1, 64); sq += __shfl_xor(sq, 2, 64);
                    sq += __shfl_xor(sq, 4, 64); sq += __shfl_xor(sq, 8, 64);
                    if (l15 == 0 && qb + r < NNEI) atomicAdd(&sums_s[mat * 128 + qb + r], sq);
                }
                if (mat == 2){
                    if (qb < NNEI){
                        const unsigned int lo = (unsigned int)f2bf(v[0]) | ((unsigned int)f2bf(v[1]) << 16);
                        const unsigned int hi = (unsigned int)f2bf(v[2]) | ((unsigned int)f2bf(v[3]) << 16);
                        *(uint2*)&vT_s[d * BP + qb] = make_uint2(lo, hi);
                    }
                } else {
                    unsigned short* dstb = (mat == 0) ? buf1 : kn_s;
                    #pragma unroll
                    for (int r = 0; r < 4; ++r)
                        if (qb + r < NNEI) dstb[(qb + r) * BP + d] = f2bf(v[r]);
                }
            }
        }
        __syncthreads();  // A1 done: Q, K, V^T, sums ready

        // ---- A2: scores (own row-tile, own col-half) + e + partial row-sums
        float ev[4][4];       // [nt'][r]
        float swr[4], rqx[4], rqy[4], rqz[4];
        float rsum[4];
        {
            bf16x8 aq[4];
            #pragma unroll
            for (int ks = 0; ks < 4; ++ks)
                aq[ks] = *(const bf16x8*)&buf1[(mt_c*16 + l15) * BP + ks*32 + lg4 * 8];
            f32x4 Cs[4];
            #pragma unroll
            for (int t = 0; t < 4; ++t) Cs[t] = (f32x4){0.f, 0.f, 0.f, 0.f};
            #pragma unroll
            for (int t = 0; t < 4; ++t){
                const int nt = hh * 4 + t;
                #pragma unroll
                for (int ks = 0; ks < 4; ++ks){
                    bf16x8 b = *(const bf16x8*)&kn_s[(nt*16 + l15) * BP + ks*32 + lg4 * 8];
                    Cs[t] = __builtin_amdgcn_mfma_f32_16x16x32_bf16(aq[ks], b, Cs[t], 0, 0, 0);
                }
            }
            float mrow[4], qi[4];
            #pragma unroll
            for (int r = 0; r < 4; ++r){
                const int row = mt_c * 16 + lg4 * 4 + r;
                mrow[r] = msk_s[row];
                swr[r]  = swm_s[row];
                rqx[r] = rhat_s[row*4+0]; rqy[r] = rhat_s[row*4+1]; rqz[r] = rhat_s[row*4+2];
                qi[r] = 1.0f / fmaxf(sqrtf(sums_s[row]), 1e-12f);
            }
            float psr[4] = {0.f, 0.f, 0.f, 0.f};
            #pragma unroll
            for (int t = 0; t < 4; ++t){
                const int k = (hh * 4 + t) * 16 + l15;
                const float mk = msk_s[k];
                const float ki = 1.0f / fmaxf(sqrtf(sums_s[128 + k]), 1e-12f);
                #pragma unroll
                for (int r = 0; r < 4; ++r){
                    const float e = (mrow[r] != 0.0f && mk != 0.0f)
                                    ? __expf(Cs[t][r] * tinv * qi[r] * ki) : 0.0f;
                    ev[t][r] = e;
                    psr[r] += e;
                }
            }
            #pragma unroll
            for (int r = 0; r < 4; ++r){
                psr[r] += __shfl_xor(psr[r], 1, 64); psr[r] += __shfl_xor(psr[r], 2, 64);
                psr[r] += __shfl_xor(psr[r], 4, 64); psr[r] += __shfl_xor(psr[r], 8, 64);
                if (l15 == 0) psum_s[(mt_c * 16 + lg4 * 4 + r) * 2 + hh] = psr[r];
            }
        }
        __syncthreads();  // A2 done: partial sums ready

        // ---- A3: P = e * (swr/total) * (swm_k*vinv_k) * gate  -> buf1 -------
        {
            #pragma unroll
            for (int r = 0; r < 4; ++r){
                const int row = mt_c * 16 + lg4 * 4 + r;
                const float total = psum_s[row * 2] + psum_s[row * 2 + 1];
                rsum[r] = (total > 0.0f) ? swr[r] / total : 0.0f;
            }
            #pragma unroll
            for (int t = 0; t < 4; ++t){
                const int k = (hh * 4 + t) * 16 + l15;
                const float vi = 1.0f / fmaxf(sqrtf(sums_s[256 + k]), 1e-12f);
                const float colf = swm_s[k] * vi;
                const float gkx = rhat_s[k*4+0], gky = rhat_s[k*4+1], gkz = rhat_s[k*4+2];
                #pragma unroll
                for (int r = 0; r < 4; ++r){
                    const int row = mt_c * 16 + lg4 * 4 + r;
                    const float gate = rqx[r]*gkx + rqy[r]*gky + rqz[r]*gkz;
                    buf1[row * BP + k] = f2bf(ev[t][r] * rsum[r] * colf * gate);
                }
            }
        }
        __syncthreads();  // A3 done: P complete

        // ---- A4: O = P @ V^T (own rows, own d-half) -> buf1 -----------------
        {
            bf16x8 ap[4];
            #pragma unroll
            for (int ks = 0; ks < 4; ++ks)
                ap[ks] = *(const bf16x8*)&buf1[(mt_c*16 + l15) * BP + ks*32 + lg4 * 8];
            f32x4 Co[4];
            #pragma unroll
            for (int t = 0; t < 4; ++t) Co[t] = (f32x4){0.f, 0.f, 0.f, 0.f};
            #pragma unroll
            for (int t = 0; t < 4; ++t){
                const int nt = hh * 4 + t;
                #pragma unroll
                for (int ks = 0; ks < 4; ++ks){
                    bf16x8 b = *(const bf16x8*)&vT_s[(nt*16 + l15) * BP + ks*32 + lg4 * 8];
                    Co[t] = __builtin_amdgcn_mfma_f32_16x16x32_bf16(ap[ks], b, Co[t], 0, 0, 0);
                }
            }
            #pragma unroll
            for (int t = 0; t < 4; ++t){
                const int d = (hh * 4 + t) * 16 + l15;
                #pragma unroll
                for (int r = 0; r < 4; ++r){
                    const int row = mt_c * 16 + lg4 * 4 + r;
                    buf1[row * BP + d] = f2bf(Co[t][r]);
                }
            }
        }
        __syncthreads();  // A4 done: O complete

        // ---- A5: out-proj (own rows; nt = hh*4+t, t=0..3, nt=7 is zero-pad) -
        float val[4][4]; bool jokv[4];
        {
            bf16x8 ao[4];
            #pragma unroll
            for (int ks = 0; ks < 4; ++ks)
                ao[ks] = *(const bf16x8*)&buf1[(mt_c*16 + l15) * BP + ks*32 + lg4 * 8];
            const float* BO = bo + l * MDIM;
            float sv[4] = {0,0,0,0}, sv2[4] = {0,0,0,0};
            #pragma unroll
            for (int t = 0; t < 4; ++t){
                const int nt = hh * 4 + t;
                f32x4 Cf = (f32x4){0.f, 0.f, 0.f, 0.f};
                #pragma unroll
                for (int ks = 0; ks < 4; ++ks){
                    bf16x8 b = *(const bf16x8*)(wsb + (size_t)(192 + (l*8+nt)*4 + ks) * 512 + lane * 8);
                    Cf = __builtin_amdgcn_mfma_f32_16x16x32_bf16(ao[ks], b, Cf, 0, 0, 0);
                }
                const int j = nt * 16 + l15;
                const bool jok = (j < MDIM);
                jokv[t] = jok;
                const float boj = jok ? BO[j] : 0.0f;
                #pragma unroll
                for (int r = 0; r < 4; ++r){
                    const float v = Cf[r] + boj;
                    val[t][r] = v;
                    if (jok){ sv[r] += v; sv2[r] += v * v; }
                }
            }
            #pragma unroll
            for (int r = 0; r < 4; ++r){
                sv[r]  += __shfl_xor(sv[r], 1, 64);  sv[r]  += __shfl_xor(sv[r], 2, 64);
                sv[r]  += __shfl_xor(sv[r], 4, 64);  sv[r]  += __shfl_xor(sv[r], 8, 64);
                sv2[r] += __shfl_xor(sv2[r], 1, 64); sv2[r] += __shfl_xor(sv2[r], 2, 64);
                sv2[r] += __shfl_xor(sv2[r], 4, 64); sv2[r] += __shfl_xor(sv2[r], 8, 64);
                if (l15 == 0){
                    const int row = mt_c * 16 + lg4 * 4 + r;
                    lnp_s[row * 4 + hh * 2 + 0] = sv[r];
                    lnp_s[row * 4 + hh * 2 + 1] = sv2[r];
                }
            }
        }
        __syncthreads();  // A5 done: LN partials ready

        // ---- A6: LayerNorm + residual into g16; zero sums for next layer ----
        {
            const float* LG = lng + l * MDIM;
            const float* LB = lnb + l * MDIM;
            #pragma unroll
            for (int r = 0; r < 4; ++r){
                const int row = mt_c * 16 + lg4 * 4 + r;
                const float sv  = lnp_s[row * 4 + 0] + lnp_s[row * 4 + 2];
                const float sv2 = lnp_s[row * 4 + 1] + lnp_s[row * 4 + 3];
                const float mu   = sv * 0.01f;
                const float var  = sv2 * 0.01f - mu * mu;
                const float rstd = rsqrtf(var + 1e-5f);
                if (row < NNEI){
                    #pragma unroll
                    for (int t = 0; t < 4; ++t){
                        if (jokv[t]){
                            const int j = (hh * 4 + t) * 16 + l15;
                            const float go = bf2f(g16[row * BP + j]);
                            g16[row * BP + j] = f2bf(go + (val[t][r] - mu) * rstd * LG[j] + LB[j]);
                        }
                    }
                }
            }
            if (tid < 384) sums_s[tid] = 0.0f;
        }
        __syncthreads();  // end of layer
    }

    // ---------------- Final: gr = env^T g / NNEI ; d = gr^T gr[:, :16] -------
    for (int idx = tid; idx < 4 * MDIM; idx += 1024){
        const int c = idx / MDIM, mm = idx - c * MDIM;
        float a = 0.0f;
        for (int k = 0; k < NNEI; ++k)
            a = fmaf(env_s[k * 4 + c], bf2f(g16[k * BP + mm]), a);
        gr_s[c * MDIM + mm] = a * (1.0f / 120.0f);
    }
    __syncthreads();

    float* outp = out + (size_t)n * OUTD;
    for (int idx = tid; idx < MDIM * 16; idx += 1024){
        const int mm = idx >> 4, aa = idx & 15;
        float acc = 0.0f;
        #pragma unroll
        for (int c = 0; c < 4; ++c)
            acc = fmaf(gr_s[c * MDIM + mm], gr_s[c * MDIM + aa], acc);
        outp[idx] = acc;
    }
    if (tid < 8) outp[1600 + tid] = tebd_s[ta_sh * 8 + tid];
}

extern "C" void kernel_launch(void* const* d_in, const int* in_sizes, int n_in,
                              void* d_out, int out_size, void* d_ws, size_t ws_size,
                              hipStream_t stream) {
    const float* rij   = (const float*)d_in[0];
    const void*  nmask = d_in[1];
    const int*   atype = (const int*)d_in[2];
    const int*   ntype = (const int*)d_in[3];
    const float* tebd  = (const float*)d_in[4];
    const float* ew0 = (const float*)d_in[5];
    const float* eb0 = (const float*)d_in[6];
    const float* ew1 = (const float*)d_in[7];
    const float* eb1 = (const float*)d_in[8];
    const float* ew2 = (const float*)d_in[9];
    const float* eb2 = (const float*)d_in[10];
    const float* wq = (const float*)d_in[11];
    const float* bq = (const float*)d_in[12];
    const float* wk = (const float*)d_in[13];
    const float* bk = (const float*)d_in[14];
    const float* wv = (const float*)d_in[15];
    const float* bv = (const float*)d_in[16];
    const float* wo = (const float*)d_in[17];
    const float* bo = (const float*)d_in[18];
    const float* lng = (const float*)d_in[19];
    const float* lnb = (const float*)d_in[20];
    float* out = (float*)d_out;
    int* flag = (int*)d_ws;
    unsigned short* wsb = (unsigned short*)((char*)d_ws + 256);

    detect_mask_kernel<<<1, 64, 0, stream>>>((const unsigned char*)nmask, flag);
    prep_weights<<<270, 64, 0, stream>>>(wq, wk, wv, wo, ew2, wsb);
    dpa1_kernel<<<4096, 1024, 0, stream>>>(rij, nmask, atype, ntype, tebd,
                                           ew0, eb0, ew1, eb1, eb2,
                                           bq, bk, bv, bo, lng, lnb,
                                           out, flag, wsb);
}

// Round 6
// 1064.657 us; speedup vs baseline: 17.1859x; 1.1413x over previous
//
#include <hip/hip_runtime.h>

// DescrptDPA1 on gfx950 — R6: full-width core (8 core waves, 2 barriers/layer,
// in-wave softmax+LN, same-wave P/O handoffs). 16 waves (1024 thr).
// NF=1, NLOC=4096, NNEI=120, TEBD=8, NTYPES=4, M=100, ATTN=128, NLAYER=2, AXIS=16.

#define NNEI 120
#define MDIM 100
#define ADIM 128
#define BP   136   // bf16 pitch (272B rows; 68 dw = 4 mod 32 banks, 16B aligned)
#define H2P  72    // bf16 pitch for h2 staging
#define OUTD 1608

typedef __attribute__((ext_vector_type(8))) short bf16x8;
typedef __attribute__((ext_vector_type(4))) float f32x4;

__device__ __forceinline__ float bf2f(unsigned short u){
    return __uint_as_float(((unsigned int)u) << 16);
}
__device__ __forceinline__ unsigned short f2bf(float f){
    unsigned int x = __float_as_uint(f);
    return (unsigned short)((x + 0x7fffu + ((x >> 16) & 1u)) >> 16);
}
__device__ __forceinline__ float ftanh(float x){
    return 1.0f - 2.0f / (__expf(2.0f * x) + 1.0f);
}
__device__ __forceinline__ float red16(float v){
    v += __shfl_xor(v, 1, 64); v += __shfl_xor(v, 2, 64);
    v += __shfl_xor(v, 4, 64); v += __shfl_xor(v, 8, 64);
    return v;
}

// nmask storage detection: 1 = int32 {0,1}, 2 = f32 {0.0,1.0}, 0 = byte bool
__global__ void detect_mask_kernel(const unsigned char* __restrict__ p,
                                   int* __restrict__ flag){
    if (blockIdx.x == 0 && threadIdx.x == 0){
        const unsigned int* u = (const unsigned int*)p;
        int alli = 1, allf = 1;
        for (int i = 0; i < 64; ++i){
            unsigned int w = u[i];
            if (!(w == 0u || w == 1u)) alli = 0;
            if (!(w == 0u || w == 0x3f800000u)) allf = 0;
        }
        flag[0] = alli ? 1 : (allf ? 2 : 0);
    }
}

// Pack weights into B-fragment order (bf16). Frag = [64 lanes][8 bf16] = 1024B.
// QKV: fid = ((l*3+mat)*8+nt)*4+ks               (0..191)
// WO:  fid = 192 + (l*8+nt)*4+ks, nt=0..7 padded (192..255)
// ew2: fid = 256 + nt*2 + ks                     (256..269)
__global__ void prep_weights(const float* __restrict__ wq, const float* __restrict__ wk,
                             const float* __restrict__ wv, const float* __restrict__ wo,
                             const float* __restrict__ ew2,
                             unsigned short* __restrict__ wsb){
    const int fid = blockIdx.x;
    const int lane = threadIdx.x;  // 64
    unsigned short* dst = wsb + (size_t)fid * 512 + lane * 8;
    if (fid < 192){
        const int l = fid / 96, rem = fid % 96, mat = rem / 32;
        const int r2 = rem % 32, nt = r2 / 4, ks = r2 % 4;
        const float* W = (mat == 0 ? wq : mat == 1 ? wk : wv) + l * MDIM * ADIM;
        const int nn = nt * 16 + (lane & 15);
        const int k0 = ks * 32 + (lane >> 4) * 8;
        #pragma unroll
        for (int i = 0; i < 8; ++i){
            const int kk = k0 + i;
            dst[i] = (kk < MDIM) ? f2bf(W[kk * ADIM + nn]) : (unsigned short)0;
        }
    } else if (fid < 256){
        const int f2 = fid - 192, l = f2 / 32, rem = f2 % 32, nt = rem / 4, ks = rem % 4;
        const float* W = wo + l * ADIM * MDIM;
        const int nn = nt * 16 + (lane & 15);
        const int k0 = ks * 32 + (lane >> 4) * 8;
        #pragma unroll
        for (int i = 0; i < 8; ++i){
            const int kk = k0 + i;
            dst[i] = (nn < MDIM) ? f2bf(W[kk * MDIM + nn]) : (unsigned short)0;
        }
    } else {
        const int f3 = fid - 256, nt = f3 >> 1, ks = f3 & 1;
        const int nn = nt * 16 + (lane & 15);
        const int k0 = ks * 32 + (lane >> 4) * 8;
        #pragma unroll
        for (int i = 0; i < 8; ++i){
            const int kk = k0 + i;
            dst[i] = (kk < 50 && nn < MDIM) ? f2bf(ew2[kk * MDIM + nn]) : (unsigned short)0;
        }
    }
}

__global__ __launch_bounds__(1024) void dpa1_kernel(
    const float* __restrict__ rij, const void* __restrict__ nmask,
    const int* __restrict__ atype, const int* __restrict__ ntype,
    const float* __restrict__ tebd,
    const float* __restrict__ ew0, const float* __restrict__ eb0,
    const float* __restrict__ ew1, const float* __restrict__ eb1,
    const float* __restrict__ eb2,
    const float* __restrict__ bq, const float* __restrict__ bk,
    const float* __restrict__ bv, const float* __restrict__ bo,
    const float* __restrict__ lng, const float* __restrict__ lnb,
    float* __restrict__ out, const int* __restrict__ flagp,
    const unsigned short* __restrict__ wsb)
{
    __shared__ __align__(16) unsigned short g16[128 * BP];   // bf16 g master
    __shared__ __align__(16) unsigned short buf1[128 * BP];  // h2 -> Q -> P -> O
    __shared__ __align__(16) unsigned short kn_s[128 * BP];  // K
    __shared__ __align__(16) unsigned short vT_s[128 * BP];  // h1(f32) -> V^T
    __shared__ float sums_s[384];          // |q|^2, |k|^2, |v|^2 per row
    __shared__ __align__(16) float env_s[128 * 4];
    __shared__ __align__(16) float rhat_s[128 * 4];
    __shared__ float swm_s[128];
    __shared__ float msk_s[128];
    __shared__ int   ntype_s[NNEI];
    __shared__ float tebd_s[32];
    __shared__ float gr_s[4 * MDIM];
    __shared__ int ta_sh;

    const int n    = blockIdx.x;
    const int tid  = threadIdx.x;
    const int lane = tid & 63;
    const int wid  = tid >> 6;
    const int flag = flagp[0];
    const int l15  = lane & 15;
    const int lg4  = lane >> 4;

    if (tid < 32) tebd_s[tid] = tebd[tid];
    if (tid == 0) ta_sh = atype[n];

    // ---------------- P-geom: geometry + zero g16 ---------------------------
    {
        unsigned int* z0 = (unsigned int*)g16;
        for (int i = tid; i < 128 * (BP/2); i += 1024) z0[i] = 0;
    }
    if (tid < 128){
        const int k = tid;
        if (k < NNEI){
            const int base = n * NNEI + k;
            const float rx = rij[base * 3 + 0];
            const float ry = rij[base * 3 + 1];
            const float rz = rij[base * 3 + 2];
            const float r  = sqrtf(rx * rx + ry * ry + rz * rz);
            float mval;
            if (flag == 1)      mval = (((const int*)nmask)[base] != 0) ? 1.0f : 0.0f;
            else if (flag == 2) mval = ((const float*)nmask)[base];
            else                mval = (((const unsigned char*)nmask)[base] != 0) ? 1.0f : 0.0f;
            float uu = (r - 0.5f) * (1.0f / 5.5f);
            uu = fminf(fmaxf(uu, 0.0f), 1.0f);
            const float sw   = uu * uu * uu * (-6.0f * uu * uu + 15.0f * uu - 10.0f) + 1.0f;
            const float invr = 1.0f / r;
            const float sr   = sw * invr * mval;
            const float hx = rx * invr, hy = ry * invr, hz = rz * invr;
            env_s[k * 4 + 0] = sr;
            env_s[k * 4 + 1] = sr * hx;
            env_s[k * 4 + 2] = sr * hy;
            env_s[k * 4 + 3] = sr * hz;
            rhat_s[k * 4 + 0] = hx; rhat_s[k * 4 + 1] = hy; rhat_s[k * 4 + 2] = hz;
            rhat_s[k * 4 + 3] = 0.0f;
            swm_s[k] = sw * mval;
            msk_s[k] = mval;
            ntype_s[k] = ntype[base];
        } else {
            env_s[k*4+0] = env_s[k*4+1] = env_s[k*4+2] = env_s[k*4+3] = 0.0f;
            rhat_s[k*4+0] = rhat_s[k*4+1] = rhat_s[k*4+2] = rhat_s[k*4+3] = 0.0f;
            swm_s[k] = 0.0f; msk_s[k] = 0.0f;
        }
    }
    __syncthreads();

    // ---------------- e1: h1 = tanh(x @ ew0 + eb0)  (f32 in vT space) --------
    {
        float* h1buf = (float*)vT_s;
        const int ta = ta_sh;
        for (int idx = tid; idx < NNEI * 25; idx += 1024){
            const int k = idx / 25, j = idx - k * 25;
            const float sr = env_s[k * 4];
            const float* tn = &tebd_s[ntype_s[k] * 8];
            const float* tc = &tebd_s[ta * 8];
            float a = eb0[j] + sr * ew0[j];
            #pragma unroll
            for (int i = 0; i < 8; ++i){
                a = fmaf(tn[i], ew0[(1 + i) * 25 + j], a);
                a = fmaf(tc[i], ew0[(9 + i) * 25 + j], a);
            }
            h1buf[k * 25 + j] = ftanh(a);
        }
    }
    __syncthreads();

    // ---------------- e2: h2 = tanh(h1 @ ew1 + eb1) + [h1,h1]  (bf16, buf1) --
    {
        const float* h1buf = (const float*)vT_s;
        for (int idx = tid; idx < NNEI * 50; idx += 1024){
            const int k = idx / 50, j = idx - k * 50;
            float a = eb1[j];
            const float* h1r = &h1buf[k * 25];
            #pragma unroll
            for (int i = 0; i < 25; ++i) a = fmaf(h1r[i], ew1[i * 50 + j], a);
            buf1[k * H2P + j] = f2bf(ftanh(a) + h1r[j >= 25 ? j - 25 : j]);
        }
        // zero pad rows of h2 (rows 120..127) so e3 MFMA reads are defined
        if (tid < 8 * (H2P/2)){
            unsigned int* hz = (unsigned int*)buf1;
            const int row = 120 + tid / (H2P/2), c = tid % (H2P/2);
            hz[row * (H2P/2) + c] = 0;
        }
    }
    __syncthreads();

    // ---------------- e3: g = (tanh(h2 @ ew2 + eb2) + [h2,h2]) * m  (MFMA) ---
    {
        for (int job = wid; job < 56; job += 16){
            const int mt = job / 7, nt = job - mt * 7;
            bf16x8 a0 = *(const bf16x8*)&buf1[(mt*16 + l15) * H2P + 0*32 + lg4 * 8];
            bf16x8 a1 = *(const bf16x8*)&buf1[(mt*16 + l15) * H2P + 1*32 + lg4 * 8];
            bf16x8 b0 = *(const bf16x8*)(wsb + (size_t)(256 + nt*2 + 0) * 512 + lane * 8);
            bf16x8 b1 = *(const bf16x8*)(wsb + (size_t)(256 + nt*2 + 1) * 512 + lane * 8);
            f32x4 C = (f32x4){0.f, 0.f, 0.f, 0.f};
            C = __builtin_amdgcn_mfma_f32_16x16x32_bf16(a0, b0, C, 0, 0, 0);
            C = __builtin_amdgcn_mfma_f32_16x16x32_bf16(a1, b1, C, 0, 0, 0);
            const int j = nt * 16 + l15;
            if (j < MDIM){
                const float ebj = eb2[j];
                const int jr = (j >= 50) ? j - 50 : j;
                #pragma unroll
                for (int r = 0; r < 4; ++r){
                    const int row = mt * 16 + lg4 * 4 + r;
                    if (row < NNEI){
                        const float h2d = bf2f(buf1[row * H2P + jr]);
                        const float t = ftanh(C[r] + ebj) + h2d;
                        g16[row * BP + j] = f2bf(t * msk_s[row]);
                    }
                }
            }
        }
        if (tid < 384) sums_s[tid] = 0.0f;
    }
    __syncthreads();

    // ---------------- Attention layers ----------------
    const float tinv = 0.08838834764831845f;  // 1/sqrt(128)

    for (int l = 0; l < 2; ++l){
        // ===== A1: QKV =====
        // KV half-job j (0..31): mat = j>>4 (0=K,1=V), nt = (j>>1)&7, mh = j&1.
        // Core wave w (0..7): Q job (own mt=w, nt 0..7) + KV job j=w.
        // Non-core wave w (8..15): KV jobs j = 8 + (w-8)*3 + {0,1,2}.
        {
            if (wid < 8){
                // --- Q job: own 16 rows, full width ---
                bf16x8 ag[4];
                #pragma unroll
                for (int ks = 0; ks < 4; ++ks)
                    ag[ks] = *(const bf16x8*)&g16[(wid*16 + l15) * BP + ks*32 + lg4 * 8];
                float sqr[4] = {0.f, 0.f, 0.f, 0.f};
                #pragma unroll
                for (int nt = 0; nt < 8; ++nt){
                    f32x4 C = (f32x4){0.f, 0.f, 0.f, 0.f};
                    #pragma unroll
                    for (int ks = 0; ks < 4; ++ks){
                        bf16x8 b = *(const bf16x8*)(wsb + (size_t)(((l*3+0)*8+nt)*4+ks) * 512 + lane * 8);
                        C = __builtin_amdgcn_mfma_f32_16x16x32_bf16(ag[ks], b, C, 0, 0, 0);
                    }
                    const float bias = bq[l * ADIM + nt*16 + l15];
                    #pragma unroll
                    for (int r = 0; r < 4; ++r){
                        const float v = C[r] + bias;
                        buf1[(wid*16 + lg4*4 + r) * BP + nt*16 + l15] = f2bf(v);
                        sqr[r] = fmaf(v, v, sqr[r]);
                    }
                }
                #pragma unroll
                for (int r = 0; r < 4; ++r){
                    const float s = red16(sqr[r]);
                    if (l15 == 0) sums_s[wid*16 + lg4*4 + r] = s;
                }
            }
            // --- KV half-jobs ---
            const int njob = (wid < 8) ? 1 : 3;
            const int jbase = (wid < 8) ? wid : 8 + (wid - 8) * 3;
            for (int t = 0; t < njob; ++t){
                const int j = jbase + t;
                const int mat = j >> 4;          // 0=K, 1=V
                const int nt  = (j >> 1) & 7;
                const int mh  = j & 1;
                bf16x8 Bf[4];
                #pragma unroll
                for (int ks = 0; ks < 4; ++ks)
                    Bf[ks] = *(const bf16x8*)(wsb + (size_t)(((l*3+1+mat)*8+nt)*4+ks) * 512 + lane * 8);
                f32x4 C[4];
                #pragma unroll
                for (int m4 = 0; m4 < 4; ++m4) C[m4] = (f32x4){0.f, 0.f, 0.f, 0.f};
                #pragma unroll
                for (int m4 = 0; m4 < 4; ++m4){
                    const int mt = mh * 4 + m4;
                    #pragma unroll
                    for (int ks = 0; ks < 4; ++ks){
                        bf16x8 a = *(const bf16x8*)&g16[(mt*16 + l15) * BP + ks*32 + lg4 * 8];
                        C[m4] = __builtin_amdgcn_mfma_f32_16x16x32_bf16(a, Bf[ks], C[m4], 0, 0, 0);
                    }
                }
                const int d = nt * 16 + l15;
                const float bias = (mat ? bv : bk)[l * ADIM + d];
                #pragma unroll
                for (int m4 = 0; m4 < 4; ++m4){
                    const int qb = (mh*4 + m4) * 16 + lg4 * 4;
                    float v[4];
                    #pragma unroll
                    for (int r = 0; r < 4; ++r){
                        v[r] = C[m4][r] + bias;
                        const float s = red16(v[r] * v[r]);
                        if (l15 == 0) atomicAdd(&sums_s[(1 + mat) * 128 + qb + r], s);
                    }
                    if (mat){
                        const unsigned int lo = (unsigned int)f2bf(v[0]) | ((unsigned int)f2bf(v[1]) << 16);
                        const unsigned int hi = (unsigned int)f2bf(v[2]) | ((unsigned int)f2bf(v[3]) << 16);
                        *(uint2*)&vT_s[d * BP + qb] = make_uint2(lo, hi);
                    } else {
                        #pragma unroll
                        for (int r = 0; r < 4; ++r)
                            kn_s[(qb + r) * BP + d] = f2bf(v[r]);
                    }
                }
            }
        }
        __syncthreads();  // Q, K, V^T, sums ready

        // ===== Core: 8 waves, full width, barrier-free =====
        if (wid < 8){
            const int qrow = wid * 16;
            // scores
            bf16x8 aq[4];
            #pragma unroll
            for (int ks = 0; ks < 4; ++ks)
                aq[ks] = *(const bf16x8*)&buf1[(qrow + l15) * BP + ks*32 + lg4 * 8];
            f32x4 Cs[8];
            #pragma unroll
            for (int nt = 0; nt < 8; ++nt) Cs[nt] = (f32x4){0.f, 0.f, 0.f, 0.f};
            #pragma unroll
            for (int nt = 0; nt < 8; ++nt)
                #pragma unroll
                for (int ks = 0; ks < 4; ++ks){
                    bf16x8 b = *(const bf16x8*)&kn_s[(nt*16 + l15) * BP + ks*32 + lg4 * 8];
                    Cs[nt] = __builtin_amdgcn_mfma_f32_16x16x32_bf16(aq[ks], b, Cs[nt], 0, 0, 0);
                }
            // row factors
            float mrow[4], swr[4], qi[4], rqx[4], rqy[4], rqz[4];
            #pragma unroll
            for (int r = 0; r < 4; ++r){
                const int row = qrow + lg4 * 4 + r;
                mrow[r] = msk_s[row];
                swr[r]  = swm_s[row];
                rqx[r] = rhat_s[row*4+0]; rqy[r] = rhat_s[row*4+1]; rqz[r] = rhat_s[row*4+2];
                qi[r] = 1.0f / fmaxf(sqrtf(sums_s[row]), 1e-12f);
            }
            // exp (no-max: |score| <= 1/temp) + row partial sums
            float psr[4] = {0.f, 0.f, 0.f, 0.f};
            #pragma unroll
            for (int nt = 0; nt < 8; ++nt){
                const int k = nt * 16 + l15;
                const float mk = msk_s[k];
                const float ki = 1.0f / fmaxf(sqrtf(sums_s[128 + k]), 1e-12f);
                #pragma unroll
                for (int r = 0; r < 4; ++r){
                    const float e = (mrow[r] != 0.0f && mk != 0.0f)
                                    ? __expf(Cs[nt][r] * tinv * qi[r] * ki) : 0.0f;
                    Cs[nt][r] = e;
                    psr[r] += e;
                }
            }
            float rsum[4];
            #pragma unroll
            for (int r = 0; r < 4; ++r){
                const float tot = red16(psr[r]);
                rsum[r] = (tot > 0.0f) ? swr[r] / tot : 0.0f;
            }
            // P = e * rsum * colf * gate -> buf1 (own rows; overwrite Q)
            #pragma unroll
            for (int nt = 0; nt < 8; ++nt){
                const int k = nt * 16 + l15;
                const float vi = 1.0f / fmaxf(sqrtf(sums_s[256 + k]), 1e-12f);
                const float colf = swm_s[k] * vi;
                const float gkx = rhat_s[k*4+0], gky = rhat_s[k*4+1], gkz = rhat_s[k*4+2];
                #pragma unroll
                for (int r = 0; r < 4; ++r){
                    const float gate = rqx[r]*gkx + rqy[r]*gky + rqz[r]*gkz;
                    buf1[(qrow + lg4*4 + r) * BP + k] = f2bf(Cs[nt][r] * rsum[r] * colf * gate);
                }
            }
            asm volatile("s_waitcnt lgkmcnt(0)" ::: "memory");
            __builtin_amdgcn_sched_barrier(0);

            // PV: O = P @ V^T (own rows, full width)
            bf16x8 ap[4];
            #pragma unroll
            for (int ks = 0; ks < 4; ++ks)
                ap[ks] = *(const bf16x8*)&buf1[(qrow + l15) * BP + ks*32 + lg4 * 8];
            f32x4 Co[8];
            #pragma unroll
            for (int nt = 0; nt < 8; ++nt) Co[nt] = (f32x4){0.f, 0.f, 0.f, 0.f};
            #pragma unroll
            for (int nt = 0; nt < 8; ++nt)
                #pragma unroll
                for (int ks = 0; ks < 4; ++ks){
                    bf16x8 b = *(const bf16x8*)&vT_s[(nt*16 + l15) * BP + ks*32 + lg4 * 8];
                    Co[nt] = __builtin_amdgcn_mfma_f32_16x16x32_bf16(ap[ks], b, Co[nt], 0, 0, 0);
                }
            #pragma unroll
            for (int nt = 0; nt < 8; ++nt)
                #pragma unroll
                for (int r = 0; r < 4; ++r)
                    buf1[(qrow + lg4*4 + r) * BP + nt*16 + l15] = f2bf(Co[nt][r]);
            asm volatile("s_waitcnt lgkmcnt(0)" ::: "memory");
            __builtin_amdgcn_sched_barrier(0);

            // out-proj: own rows, nt 0..6
            bf16x8 ao[4];
            #pragma unroll
            for (int ks = 0; ks < 4; ++ks)
                ao[ks] = *(const bf16x8*)&buf1[(qrow + l15) * BP + ks*32 + lg4 * 8];
            const float* BO = bo + l * MDIM;
            float val[7][4];
            float sv[4] = {0,0,0,0}, sv2[4] = {0,0,0,0};
            #pragma unroll
            for (int t = 0; t < 7; ++t){
                f32x4 Cf = (f32x4){0.f, 0.f, 0.f, 0.f};
                #pragma unroll
                for (int ks = 0; ks < 4; ++ks){
                    bf16x8 b = *(const bf16x8*)(wsb + (size_t)(192 + (l*8+t)*4 + ks) * 512 + lane * 8);
                    Cf = __builtin_amdgcn_mfma_f32_16x16x32_bf16(ao[ks], b, Cf, 0, 0, 0);
                }
                const int jj = t * 16 + l15;
                const bool jok = (jj < MDIM);
                const float boj = jok ? BO[jj] : 0.0f;
                #pragma unroll
                for (int r = 0; r < 4; ++r){
                    const float v = Cf[r] + boj;
                    val[t][r] = v;
                    if (jok){ sv[r] += v; sv2[r] += v * v; }
                }
            }
            const float* LG = lng + l * MDIM;
            const float* LB = lnb + l * MDIM;
            #pragma unroll
            for (int r = 0; r < 4; ++r){
                const float svt  = red16(sv[r]);
                const float sv2t = red16(sv2[r]);
                const float mu   = svt * 0.01f;
                const float var  = sv2t * 0.01f - mu * mu;
                const float rstd = rsqrtf(var + 1e-5f);
                const int row = qrow + lg4 * 4 + r;
                if (row < NNEI){
                    #pragma unroll
                    for (int t = 0; t < 7; ++t){
                        const int jj = t * 16 + l15;
                        if (jj < MDIM){
                            const float go = bf2f(g16[row * BP + jj]);
                            g16[row * BP + jj] = f2bf(go + (val[t][r] - mu) * rstd * LG[jj] + LB[jj]);
                        }
                    }
                }
            }
            if (tid < 384) sums_s[tid] = 0.0f;  // threads 0..383 are in waves 0..5
        }
        __syncthreads();  // end of layer
    }

    // ---------------- Final: gr = env^T g / NNEI ; d = gr^T gr[:, :16] -------
    for (int idx = tid; idx < 4 * MDIM; idx += 1024){
        const int c = idx / MDIM, mm = idx - c * MDIM;
        float a = 0.0f;
        for (int k = 0; k < NNEI; ++k)
            a = fmaf(env_s[k * 4 + c], bf2f(g16[k * BP + mm]), a);
        gr_s[c * MDIM + mm] = a * (1.0f / 120.0f);
    }
    __syncthreads();

    float* outp = out + (size_t)n * OUTD;
    for (int idx = tid; idx < MDIM * 16; idx += 1024){
        const int mm = idx >> 4, aa = idx & 15;
        float acc = 0.0f;
        #pragma unroll
        for (int c = 0; c < 4; ++c)
            acc = fmaf(gr_s[c * MDIM + mm], gr_s[c * MDIM + aa], acc);
        outp[idx] = acc;
    }
    if (tid < 8) outp[1600 + tid] = tebd_s[ta_sh * 8 + tid];
}

extern "C" void kernel_launch(void* const* d_in, const int* in_sizes, int n_in,
                              void* d_out, int out_size, void* d_ws, size_t ws_size,
                              hipStream_t stream) {
    const float* rij   = (const float*)d_in[0];
    const void*  nmask = d_in[1];
    const int*   atype = (const int*)d_in[2];
    const int*   ntype = (const int*)d_in[3];
    const float* tebd  = (const float*)d_in[4];
    const float* ew0 = (const float*)d_in[5];
    const float* eb0 = (const float*)d_in[6];
    const float* ew1 = (const float*)d_in[7];
    const float* eb1 = (const float*)d_in[8];
    const float* ew2 = (const float*)d_in[9];
    const float* eb2 = (const float*)d_in[10];
    const float* wq = (const float*)d_in[11];
    const float* bq = (const float*)d_in[12];
    const float* wk = (const float*)d_in[13];
    const float* bk = (const float*)d_in[14];
    const float* wv = (const float*)d_in[15];
    const float* bv = (const float*)d_in[16];
    const float* wo = (const float*)d_in[17];
    const float* bo = (const float*)d_in[18];
    const float* lng = (const float*)d_in[19];
    const float* lnb = (const float*)d_in[20];
    float* out = (float*)d_out;
    int* flag = (int*)d_ws;
    unsigned short* wsb = (unsigned short*)((char*)d_ws + 256);

    detect_mask_kernel<<<1, 64, 0, stream>>>((const unsigned char*)nmask, flag);
    prep_weights<<<270, 64, 0, stream>>>(wq, wk, wv, wo, ew2, wsb);
    dpa1_kernel<<<4096, 1024, 0, stream>>>(rij, nmask, atype, ntype, tebd,
                                           ew0, eb0, ew1, eb1, eb2,
                                           bq, bk, bv, bo, lng, lnb,
                                           out, flag, wsb);
}

// Round 8
// 913.759 us; speedup vs baseline: 20.0240x; 1.1651x over previous
//
#include <hip/hip_runtime.h>

// DescrptDPA1 on gfx950 — R8: R7 transposed core + fix: e2 zero-fills h2
// staging cols 50..63 (stale-LDS NaN through e3 MFMA A-operand).
// 16 waves (1024 thr), 2 barriers/layer.
// NF=1, NLOC=4096, NNEI=120, TEBD=8, NTYPES=4, M=100, ATTN=128, NLAYER=2, AXIS=16.

#define NNEI 120
#define MDIM 100
#define ADIM 128
#define BP   136   // bf16 pitch (272B rows; 68 dw = 4 mod 32 banks, 16B aligned)
#define H2P  72    // bf16 pitch for h2 staging
#define OUTD 1608

typedef __attribute__((ext_vector_type(8))) short bf16x8;
typedef __attribute__((ext_vector_type(4))) float f32x4;

__device__ __forceinline__ float bf2f(unsigned short u){
    return __uint_as_float(((unsigned int)u) << 16);
}
__device__ __forceinline__ unsigned short f2bf(float f){
    unsigned int x = __float_as_uint(f);
    return (unsigned short)((x + 0x7fffu + ((x >> 16) & 1u)) >> 16);
}
__device__ __forceinline__ unsigned int cvtpk(float lo, float hi){
    unsigned int r;
    asm("v_cvt_pk_bf16_f32 %0, %1, %2" : "=v"(r) : "v"(lo), "v"(hi));
    return r;
}
__device__ __forceinline__ float ftanh(float x){
    return 1.0f - 2.0f / (__expf(2.0f * x) + 1.0f);
}
__device__ __forceinline__ float red16(float v){
    v += __shfl_xor(v, 1, 64); v += __shfl_xor(v, 2, 64);
    v += __shfl_xor(v, 4, 64); v += __shfl_xor(v, 8, 64);
    return v;
}

// nmask storage detection: 1 = int32 {0,1}, 2 = f32 {0.0,1.0}, 0 = byte bool
__global__ void detect_mask_kernel(const unsigned char* __restrict__ p,
                                   int* __restrict__ flag){
    if (blockIdx.x == 0 && threadIdx.x == 0){
        const unsigned int* u = (const unsigned int*)p;
        int alli = 1, allf = 1;
        for (int i = 0; i < 64; ++i){
            unsigned int w = u[i];
            if (!(w == 0u || w == 1u)) alli = 0;
            if (!(w == 0u || w == 0x3f800000u)) allf = 0;
        }
        flag[0] = alli ? 1 : (allf ? 2 : 0);
    }
}

// Pack weights (bf16). Frag = [64 lanes][8 bf16] = 1024B.
// QKV B-frags: fid = ((l*3+mat)*8+nt)*4+ks            (0..191)
//   elem(lane,i): n = nt*16+(lane&15), k = ks*32+(lane>>4)*8+i, val = W[k][n]
// WO A-frags:  fid = 192 + (l*8+jt)*4+ks              (192..255)
//   elem(lane,i): j = jt*16+(lane&15), d = ks*32+(lane>>4)*8+i, val = WO[d][j]
// ew2 B-frags: fid = 256 + nt*2 + ks                  (256..269)
__global__ void prep_weights(const float* __restrict__ wq, const float* __restrict__ wk,
                             const float* __restrict__ wv, const float* __restrict__ wo,
                             const float* __restrict__ ew2,
                             unsigned short* __restrict__ wsb){
    const int fid = blockIdx.x;
    const int lane = threadIdx.x;  // 64
    unsigned short* dst = wsb + (size_t)fid * 512 + lane * 8;
    if (fid < 192){
        const int l = fid / 96, rem = fid % 96, mat = rem / 32;
        const int r2 = rem % 32, nt = r2 / 4, ks = r2 % 4;
        const float* W = (mat == 0 ? wq : mat == 1 ? wk : wv) + l * MDIM * ADIM;
        const int nn = nt * 16 + (lane & 15);
        const int k0 = ks * 32 + (lane >> 4) * 8;
        #pragma unroll
        for (int i = 0; i < 8; ++i){
            const int kk = k0 + i;
            dst[i] = (kk < MDIM) ? f2bf(W[kk * ADIM + nn]) : (unsigned short)0;
        }
    } else if (fid < 256){
        const int f2 = fid - 192, l = f2 / 32, rem = f2 % 32, jt = rem / 4, ks = rem % 4;
        const float* W = wo + l * ADIM * MDIM;
        const int j = jt * 16 + (lane & 15);
        const int d0 = ks * 32 + (lane >> 4) * 8;
        #pragma unroll
        for (int i = 0; i < 8; ++i)
            dst[i] = (j < MDIM) ? f2bf(W[(d0 + i) * MDIM + j]) : (unsigned short)0;
    } else {
        const int f3 = fid - 256, nt = f3 >> 1, ks = f3 & 1;
        const int nn = nt * 16 + (lane & 15);
        const int k0 = ks * 32 + (lane >> 4) * 8;
        #pragma unroll
        for (int i = 0; i < 8; ++i){
            const int kk = k0 + i;
            dst[i] = (kk < 50 && nn < MDIM) ? f2bf(ew2[kk * MDIM + nn]) : (unsigned short)0;
        }
    }
}

__global__ __launch_bounds__(1024) void dpa1_kernel(
    const float* __restrict__ rij, const void* __restrict__ nmask,
    const int* __restrict__ atype, const int* __restrict__ ntype,
    const float* __restrict__ tebd,
    const float* __restrict__ ew0, const float* __restrict__ eb0,
    const float* __restrict__ ew1, const float* __restrict__ eb1,
    const float* __restrict__ eb2,
    const float* __restrict__ bq, const float* __restrict__ bk,
    const float* __restrict__ bv, const float* __restrict__ bo,
    const float* __restrict__ lng, const float* __restrict__ lnb,
    float* __restrict__ out, const int* __restrict__ flagp,
    const unsigned short* __restrict__ wsb)
{
    __shared__ __align__(16) unsigned short g16[128 * BP];   // bf16 g master
    __shared__ __align__(16) unsigned short buf1[128 * BP];  // h2 -> Qn
    __shared__ __align__(16) unsigned short kn_s[128 * BP];  // Kn (ki*tinv folded)
    __shared__ __align__(16) unsigned short vT_s[128 * BP];  // h1(f32) -> Vn^T (vinv*swm folded)
    __shared__ __align__(16) float env_s[128 * 4];
    __shared__ __align__(16) float rhat_s[128 * 4];
    __shared__ __align__(16) float swm_s[128];
    __shared__ __align__(16) float msk_s[128];
    __shared__ int   ntype_s[NNEI];
    __shared__ float tebd_s[32];
    __shared__ float gr_s[4 * MDIM];
    __shared__ int ta_sh;

    const int n    = blockIdx.x;
    const int tid  = threadIdx.x;
    const int lane = tid & 63;
    const int wid  = tid >> 6;
    const int flag = flagp[0];
    const int l15  = lane & 15;
    const int lg4  = lane >> 4;

    if (tid < 32) tebd_s[tid] = tebd[tid];
    if (tid == 0) ta_sh = atype[n];

    // ---------------- P-geom: geometry + zero g16 ---------------------------
    {
        unsigned int* z0 = (unsigned int*)g16;
        for (int i = tid; i < 128 * (BP/2); i += 1024) z0[i] = 0;
    }
    if (tid < 128){
        const int k = tid;
        if (k < NNEI){
            const int base = n * NNEI + k;
            const float rx = rij[base * 3 + 0];
            const float ry = rij[base * 3 + 1];
            const float rz = rij[base * 3 + 2];
            const float r  = sqrtf(rx * rx + ry * ry + rz * rz);
            float mval;
            if (flag == 1)      mval = (((const int*)nmask)[base] != 0) ? 1.0f : 0.0f;
            else if (flag == 2) mval = ((const float*)nmask)[base];
            else                mval = (((const unsigned char*)nmask)[base] != 0) ? 1.0f : 0.0f;
            float uu = (r - 0.5f) * (1.0f / 5.5f);
            uu = fminf(fmaxf(uu, 0.0f), 1.0f);
            const float sw   = uu * uu * uu * (-6.0f * uu * uu + 15.0f * uu - 10.0f) + 1.0f;
            const float invr = 1.0f / r;
            const float sr   = sw * invr * mval;
            const float hx = rx * invr, hy = ry * invr, hz = rz * invr;
            env_s[k * 4 + 0] = sr;
            env_s[k * 4 + 1] = sr * hx;
            env_s[k * 4 + 2] = sr * hy;
            env_s[k * 4 + 3] = sr * hz;
            rhat_s[k * 4 + 0] = hx; rhat_s[k * 4 + 1] = hy; rhat_s[k * 4 + 2] = hz;
            rhat_s[k * 4 + 3] = 0.0f;
            swm_s[k] = sw * mval;
            msk_s[k] = mval;
            ntype_s[k] = ntype[base];
        } else {
            env_s[k*4+0] = env_s[k*4+1] = env_s[k*4+2] = env_s[k*4+3] = 0.0f;
            rhat_s[k*4+0] = rhat_s[k*4+1] = rhat_s[k*4+2] = rhat_s[k*4+3] = 0.0f;
            swm_s[k] = 0.0f; msk_s[k] = 0.0f;
        }
    }
    __syncthreads();

    // ---------------- e1: h1 = tanh(x @ ew0 + eb0)  (f32 in vT space) --------
    {
        float* h1buf = (float*)vT_s;
        const int ta = ta_sh;
        for (int idx = tid; idx < NNEI * 25; idx += 1024){
            const int k = idx / 25, j = idx - k * 25;
            const float sr = env_s[k * 4];
            const float* tn = &tebd_s[ntype_s[k] * 8];
            const float* tc = &tebd_s[ta * 8];
            float a = eb0[j] + sr * ew0[j];
            #pragma unroll
            for (int i = 0; i < 8; ++i){
                a = fmaf(tn[i], ew0[(1 + i) * 25 + j], a);
                a = fmaf(tc[i], ew0[(9 + i) * 25 + j], a);
            }
            h1buf[k * 25 + j] = ftanh(a);
        }
    }
    __syncthreads();

    // ---------------- e2: h2 = tanh(h1 @ ew1 + eb1) + [h1,h1]  (bf16, buf1) --
    // FIX (R8): write full 64-wide rows — cols 50..63 get explicit zeros so the
    // e3 MFMA A-operand (K=64) never reads stale LDS (NaN x 0 = NaN in MFMA).
    {
        const float* h1buf = (const float*)vT_s;
        for (int idx = tid; idx < NNEI * 64; idx += 1024){
            const int k = idx >> 6, j = idx & 63;
            unsigned short w = 0;
            if (j < 50){
                float a = eb1[j];
                const float* h1r = &h1buf[k * 25];
                #pragma unroll
                for (int i = 0; i < 25; ++i) a = fmaf(h1r[i], ew1[i * 50 + j], a);
                w = f2bf(ftanh(a) + h1r[j >= 25 ? j - 25 : j]);
            }
            buf1[k * H2P + j] = w;
        }
        if (tid < 8 * (H2P/2)){
            unsigned int* hz = (unsigned int*)buf1;
            const int row = 120 + tid / (H2P/2), c = tid % (H2P/2);
            hz[row * (H2P/2) + c] = 0;
        }
    }
    __syncthreads();

    // ---------------- e3: g = (tanh(h2 @ ew2 + eb2) + [h2,h2]) * m  (MFMA) ---
    {
        for (int job = wid; job < 56; job += 16){
            const int mt = job / 7, nt = job - mt * 7;
            bf16x8 a0 = *(const bf16x8*)&buf1[(mt*16 + l15) * H2P + 0*32 + lg4 * 8];
            bf16x8 a1 = *(const bf16x8*)&buf1[(mt*16 + l15) * H2P + 1*32 + lg4 * 8];
            bf16x8 b0 = *(const bf16x8*)(wsb + (size_t)(256 + nt*2 + 0) * 512 + lane * 8);
            bf16x8 b1 = *(const bf16x8*)(wsb + (size_t)(256 + nt*2 + 1) * 512 + lane * 8);
            f32x4 C = (f32x4){0.f, 0.f, 0.f, 0.f};
            C = __builtin_amdgcn_mfma_f32_16x16x32_bf16(a0, b0, C, 0, 0, 0);
            C = __builtin_amdgcn_mfma_f32_16x16x32_bf16(a1, b1, C, 0, 0, 0);
            const int j = nt * 16 + l15;
            if (j < MDIM){
                const float ebj = eb2[j];
                const int jr = (j >= 50) ? j - 50 : j;
                #pragma unroll
                for (int r = 0; r < 4; ++r){
                    const int row = mt * 16 + lg4 * 4 + r;
                    if (row < NNEI){
                        const float h2d = bf2f(buf1[row * H2P + jr]);
                        const float t = ftanh(C[r] + ebj) + h2d;
                        g16[row * BP + j] = f2bf(t * msk_s[row]);
                    }
                }
            }
        }
    }
    __syncthreads();

    // ---------------- Attention layers ----------------
    const float tinv = 0.08838834764831845f;  // 1/sqrt(128)

    for (int l = 0; l < 2; ++l){
        // ===== A1: full-width jobs; norms folded at the producer =====
        if (wid < 8){
            // Q tile wid: Qn = (g@WQ + bq) * rsqrt(rowsum)
            bf16x8 ag[4];
            #pragma unroll
            for (int ks = 0; ks < 4; ++ks)
                ag[ks] = *(const bf16x8*)&g16[(wid*16 + l15) * BP + ks*32 + lg4 * 8];
            float qv[8][4];
            float sq[4] = {0.f, 0.f, 0.f, 0.f};
            #pragma unroll
            for (int nt = 0; nt < 8; ++nt){
                f32x4 C = (f32x4){0.f, 0.f, 0.f, 0.f};
                #pragma unroll
                for (int ks = 0; ks < 4; ++ks){
                    bf16x8 b = *(const bf16x8*)(wsb + (size_t)(((l*3+0)*8+nt)*4+ks) * 512 + lane * 8);
                    C = __builtin_amdgcn_mfma_f32_16x16x32_bf16(ag[ks], b, C, 0, 0, 0);
                }
                const float bias = bq[l * ADIM + nt*16 + l15];
                #pragma unroll
                for (int r = 0; r < 4; ++r){
                    qv[nt][r] = C[r] + bias;
                    sq[r] = fmaf(qv[nt][r], qv[nt][r], sq[r]);
                }
            }
            float qs[4];
            #pragma unroll
            for (int r = 0; r < 4; ++r)
                qs[r] = rsqrtf(fmaxf(red16(sq[r]), 1e-24f));
            #pragma unroll
            for (int nt = 0; nt < 8; ++nt)
                #pragma unroll
                for (int r = 0; r < 4; ++r)
                    buf1[(wid*16 + lg4*4 + r) * BP + nt*16 + l15] = f2bf(qv[nt][r] * qs[r]);
        } else {
            const int t = wid - 8;
            bf16x8 ag[4];
            #pragma unroll
            for (int ks = 0; ks < 4; ++ks)
                ag[ks] = *(const bf16x8*)&g16[(t*16 + l15) * BP + ks*32 + lg4 * 8];
            // K tile t: Kn = (g@WK + bk) * tinv * rsqrt(rowsum)
            {
                float kv[8][4];
                float sq[4] = {0.f, 0.f, 0.f, 0.f};
                #pragma unroll
                for (int nt = 0; nt < 8; ++nt){
                    f32x4 C = (f32x4){0.f, 0.f, 0.f, 0.f};
                    #pragma unroll
                    for (int ks = 0; ks < 4; ++ks){
                        bf16x8 b = *(const bf16x8*)(wsb + (size_t)(((l*3+1)*8+nt)*4+ks) * 512 + lane * 8);
                        C = __builtin_amdgcn_mfma_f32_16x16x32_bf16(ag[ks], b, C, 0, 0, 0);
                    }
                    const float bias = bk[l * ADIM + nt*16 + l15];
                    #pragma unroll
                    for (int r = 0; r < 4; ++r){
                        kv[nt][r] = C[r] + bias;
                        sq[r] = fmaf(kv[nt][r], kv[nt][r], sq[r]);
                    }
                }
                float kss[4];
                #pragma unroll
                for (int r = 0; r < 4; ++r)
                    kss[r] = tinv * rsqrtf(fmaxf(red16(sq[r]), 1e-24f));
                #pragma unroll
                for (int nt = 0; nt < 8; ++nt)
                    #pragma unroll
                    for (int r = 0; r < 4; ++r)
                        kn_s[(t*16 + lg4*4 + r) * BP + nt*16 + l15] = f2bf(kv[nt][r] * kss[r]);
            }
            // V tile t: Vn^T = ((g@WV + bv) * swm_k * rsqrt(rowsum))^T
            {
                float vv[8][4];
                float sq[4] = {0.f, 0.f, 0.f, 0.f};
                #pragma unroll
                for (int nt = 0; nt < 8; ++nt){
                    f32x4 C = (f32x4){0.f, 0.f, 0.f, 0.f};
                    #pragma unroll
                    for (int ks = 0; ks < 4; ++ks){
                        bf16x8 b = *(const bf16x8*)(wsb + (size_t)(((l*3+2)*8+nt)*4+ks) * 512 + lane * 8);
                        C = __builtin_amdgcn_mfma_f32_16x16x32_bf16(ag[ks], b, C, 0, 0, 0);
                    }
                    const float bias = bv[l * ADIM + nt*16 + l15];
                    #pragma unroll
                    for (int r = 0; r < 4; ++r){
                        vv[nt][r] = C[r] + bias;
                        sq[r] = fmaf(vv[nt][r], vv[nt][r], sq[r]);
                    }
                }
                float vs[4];
                #pragma unroll
                for (int r = 0; r < 4; ++r){
                    const int k = t*16 + lg4*4 + r;
                    vs[r] = swm_s[k] * rsqrtf(fmaxf(red16(sq[r]), 1e-24f));
                }
                #pragma unroll
                for (int nt = 0; nt < 8; ++nt){
                    const unsigned int lo = cvtpk(vv[nt][0]*vs[0], vv[nt][1]*vs[1]);
                    const unsigned int hi = cvtpk(vv[nt][2]*vs[2], vv[nt][3]*vs[3]);
                    *(uint2*)&vT_s[(nt*16 + l15) * BP + t*16 + lg4*4] = make_uint2(lo, hi);
                }
            }
        }
        __syncthreads();  // Qn, Kn, Vn^T ready

        // ===== Core (waves 0..7): transposed pipeline, all in-wave =====
        if (wid < 8){
            const int qt = wid;
            const int q  = qt * 16 + l15;       // this lane's q-row
            // B-frags of scores = Qn rows
            bf16x8 bqf[4];
            #pragma unroll
            for (int ks = 0; ks < 4; ++ks)
                bqf[ks] = *(const bf16x8*)&buf1[(qt*16 + l15) * BP + ks*32 + lg4 * 8];
            // Cs[kt] = K·Q^T : col=q(l15), row=k(lg4*4+r)
            f32x4 Cs[8];
            #pragma unroll
            for (int kt = 0; kt < 8; ++kt) Cs[kt] = (f32x4){0.f, 0.f, 0.f, 0.f};
            #pragma unroll
            for (int kt = 0; kt < 8; ++kt)
                #pragma unroll
                for (int ks = 0; ks < 4; ++ks){
                    bf16x8 a = *(const bf16x8*)&kn_s[(kt*16 + l15) * BP + ks*32 + lg4 * 8];
                    Cs[kt] = __builtin_amdgcn_mfma_f32_16x16x32_bf16(a, bqf[ks], Cs[kt], 0, 0, 0);
                }
            // softmax (no-max: |arg| <= tinv); e = exp * mask_k; in-lane + 2-shfl row sum
            const float swr = swm_s[q];
            const float4 rq = *(const float4*)&rhat_s[q * 4];
            float tot = 0.f;
            #pragma unroll
            for (int kt = 0; kt < 8; ++kt){
                const float4 mk = *(const float4*)&msk_s[kt*16 + lg4*4];
                #pragma unroll
                for (int r = 0; r < 4; ++r){
                    const float e = __expf(Cs[kt][r]) * ((const float*)&mk)[r];
                    Cs[kt][r] = e;
                    tot += e;
                }
            }
            tot += __shfl_xor(tot, 16, 64);
            tot += __shfl_xor(tot, 32, 64);
            const float rsum = (tot > 0.0f) ? swr / tot : 0.0f;
            // p = e * rsum * gate ; pack to bf16 pairs
            unsigned int pk0[8], pk1[8];
            #pragma unroll
            for (int kt = 0; kt < 8; ++kt){
                float p[4];
                #pragma unroll
                for (int r = 0; r < 4; ++r){
                    const int k = kt*16 + lg4*4 + r;
                    const float4 rk = *(const float4*)&rhat_s[k * 4];
                    const float gate = rq.x*rk.x + rq.y*rk.y + rq.z*rk.z;
                    p[r] = Cs[kt][r] * rsum * gate;
                }
                pk0[kt] = cvtpk(p[0], p[1]);
                pk1[kt] = cvtpk(p[2], p[3]);
            }
            // redistribute P -> B-frags of PV (col q, kdim k)
            const int srcA = (l15 + ((lane & 16) << 1)) << 2;  // (l15 + 32*(lg4&1))*4
            const int srcB = srcA + 64;
            const bool hi = (lane & 32) != 0;
            bf16x8 bpf[4];
            #pragma unroll
            for (int ks = 0; ks < 4; ++ks){
                const int e0 = __builtin_amdgcn_ds_bpermute(srcA, (int)pk0[2*ks]);
                const int f0 = __builtin_amdgcn_ds_bpermute(srcA, (int)pk0[2*ks+1]);
                const int e1 = __builtin_amdgcn_ds_bpermute(srcA, (int)pk1[2*ks]);
                const int f1 = __builtin_amdgcn_ds_bpermute(srcA, (int)pk1[2*ks+1]);
                const int e2 = __builtin_amdgcn_ds_bpermute(srcB, (int)pk0[2*ks]);
                const int f2 = __builtin_amdgcn_ds_bpermute(srcB, (int)pk0[2*ks+1]);
                const int e3 = __builtin_amdgcn_ds_bpermute(srcB, (int)pk1[2*ks]);
                const int f3 = __builtin_amdgcn_ds_bpermute(srcB, (int)pk1[2*ks+1]);
                uint4 w;
                w.x = hi ? (unsigned)f0 : (unsigned)e0;
                w.y = hi ? (unsigned)f1 : (unsigned)e1;
                w.z = hi ? (unsigned)f2 : (unsigned)e2;
                w.w = hi ? (unsigned)f3 : (unsigned)e3;
                bpf[ks] = *(bf16x8*)&w;
            }
            // PV: O^T = Vn^T · P^T : col=q, row=d
            f32x4 Co[8];
            #pragma unroll
            for (int dt = 0; dt < 8; ++dt) Co[dt] = (f32x4){0.f, 0.f, 0.f, 0.f};
            #pragma unroll
            for (int dt = 0; dt < 8; ++dt)
                #pragma unroll
                for (int ks = 0; ks < 4; ++ks){
                    bf16x8 a = *(const bf16x8*)&vT_s[(dt*16 + l15) * BP + ks*32 + lg4 * 8];
                    Co[dt] = __builtin_amdgcn_mfma_f32_16x16x32_bf16(a, bpf[ks], Co[dt], 0, 0, 0);
                }
            // redistribute O -> B-frags of out-proj (col q, kdim d)
            #pragma unroll
            for (int dt = 0; dt < 8; ++dt){
                pk0[dt] = cvtpk(Co[dt][0], Co[dt][1]);
                pk1[dt] = cvtpk(Co[dt][2], Co[dt][3]);
            }
            bf16x8 bof[4];
            #pragma unroll
            for (int ks = 0; ks < 4; ++ks){
                const int e0 = __builtin_amdgcn_ds_bpermute(srcA, (int)pk0[2*ks]);
                const int f0 = __builtin_amdgcn_ds_bpermute(srcA, (int)pk0[2*ks+1]);
                const int e1 = __builtin_amdgcn_ds_bpermute(srcA, (int)pk1[2*ks]);
                const int f1 = __builtin_amdgcn_ds_bpermute(srcA, (int)pk1[2*ks+1]);
                const int e2 = __builtin_amdgcn_ds_bpermute(srcB, (int)pk0[2*ks]);
                const int f2 = __builtin_amdgcn_ds_bpermute(srcB, (int)pk0[2*ks+1]);
                const int e3 = __builtin_amdgcn_ds_bpermute(srcB, (int)pk1[2*ks]);
                const int f3 = __builtin_amdgcn_ds_bpermute(srcB, (int)pk1[2*ks+1]);
                uint4 w;
                w.x = hi ? (unsigned)f0 : (unsigned)e0;
                w.y = hi ? (unsigned)f1 : (unsigned)e1;
                w.z = hi ? (unsigned)f2 : (unsigned)e2;
                w.w = hi ? (unsigned)f3 : (unsigned)e3;
                bof[ks] = *(bf16x8*)&w;
            }
            // out-proj: F^T = WO^T · O^T : col=q, row=j
            const float* BO = bo  + l * MDIM;
            const float* LG = lng + l * MDIM;
            const float* LB = lnb + l * MDIM;
            float val[7][4];
            float sv = 0.f, sv2 = 0.f;
            #pragma unroll
            for (int jt = 0; jt < 7; ++jt){
                f32x4 Cf = (f32x4){0.f, 0.f, 0.f, 0.f};
                #pragma unroll
                for (int ks = 0; ks < 4; ++ks){
                    bf16x8 a = *(const bf16x8*)(wsb + (size_t)(192 + (l*8+jt)*4 + ks) * 512 + lane * 8);
                    Cf = __builtin_amdgcn_mfma_f32_16x16x32_bf16(a, bof[ks], Cf, 0, 0, 0);
                }
                const bool jok = (jt < 6) || (lg4 == 0);
                float4 BO4 = jok ? *(const float4*)&BO[jt*16 + lg4*4] : make_float4(0,0,0,0);
                #pragma unroll
                for (int r = 0; r < 4; ++r){
                    const float v = Cf[r] + ((const float*)&BO4)[r];
                    val[jt][r] = v;
                    if (jok){ sv += v; sv2 += v * v; }
                }
            }
            sv  += __shfl_xor(sv, 16, 64);  sv  += __shfl_xor(sv, 32, 64);
            sv2 += __shfl_xor(sv2, 16, 64); sv2 += __shfl_xor(sv2, 32, 64);
            const float mu   = sv * 0.01f;
            const float var  = sv2 * 0.01f - mu * mu;
            const float rstd = rsqrtf(var + 1e-5f);
            // residual into g16 (paired-dword r-m-w), own q row
            if (q < NNEI){
                #pragma unroll
                for (int jt = 0; jt < 7; ++jt){
                    const bool jok = (jt < 6) || (lg4 == 0);
                    if (jok){
                        const int jb = jt*16 + lg4*4;
                        const float4 LG4 = *(const float4*)&LG[jb];
                        const float4 LB4 = *(const float4*)&LB[jb];
                        uint2 old = *(const uint2*)&g16[q * BP + jb];
                        float nv[4];
                        nv[0] = bf2f((unsigned short)(old.x & 0xffffu))  + (val[jt][0] - mu) * rstd * LG4.x + LB4.x;
                        nv[1] = bf2f((unsigned short)(old.x >> 16))      + (val[jt][1] - mu) * rstd * LG4.y + LB4.y;
                        nv[2] = bf2f((unsigned short)(old.y & 0xffffu))  + (val[jt][2] - mu) * rstd * LG4.z + LB4.z;
                        nv[3] = bf2f((unsigned short)(old.y >> 16))      + (val[jt][3] - mu) * rstd * LG4.w + LB4.w;
                        uint2 nw;
                        nw.x = cvtpk(nv[0], nv[1]);
                        nw.y = cvtpk(nv[2], nv[3]);
                        *(uint2*)&g16[q * BP + jb] = nw;
                    }
                }
            }
        }
        __syncthreads();  // end of layer
    }

    // ---------------- Final: gr = env^T g / NNEI ; d = gr^T gr[:, :16] -------
    for (int idx = tid; idx < 4 * MDIM; idx += 1024){
        const int c = idx / MDIM, mm = idx - c * MDIM;
        float a = 0.0f;
        for (int k = 0; k < NNEI; ++k)
            a = fmaf(env_s[k * 4 + c], bf2f(g16[k * BP + mm]), a);
        gr_s[c * MDIM + mm] = a * (1.0f / 120.0f);
    }
    __syncthreads();

    float* outp = out + (size_t)n * OUTD;
    for (int idx = tid; idx < MDIM * 16; idx += 1024){
        const int mm = idx >> 4, aa = idx & 15;
        float acc = 0.0f;
        #pragma unroll
        for (int c = 0; c < 4; ++c)
            acc = fmaf(gr_s[c * MDIM + mm], gr_s[c * MDIM + aa], acc);
        outp[idx] = acc;
    }
    if (tid < 8) outp[1600 + tid] = tebd_s[ta_sh * 8 + tid];
}

extern "C" void kernel_launch(void* const* d_in, const int* in_sizes, int n_in,
                              void* d_out, int out_size, void* d_ws, size_t ws_size,
                              hipStream_t stream) {
    const float* rij   = (const float*)d_in[0];
    const void*  nmask = d_in[1];
    const int*   atype = (const int*)d_in[2];
    const int*   ntype = (const int*)d_in[3];
    const float* tebd  = (const float*)d_in[4];
    const float* ew0 = (const float*)d_in[5];
    const float* eb0 = (const float*)d_in[6];
    const float* ew1 = (const float*)d_in[7];
    const float* eb1 = (const float*)d_in[8];
    const float* ew2 = (const float*)d_in[9];
    const float* eb2 = (const float*)d_in[10];
    const float* wq = (const float*)d_in[11];
    const float* bq = (const float*)d_in[12];
    const float* wk = (const float*)d_in[13];
    const float* bk = (const float*)d_in[14];
    const float* wv = (const float*)d_in[15];
    const float* bv = (const float*)d_in[16];
    const float* wo = (const float*)d_in[17];
    const float* bo = (const float*)d_in[18];
    const float* lng = (const float*)d_in[19];
    const float* lnb = (const float*)d_in[20];
    float* out = (float*)d_out;
    int* flag = (int*)d_ws;
    unsigned short* wsb = (unsigned short*)((char*)d_ws + 256);

    detect_mask_kernel<<<1, 64, 0, stream>>>((const unsigned char*)nmask, flag);
    prep_weights<<<270, 64, 0, stream>>>(wq, wk, wv, wo, ew2, wsb);
    dpa1_kernel<<<4096, 1024, 0, stream>>>(rij, nmask, atype, ntype, tebd,
                                           ew0, eb0, ew1, eb1, eb2,
                                           bq, bk, bv, bo, lng, lnb,
                                           out, flag, wsb);
}

// Round 9
// 912.459 us; speedup vs baseline: 20.0525x; 1.0014x over previous
//
#include <hip/hip_runtime.h>

// DescrptDPA1 on gfx950 — R9: R8 + __launch_bounds__(1024,4) so the register
// allocator targets the real occupancy (4 waves/EU, 128 VGPR cap) instead of
// spilling the core's live arrays to scratch (R8: 110 MB scratch writes).
// NF=1, NLOC=4096, NNEI=120, TEBD=8, NTYPES=4, M=100, ATTN=128, NLAYER=2, AXIS=16.

#define NNEI 120
#define MDIM 100
#define ADIM 128
#define BP   136   // bf16 pitch (272B rows; 68 dw = 4 mod 32 banks, 16B aligned)
#define H2P  72    // bf16 pitch for h2 staging
#define OUTD 1608

typedef __attribute__((ext_vector_type(8))) short bf16x8;
typedef __attribute__((ext_vector_type(4))) float f32x4;

__device__ __forceinline__ float bf2f(unsigned short u){
    return __uint_as_float(((unsigned int)u) << 16);
}
__device__ __forceinline__ unsigned short f2bf(float f){
    unsigned int x = __float_as_uint(f);
    return (unsigned short)((x + 0x7fffu + ((x >> 16) & 1u)) >> 16);
}
__device__ __forceinline__ unsigned int cvtpk(float lo, float hi){
    unsigned int r;
    asm("v_cvt_pk_bf16_f32 %0, %1, %2" : "=v"(r) : "v"(lo), "v"(hi));
    return r;
}
__device__ __forceinline__ float ftanh(float x){
    return 1.0f - 2.0f / (__expf(2.0f * x) + 1.0f);
}
__device__ __forceinline__ float red16(float v){
    v += __shfl_xor(v, 1, 64); v += __shfl_xor(v, 2, 64);
    v += __shfl_xor(v, 4, 64); v += __shfl_xor(v, 8, 64);
    return v;
}

// nmask storage detection: 1 = int32 {0,1}, 2 = f32 {0.0,1.0}, 0 = byte bool
__global__ void detect_mask_kernel(const unsigned char* __restrict__ p,
                                   int* __restrict__ flag){
    if (blockIdx.x == 0 && threadIdx.x == 0){
        const unsigned int* u = (const unsigned int*)p;
        int alli = 1, allf = 1;
        for (int i = 0; i < 64; ++i){
            unsigned int w = u[i];
            if (!(w == 0u || w == 1u)) alli = 0;
            if (!(w == 0u || w == 0x3f800000u)) allf = 0;
        }
        flag[0] = alli ? 1 : (allf ? 2 : 0);
    }
}

// Pack weights (bf16). Frag = [64 lanes][8 bf16] = 1024B.
// QKV B-frags: fid = ((l*3+mat)*8+nt)*4+ks            (0..191)
//   elem(lane,i): n = nt*16+(lane&15), k = ks*32+(lane>>4)*8+i, val = W[k][n]
// WO A-frags:  fid = 192 + (l*8+jt)*4+ks              (192..255)
//   elem(lane,i): j = jt*16+(lane&15), d = ks*32+(lane>>4)*8+i, val = WO[d][j]
// ew2 B-frags: fid = 256 + nt*2 + ks                  (256..269)
__global__ void prep_weights(const float* __restrict__ wq, const float* __restrict__ wk,
                             const float* __restrict__ wv, const float* __restrict__ wo,
                             const float* __restrict__ ew2,
                             unsigned short* __restrict__ wsb){
    const int fid = blockIdx.x;
    const int lane = threadIdx.x;  // 64
    unsigned short* dst = wsb + (size_t)fid * 512 + lane * 8;
    if (fid < 192){
        const int l = fid / 96, rem = fid % 96, mat = rem / 32;
        const int r2 = rem % 32, nt = r2 / 4, ks = r2 % 4;
        const float* W = (mat == 0 ? wq : mat == 1 ? wk : wv) + l * MDIM * ADIM;
        const int nn = nt * 16 + (lane & 15);
        const int k0 = ks * 32 + (lane >> 4) * 8;
        #pragma unroll
        for (int i = 0; i < 8; ++i){
            const int kk = k0 + i;
            dst[i] = (kk < MDIM) ? f2bf(W[kk * ADIM + nn]) : (unsigned short)0;
        }
    } else if (fid < 256){
        const int f2 = fid - 192, l = f2 / 32, rem = f2 % 32, jt = rem / 4, ks = rem % 4;
        const float* W = wo + l * ADIM * MDIM;
        const int j = jt * 16 + (lane & 15);
        const int d0 = ks * 32 + (lane >> 4) * 8;
        #pragma unroll
        for (int i = 0; i < 8; ++i)
            dst[i] = (j < MDIM) ? f2bf(W[(d0 + i) * MDIM + j]) : (unsigned short)0;
    } else {
        const int f3 = fid - 256, nt = f3 >> 1, ks = f3 & 1;
        const int nn = nt * 16 + (lane & 15);
        const int k0 = ks * 32 + (lane >> 4) * 8;
        #pragma unroll
        for (int i = 0; i < 8; ++i){
            const int kk = k0 + i;
            dst[i] = (kk < 50 && nn < MDIM) ? f2bf(ew2[kk * MDIM + nn]) : (unsigned short)0;
        }
    }
}

__global__ __launch_bounds__(1024, 4) void dpa1_kernel(
    const float* __restrict__ rij, const void* __restrict__ nmask,
    const int* __restrict__ atype, const int* __restrict__ ntype,
    const float* __restrict__ tebd,
    const float* __restrict__ ew0, const float* __restrict__ eb0,
    const float* __restrict__ ew1, const float* __restrict__ eb1,
    const float* __restrict__ eb2,
    const float* __restrict__ bq, const float* __restrict__ bk,
    const float* __restrict__ bv, const float* __restrict__ bo,
    const float* __restrict__ lng, const float* __restrict__ lnb,
    float* __restrict__ out, const int* __restrict__ flagp,
    const unsigned short* __restrict__ wsb)
{
    __shared__ __align__(16) unsigned short g16[128 * BP];   // bf16 g master
    __shared__ __align__(16) unsigned short buf1[128 * BP];  // h2 -> Qn
    __shared__ __align__(16) unsigned short kn_s[128 * BP];  // Kn (ki*tinv folded)
    __shared__ __align__(16) unsigned short vT_s[128 * BP];  // h1(f32) -> Vn^T (vinv*swm folded)
    __shared__ __align__(16) float env_s[128 * 4];
    __shared__ __align__(16) float rhat_s[128 * 4];
    __shared__ __align__(16) float swm_s[128];
    __shared__ __align__(16) float msk_s[128];
    __shared__ int   ntype_s[NNEI];
    __shared__ float tebd_s[32];
    __shared__ float gr_s[4 * MDIM];
    __shared__ int ta_sh;

    const int n    = blockIdx.x;
    const int tid  = threadIdx.x;
    const int lane = tid & 63;
    const int wid  = tid >> 6;
    const int flag = flagp[0];
    const int l15  = lane & 15;
    const int lg4  = lane >> 4;

    if (tid < 32) tebd_s[tid] = tebd[tid];
    if (tid == 0) ta_sh = atype[n];

    // ---------------- P-geom: geometry + zero g16 ---------------------------
    {
        unsigned int* z0 = (unsigned int*)g16;
        for (int i = tid; i < 128 * (BP/2); i += 1024) z0[i] = 0;
    }
    if (tid < 128){
        const int k = tid;
        if (k < NNEI){
            const int base = n * NNEI + k;
            const float rx = rij[base * 3 + 0];
            const float ry = rij[base * 3 + 1];
            const float rz = rij[base * 3 + 2];
            const float r  = sqrtf(rx * rx + ry * ry + rz * rz);
            float mval;
            if (flag == 1)      mval = (((const int*)nmask)[base] != 0) ? 1.0f : 0.0f;
            else if (flag == 2) mval = ((const float*)nmask)[base];
            else                mval = (((const unsigned char*)nmask)[base] != 0) ? 1.0f : 0.0f;
            float uu = (r - 0.5f) * (1.0f / 5.5f);
            uu = fminf(fmaxf(uu, 0.0f), 1.0f);
            const float sw   = uu * uu * uu * (-6.0f * uu * uu + 15.0f * uu - 10.0f) + 1.0f;
            const float invr = 1.0f / r;
            const float sr   = sw * invr * mval;
            const float hx = rx * invr, hy = ry * invr, hz = rz * invr;
            env_s[k * 4 + 0] = sr;
            env_s[k * 4 + 1] = sr * hx;
            env_s[k * 4 + 2] = sr * hy;
            env_s[k * 4 + 3] = sr * hz;
            rhat_s[k * 4 + 0] = hx; rhat_s[k * 4 + 1] = hy; rhat_s[k * 4 + 2] = hz;
            rhat_s[k * 4 + 3] = 0.0f;
            swm_s[k] = sw * mval;
            msk_s[k] = mval;
            ntype_s[k] = ntype[base];
        } else {
            env_s[k*4+0] = env_s[k*4+1] = env_s[k*4+2] = env_s[k*4+3] = 0.0f;
            rhat_s[k*4+0] = rhat_s[k*4+1] = rhat_s[k*4+2] = rhat_s[k*4+3] = 0.0f;
            swm_s[k] = 0.0f; msk_s[k] = 0.0f;
        }
    }
    __syncthreads();

    // ---------------- e1: h1 = tanh(x @ ew0 + eb0)  (f32 in vT space) --------
    {
        float* h1buf = (float*)vT_s;
        const int ta = ta_sh;
        for (int idx = tid; idx < NNEI * 25; idx += 1024){
            const int k = idx / 25, j = idx - k * 25;
            const float sr = env_s[k * 4];
            const float* tn = &tebd_s[ntype_s[k] * 8];
            const float* tc = &tebd_s[ta * 8];
            float a = eb0[j] + sr * ew0[j];
            #pragma unroll
            for (int i = 0; i < 8; ++i){
                a = fmaf(tn[i], ew0[(1 + i) * 25 + j], a);
                a = fmaf(tc[i], ew0[(9 + i) * 25 + j], a);
            }
            h1buf[k * 25 + j] = ftanh(a);
        }
    }
    __syncthreads();

    // ---------------- e2: h2 = tanh(h1 @ ew1 + eb1) + [h1,h1]  (bf16, buf1) --
    // Full 64-wide rows: cols 50..63 explicit zeros (e3 A-operand reads K=64).
    {
        const float* h1buf = (const float*)vT_s;
        for (int idx = tid; idx < NNEI * 64; idx += 1024){
            const int k = idx >> 6, j = idx & 63;
            unsigned short w = 0;
            if (j < 50){
                float a = eb1[j];
                const float* h1r = &h1buf[k * 25];
                #pragma unroll
                for (int i = 0; i < 25; ++i) a = fmaf(h1r[i], ew1[i * 50 + j], a);
                w = f2bf(ftanh(a) + h1r[j >= 25 ? j - 25 : j]);
            }
            buf1[k * H2P + j] = w;
        }
        if (tid < 8 * (H2P/2)){
            unsigned int* hz = (unsigned int*)buf1;
            const int row = 120 + tid / (H2P/2), c = tid % (H2P/2);
            hz[row * (H2P/2) + c] = 0;
        }
    }
    __syncthreads();

    // ---------------- e3: g = (tanh(h2 @ ew2 + eb2) + [h2,h2]) * m  (MFMA) ---
    {
        for (int job = wid; job < 56; job += 16){
            const int mt = job / 7, nt = job - mt * 7;
            bf16x8 a0 = *(const bf16x8*)&buf1[(mt*16 + l15) * H2P + 0*32 + lg4 * 8];
            bf16x8 a1 = *(const bf16x8*)&buf1[(mt*16 + l15) * H2P + 1*32 + lg4 * 8];
            bf16x8 b0 = *(const bf16x8*)(wsb + (size_t)(256 + nt*2 + 0) * 512 + lane * 8);
            bf16x8 b1 = *(const bf16x8*)(wsb + (size_t)(256 + nt*2 + 1) * 512 + lane * 8);
            f32x4 C = (f32x4){0.f, 0.f, 0.f, 0.f};
            C = __builtin_amdgcn_mfma_f32_16x16x32_bf16(a0, b0, C, 0, 0, 0);
            C = __builtin_amdgcn_mfma_f32_16x16x32_bf16(a1, b1, C, 0, 0, 0);
            const int j = nt * 16 + l15;
            if (j < MDIM){
                const float ebj = eb2[j];
                const int jr = (j >= 50) ? j - 50 : j;
                #pragma unroll
                for (int r = 0; r < 4; ++r){
                    const int row = mt * 16 + lg4 * 4 + r;
                    if (row < NNEI){
                        const float h2d = bf2f(buf1[row * H2P + jr]);
                        const float t = ftanh(C[r] + ebj) + h2d;
                        g16[row * BP + j] = f2bf(t * msk_s[row]);
                    }
                }
            }
        }
    }
    __syncthreads();

    // ---------------- Attention layers ----------------
    const float tinv = 0.08838834764831845f;  // 1/sqrt(128)

    for (int l = 0; l < 2; ++l){
        // ===== A1: full-width jobs; norms folded at the producer =====
        if (wid < 8){
            // Q tile wid: Qn = (g@WQ + bq) * rsqrt(rowsum)
            bf16x8 ag[4];
            #pragma unroll
            for (int ks = 0; ks < 4; ++ks)
                ag[ks] = *(const bf16x8*)&g16[(wid*16 + l15) * BP + ks*32 + lg4 * 8];
            float qv[8][4];
            float sq[4] = {0.f, 0.f, 0.f, 0.f};
            #pragma unroll
            for (int nt = 0; nt < 8; ++nt){
                f32x4 C = (f32x4){0.f, 0.f, 0.f, 0.f};
                #pragma unroll
                for (int ks = 0; ks < 4; ++ks){
                    bf16x8 b = *(const bf16x8*)(wsb + (size_t)(((l*3+0)*8+nt)*4+ks) * 512 + lane * 8);
                    C = __builtin_amdgcn_mfma_f32_16x16x32_bf16(ag[ks], b, C, 0, 0, 0);
                }
                const float bias = bq[l * ADIM + nt*16 + l15];
                #pragma unroll
                for (int r = 0; r < 4; ++r){
                    qv[nt][r] = C[r] + bias;
                    sq[r] = fmaf(qv[nt][r], qv[nt][r], sq[r]);
                }
            }
            float qs[4];
            #pragma unroll
            for (int r = 0; r < 4; ++r)
                qs[r] = rsqrtf(fmaxf(red16(sq[r]), 1e-24f));
            #pragma unroll
            for (int nt = 0; nt < 8; ++nt)
                #pragma unroll
                for (int r = 0; r < 4; ++r)
                    buf1[(wid*16 + lg4*4 + r) * BP + nt*16 + l15] = f2bf(qv[nt][r] * qs[r]);
        } else {
            const int t = wid - 8;
            bf16x8 ag[4];
            #pragma unroll
            for (int ks = 0; ks < 4; ++ks)
                ag[ks] = *(const bf16x8*)&g16[(t*16 + l15) * BP + ks*32 + lg4 * 8];
            // K tile t: Kn = (g@WK + bk) * tinv * rsqrt(rowsum)
            {
                float kv[8][4];
                float sq[4] = {0.f, 0.f, 0.f, 0.f};
                #pragma unroll
                for (int nt = 0; nt < 8; ++nt){
                    f32x4 C = (f32x4){0.f, 0.f, 0.f, 0.f};
                    #pragma unroll
                    for (int ks = 0; ks < 4; ++ks){
                        bf16x8 b = *(const bf16x8*)(wsb + (size_t)(((l*3+1)*8+nt)*4+ks) * 512 + lane * 8);
                        C = __builtin_amdgcn_mfma_f32_16x16x32_bf16(ag[ks], b, C, 0, 0, 0);
                    }
                    const float bias = bk[l * ADIM + nt*16 + l15];
                    #pragma unroll
                    for (int r = 0; r < 4; ++r){
                        kv[nt][r] = C[r] + bias;
                        sq[r] = fmaf(kv[nt][r], kv[nt][r], sq[r]);
                    }
                }
                float kss[4];
                #pragma unroll
                for (int r = 0; r < 4; ++r)
                    kss[r] = tinv * rsqrtf(fmaxf(red16(sq[r]), 1e-24f));
                #pragma unroll
                for (int nt = 0; nt < 8; ++nt)
                    #pragma unroll
                    for (int r = 0; r < 4; ++r)
                        kn_s[(t*16 + lg4*4 + r) * BP + nt*16 + l15] = f2bf(kv[nt][r] * kss[r]);
            }
            // V tile t: Vn^T = ((g@WV + bv) * swm_k * rsqrt(rowsum))^T
            {
                float vv[8][4];
                float sq[4] = {0.f, 0.f, 0.f, 0.f};
                #pragma unroll
                for (int nt = 0; nt < 8; ++nt){
                    f32x4 C = (f32x4){0.f, 0.f, 0.f, 0.f};
                    #pragma unroll
                    for (int ks = 0; ks < 4; ++ks){
                        bf16x8 b = *(const bf16x8*)(wsb + (size_t)(((l*3+2)*8+nt)*4+ks) * 512 + lane * 8);
                        C = __builtin_amdgcn_mfma_f32_16x16x32_bf16(ag[ks], b, C, 0, 0, 0);
                    }
                    const float bias = bv[l * ADIM + nt*16 + l15];
                    #pragma unroll
                    for (int r = 0; r < 4; ++r){
                        vv[nt][r] = C[r] + bias;
                        sq[r] = fmaf(vv[nt][r], vv[nt][r], sq[r]);
                    }
                }
                float vs[4];
                #pragma unroll
                for (int r = 0; r < 4; ++r){
                    const int k = t*16 + lg4*4 + r;
                    vs[r] = swm_s[k] * rsqrtf(fmaxf(red16(sq[r]), 1e-24f));
                }
                #pragma unroll
                for (int nt = 0; nt < 8; ++nt){
                    const unsigned int lo = cvtpk(vv[nt][0]*vs[0], vv[nt][1]*vs[1]);
                    const unsigned int hi = cvtpk(vv[nt][2]*vs[2], vv[nt][3]*vs[3]);
                    *(uint2*)&vT_s[(nt*16 + l15) * BP + t*16 + lg4*4] = make_uint2(lo, hi);
                }
            }
        }
        __syncthreads();  // Qn, Kn, Vn^T ready

        // ===== Core (waves 0..7): transposed pipeline, all in-wave =====
        if (wid < 8){
            const int qt = wid;
            const int q  = qt * 16 + l15;       // this lane's q-row
            // B-frags of scores = Qn rows
            bf16x8 bqf[4];
            #pragma unroll
            for (int ks = 0; ks < 4; ++ks)
                bqf[ks] = *(const bf16x8*)&buf1[(qt*16 + l15) * BP + ks*32 + lg4 * 8];
            // Cs[kt] = K·Q^T : col=q(l15), row=k(lg4*4+r)
            f32x4 Cs[8];
            #pragma unroll
            for (int kt = 0; kt < 8; ++kt) Cs[kt] = (f32x4){0.f, 0.f, 0.f, 0.f};
            #pragma unroll
            for (int kt = 0; kt < 8; ++kt)
                #pragma unroll
                for (int ks = 0; ks < 4; ++ks){
                    bf16x8 a = *(const bf16x8*)&kn_s[(kt*16 + l15) * BP + ks*32 + lg4 * 8];
                    Cs[kt] = __builtin_amdgcn_mfma_f32_16x16x32_bf16(a, bqf[ks], Cs[kt], 0, 0, 0);
                }
            // softmax (no-max: |arg| <= tinv); e = exp * mask_k; in-lane + 2-shfl row sum
            const float swr = swm_s[q];
            const float4 rq = *(const float4*)&rhat_s[q * 4];
            float tot = 0.f;
            #pragma unroll
            for (int kt = 0; kt < 8; ++kt){
                const float4 mk = *(const float4*)&msk_s[kt*16 + lg4*4];
                #pragma unroll
                for (int r = 0; r < 4; ++r){
                    const float e = __expf(Cs[kt][r]) * ((const float*)&mk)[r];
                    Cs[kt][r] = e;
                    tot += e;
                }
            }
            tot += __shfl_xor(tot, 16, 64);
            tot += __shfl_xor(tot, 32, 64);
            const float rsum = (tot > 0.0f) ? swr / tot : 0.0f;
            // p = e * rsum * gate ; pack to bf16 pairs
            unsigned int pk0[8], pk1[8];
            #pragma unroll
            for (int kt = 0; kt < 8; ++kt){
                float p[4];
                #pragma unroll
                for (int r = 0; r < 4; ++r){
                    const int k = kt*16 + lg4*4 + r;
                    const float4 rk = *(const float4*)&rhat_s[k * 4];
                    const float gate = rq.x*rk.x + rq.y*rk.y + rq.z*rk.z;
                    p[r] = Cs[kt][r] * rsum * gate;
                }
                pk0[kt] = cvtpk(p[0], p[1]);
                pk1[kt] = cvtpk(p[2], p[3]);
            }
            // redistribute P -> B-frags of PV (col q, kdim k)
            const int srcA = (l15 + ((lane & 16) << 1)) << 2;  // (l15 + 32*(lg4&1))*4
            const int srcB = srcA + 64;
            const bool hi = (lane & 32) != 0;
            bf16x8 bpf[4];
            #pragma unroll
            for (int ks = 0; ks < 4; ++ks){
                const int e0 = __builtin_amdgcn_ds_bpermute(srcA, (int)pk0[2*ks]);
                const int f0 = __builtin_amdgcn_ds_bpermute(srcA, (int)pk0[2*ks+1]);
                const int e1 = __builtin_amdgcn_ds_bpermute(srcA, (int)pk1[2*ks]);
                const int f1 = __builtin_amdgcn_ds_bpermute(srcA, (int)pk1[2*ks+1]);
                const int e2 = __builtin_amdgcn_ds_bpermute(srcB, (int)pk0[2*ks]);
                const int f2 = __builtin_amdgcn_ds_bpermute(srcB, (int)pk0[2*ks+1]);
                const int e3 = __builtin_amdgcn_ds_bpermute(srcB, (int)pk1[2*ks]);
                const int f3 = __builtin_amdgcn_ds_bpermute(srcB, (int)pk1[2*ks+1]);
                uint4 w;
                w.x = hi ? (unsigned)f0 : (unsigned)e0;
                w.y = hi ? (unsigned)f1 : (unsigned)e1;
                w.z = hi ? (unsigned)f2 : (unsigned)e2;
                w.w = hi ? (unsigned)f3 : (unsigned)e3;
                bpf[ks] = *(bf16x8*)&w;
            }
            // PV: O^T = Vn^T · P^T : col=q, row=d
            f32x4 Co[8];
            #pragma unroll
            for (int dt = 0; dt < 8; ++dt) Co[dt] = (f32x4){0.f, 0.f, 0.f, 0.f};
            #pragma unroll
            for (int dt = 0; dt < 8; ++dt)
                #pragma unroll
                for (int ks = 0; ks < 4; ++ks){
                    bf16x8 a = *(const bf16x8*)&vT_s[(dt*16 + l15) * BP + ks*32 + lg4 * 8];
                    Co[dt] = __builtin_amdgcn_mfma_f32_16x16x32_bf16(a, bpf[ks], Co[dt], 0, 0, 0);
                }
            // redistribute O -> B-frags of out-proj (col q, kdim d)
            #pragma unroll
            for (int dt = 0; dt < 8; ++dt){
                pk0[dt] = cvtpk(Co[dt][0], Co[dt][1]);
                pk1[dt] = cvtpk(Co[dt][2], Co[dt][3]);
            }
            bf16x8 bof[4];
            #pragma unroll
            for (int ks = 0; ks < 4; ++ks){
                const int e0 = __builtin_amdgcn_ds_bpermute(srcA, (int)pk0[2*ks]);
                const int f0 = __builtin_amdgcn_ds_bpermute(srcA, (int)pk0[2*ks+1]);
                const int e1 = __builtin_amdgcn_ds_bpermute(srcA, (int)pk1[2*ks]);
                const int f1 = __builtin_amdgcn_ds_bpermute(srcA, (int)pk1[2*ks+1]);
                const int e2 = __builtin_amdgcn_ds_bpermute(srcB, (int)pk0[2*ks]);
                const int f2 = __builtin_amdgcn_ds_bpermute(srcB, (int)pk0[2*ks+1]);
                const int e3 = __builtin_amdgcn_ds_bpermute(srcB, (int)pk1[2*ks]);
                const int f3 = __builtin_amdgcn_ds_bpermute(srcB, (int)pk1[2*ks+1]);
                uint4 w;
                w.x = hi ? (unsigned)f0 : (unsigned)e0;
                w.y = hi ? (unsigned)f1 : (unsigned)e1;
                w.z = hi ? (unsigned)f2 : (unsigned)e2;
                w.w = hi ? (unsigned)f3 : (unsigned)e3;
                bof[ks] = *(bf16x8*)&w;
            }
            // out-proj: F^T = WO^T · O^T : col=q, row=j
            const float* BO = bo  + l * MDIM;
            const float* LG = lng + l * MDIM;
            const float* LB = lnb + l * MDIM;
            float val[7][4];
            float sv = 0.f, sv2 = 0.f;
            #pragma unroll
            for (int jt = 0; jt < 7; ++jt){
                f32x4 Cf = (f32x4){0.f, 0.f, 0.f, 0.f};
                #pragma unroll
                for (int ks = 0; ks < 4; ++ks){
                    bf16x8 a = *(const bf16x8*)(wsb + (size_t)(192 + (l*8+jt)*4 + ks) * 512 + lane * 8);
                    Cf = __builtin_amdgcn_mfma_f32_16x16x32_bf16(a, bof[ks], Cf, 0, 0, 0);
                }
                const bool jok = (jt < 6) || (lg4 == 0);
                float4 BO4 = jok ? *(const float4*)&BO[jt*16 + lg4*4] : make_float4(0,0,0,0);
                #pragma unroll
                for (int r = 0; r < 4; ++r){
                    const float v = Cf[r] + ((const float*)&BO4)[r];
                    val[jt][r] = v;
                    if (jok){ sv += v; sv2 += v * v; }
                }
            }
            sv  += __shfl_xor(sv, 16, 64);  sv  += __shfl_xor(sv, 32, 64);
            sv2 += __shfl_xor(sv2, 16, 64); sv2 += __shfl_xor(sv2, 32, 64);
            const float mu   = sv * 0.01f;
            const float var  = sv2 * 0.01f - mu * mu;
            const float rstd = rsqrtf(var + 1e-5f);
            // residual into g16 (paired-dword r-m-w), own q row
            if (q < NNEI){
                #pragma unroll
                for (int jt = 0; jt < 7; ++jt){
                    const bool jok = (jt < 6) || (lg4 == 0);
                    if (jok){
                        const int jb = jt*16 + lg4*4;
                        const float4 LG4 = *(const float4*)&LG[jb];
                        const float4 LB4 = *(const float4*)&LB[jb];
                        uint2 old = *(const uint2*)&g16[q * BP + jb];
                        float nv[4];
                        nv[0] = bf2f((unsigned short)(old.x & 0xffffu))  + (val[jt][0] - mu) * rstd * LG4.x + LB4.x;
                        nv[1] = bf2f((unsigned short)(old.x >> 16))      + (val[jt][1] - mu) * rstd * LG4.y + LB4.y;
                        nv[2] = bf2f((unsigned short)(old.y & 0xffffu))  + (val[jt][2] - mu) * rstd * LG4.z + LB4.z;
                        nv[3] = bf2f((unsigned short)(old.y >> 16))      + (val[jt][3] - mu) * rstd * LG4.w + LB4.w;
                        uint2 nw;
                        nw.x = cvtpk(nv[0], nv[1]);
                        nw.y = cvtpk(nv[2], nv[3]);
                        *(uint2*)&g16[q * BP + jb] = nw;
                    }
                }
            }
        }
        __syncthreads();  // end of layer
    }

    // ---------------- Final: gr = env^T g / NNEI ; d = gr^T gr[:, :16] -------
    for (int idx = tid; idx < 4 * MDIM; idx += 1024){
        const int c = idx / MDIM, mm = idx - c * MDIM;
        float a = 0.0f;
        for (int k = 0; k < NNEI; ++k)
            a = fmaf(env_s[k * 4 + c], bf2f(g16[k * BP + mm]), a);
        gr_s[c * MDIM + mm] = a * (1.0f / 120.0f);
    }
    __syncthreads();

    float* outp = out + (size_t)n * OUTD;
    for (int idx = tid; idx < MDIM * 16; idx += 1024){
        const int mm = idx >> 4, aa = idx & 15;
        float acc = 0.0f;
        #pragma unroll
        for (int c = 0; c < 4; ++c)
            acc = fmaf(gr_s[c * MDIM + mm], gr_s[c * MDIM + aa], acc);
        outp[idx] = acc;
    }
    if (tid < 8) outp[1600 + tid] = tebd_s[ta_sh * 8 + tid];
}

extern "C" void kernel_launch(void* const* d_in, const int* in_sizes, int n_in,
                              void* d_out, int out_size, void* d_ws, size_t ws_size,
                              hipStream_t stream) {
    const float* rij   = (const float*)d_in[0];
    const void*  nmask = d_in[1];
    const int*   atype = (const int*)d_in[2];
    const int*   ntype = (const int*)d_in[3];
    const float* tebd  = (const float*)d_in[4];
    const float* ew0 = (const float*)d_in[5];
    const float* eb0 = (const float*)d_in[6];
    const float* ew1 = (const float*)d_in[7];
    const float* eb1 = (const float*)d_in[8];
    const float* ew2 = (const float*)d_in[9];
    const float* eb2 = (const float*)d_in[10];
    const float* wq = (const float*)d_in[11];
    const float* bq = (const float*)d_in[12];
    const float* wk = (const float*)d_in[13];
    const float* bk = (const float*)d_in[14];
    const float* wv = (const float*)d_in[15];
    const float* bv = (const float*)d_in[16];
    const float* wo = (const float*)d_in[17];
    const float* bo = (const float*)d_in[18];
    const float* lng = (const float*)d_in[19];
    const float* lnb = (const float*)d_in[20];
    float* out = (float*)d_out;
    int* flag = (int*)d_ws;
    unsigned short* wsb = (unsigned short*)((char*)d_ws + 256);

    detect_mask_kernel<<<1, 64, 0, stream>>>((const unsigned char*)nmask, flag);
    prep_weights<<<270, 64, 0, stream>>>(wq, wk, wv, wo, ew2, wsb);
    dpa1_kernel<<<4096, 1024, 0, stream>>>(rij, nmask, atype, ntype, tebd,
                                           ew0, eb0, ew1, eb1, eb2,
                                           bq, bk, bv, bo, lng, lnb,
                                           out, flag, wsb);
}

// Round 10
// 912.431 us; speedup vs baseline: 20.0531x; 1.0000x over previous
//
#include <hip/hip_runtime.h>

// DescrptDPA1 on gfx950 — R10: R8 + amdgpu_waves_per_eu(4,4) so the backend's
// occupancy TARGET (which sets the VGPR budget) matches the LDS-imposed
// 4 waves/EU, giving the allocator 128 VGPRs instead of spilling at 64.
// (R9's __launch_bounds__(1024,4) was a no-op: 1024 threads already imply
// min 4 waves/EU; the budget heuristic targeted 8.)
// NF=1, NLOC=4096, NNEI=120, TEBD=8, NTYPES=4, M=100, ATTN=128, NLAYER=2, AXIS=16.

#define NNEI 120
#define MDIM 100
#define ADIM 128
#define BP   136   // bf16 pitch (272B rows; 68 dw = 4 mod 32 banks, 16B aligned)
#define H2P  72    // bf16 pitch for h2 staging
#define OUTD 1608

typedef __attribute__((ext_vector_type(8))) short bf16x8;
typedef __attribute__((ext_vector_type(4))) float f32x4;

__device__ __forceinline__ float bf2f(unsigned short u){
    return __uint_as_float(((unsigned int)u) << 16);
}
__device__ __forceinline__ unsigned short f2bf(float f){
    unsigned int x = __float_as_uint(f);
    return (unsigned short)((x + 0x7fffu + ((x >> 16) & 1u)) >> 16);
}
__device__ __forceinline__ unsigned int cvtpk(float lo, float hi){
    unsigned int r;
    asm("v_cvt_pk_bf16_f32 %0, %1, %2" : "=v"(r) : "v"(lo), "v"(hi));
    return r;
}
__device__ __forceinline__ float ftanh(float x){
    return 1.0f - 2.0f / (__expf(2.0f * x) + 1.0f);
}
__device__ __forceinline__ float red16(float v){
    v += __shfl_xor(v, 1, 64); v += __shfl_xor(v, 2, 64);
    v += __shfl_xor(v, 4, 64); v += __shfl_xor(v, 8, 64);
    return v;
}

// nmask storage detection: 1 = int32 {0,1}, 2 = f32 {0.0,1.0}, 0 = byte bool
__global__ void detect_mask_kernel(const unsigned char* __restrict__ p,
                                   int* __restrict__ flag){
    if (blockIdx.x == 0 && threadIdx.x == 0){
        const unsigned int* u = (const unsigned int*)p;
        int alli = 1, allf = 1;
        for (int i = 0; i < 64; ++i){
            unsigned int w = u[i];
            if (!(w == 0u || w == 1u)) alli = 0;
            if (!(w == 0u || w == 0x3f800000u)) allf = 0;
        }
        flag[0] = alli ? 1 : (allf ? 2 : 0);
    }
}

// Pack weights (bf16). Frag = [64 lanes][8 bf16] = 1024B.
// QKV B-frags: fid = ((l*3+mat)*8+nt)*4+ks            (0..191)
//   elem(lane,i): n = nt*16+(lane&15), k = ks*32+(lane>>4)*8+i, val = W[k][n]
// WO A-frags:  fid = 192 + (l*8+jt)*4+ks              (192..255)
//   elem(lane,i): j = jt*16+(lane&15), d = ks*32+(lane>>4)*8+i, val = WO[d][j]
// ew2 B-frags: fid = 256 + nt*2 + ks                  (256..269)
__global__ void prep_weights(const float* __restrict__ wq, const float* __restrict__ wk,
                             const float* __restrict__ wv, const float* __restrict__ wo,
                             const float* __restrict__ ew2,
                             unsigned short* __restrict__ wsb){
    const int fid = blockIdx.x;
    const int lane = threadIdx.x;  // 64
    unsigned short* dst = wsb + (size_t)fid * 512 + lane * 8;
    if (fid < 192){
        const int l = fid / 96, rem = fid % 96, mat = rem / 32;
        const int r2 = rem % 32, nt = r2 / 4, ks = r2 % 4;
        const float* W = (mat == 0 ? wq : mat == 1 ? wk : wv) + l * MDIM * ADIM;
        const int nn = nt * 16 + (lane & 15);
        const int k0 = ks * 32 + (lane >> 4) * 8;
        #pragma unroll
        for (int i = 0; i < 8; ++i){
            const int kk = k0 + i;
            dst[i] = (kk < MDIM) ? f2bf(W[kk * ADIM + nn]) : (unsigned short)0;
        }
    } else if (fid < 256){
        const int f2 = fid - 192, l = f2 / 32, rem = f2 % 32, jt = rem / 4, ks = rem % 4;
        const float* W = wo + l * ADIM * MDIM;
        const int j = jt * 16 + (lane & 15);
        const int d0 = ks * 32 + (lane >> 4) * 8;
        #pragma unroll
        for (int i = 0; i < 8; ++i)
            dst[i] = (j < MDIM) ? f2bf(W[(d0 + i) * MDIM + j]) : (unsigned short)0;
    } else {
        const int f3 = fid - 256, nt = f3 >> 1, ks = f3 & 1;
        const int nn = nt * 16 + (lane & 15);
        const int k0 = ks * 32 + (lane >> 4) * 8;
        #pragma unroll
        for (int i = 0; i < 8; ++i){
            const int kk = k0 + i;
            dst[i] = (kk < 50 && nn < MDIM) ? f2bf(ew2[kk * MDIM + nn]) : (unsigned short)0;
        }
    }
}

__global__ __launch_bounds__(1024)
__attribute__((amdgpu_waves_per_eu(4, 4)))
void dpa1_kernel(
    const float* __restrict__ rij, const void* __restrict__ nmask,
    const int* __restrict__ atype, const int* __restrict__ ntype,
    const float* __restrict__ tebd,
    const float* __restrict__ ew0, const float* __restrict__ eb0,
    const float* __restrict__ ew1, const float* __restrict__ eb1,
    const float* __restrict__ eb2,
    const float* __restrict__ bq, const float* __restrict__ bk,
    const float* __restrict__ bv, const float* __restrict__ bo,
    const float* __restrict__ lng, const float* __restrict__ lnb,
    float* __restrict__ out, const int* __restrict__ flagp,
    const unsigned short* __restrict__ wsb)
{
    __shared__ __align__(16) unsigned short g16[128 * BP];   // bf16 g master
    __shared__ __align__(16) unsigned short buf1[128 * BP];  // h2 -> Qn
    __shared__ __align__(16) unsigned short kn_s[128 * BP];  // Kn (ki*tinv folded)
    __shared__ __align__(16) unsigned short vT_s[128 * BP];  // h1(f32) -> Vn^T (vinv*swm folded)
    __shared__ __align__(16) float env_s[128 * 4];
    __shared__ __align__(16) float rhat_s[128 * 4];
    __shared__ __align__(16) float swm_s[128];
    __shared__ __align__(16) float msk_s[128];
    __shared__ int   ntype_s[NNEI];
    __shared__ float tebd_s[32];
    __shared__ float gr_s[4 * MDIM];
    __shared__ int ta_sh;

    const int n    = blockIdx.x;
    const int tid  = threadIdx.x;
    const int lane = tid & 63;
    const int wid  = tid >> 6;
    const int flag = flagp[0];
    const int l15  = lane & 15;
    const int lg4  = lane >> 4;

    if (tid < 32) tebd_s[tid] = tebd[tid];
    if (tid == 0) ta_sh = atype[n];

    // ---------------- P-geom: geometry + zero g16 ---------------------------
    {
        unsigned int* z0 = (unsigned int*)g16;
        for (int i = tid; i < 128 * (BP/2); i += 1024) z0[i] = 0;
    }
    if (tid < 128){
        const int k = tid;
        if (k < NNEI){
            const int base = n * NNEI + k;
            const float rx = rij[base * 3 + 0];
            const float ry = rij[base * 3 + 1];
            const float rz = rij[base * 3 + 2];
            const float r  = sqrtf(rx * rx + ry * ry + rz * rz);
            float mval;
            if (flag == 1)      mval = (((const int*)nmask)[base] != 0) ? 1.0f : 0.0f;
            else if (flag == 2) mval = ((const float*)nmask)[base];
            else                mval = (((const unsigned char*)nmask)[base] != 0) ? 1.0f : 0.0f;
            float uu = (r - 0.5f) * (1.0f / 5.5f);
            uu = fminf(fmaxf(uu, 0.0f), 1.0f);
            const float sw   = uu * uu * uu * (-6.0f * uu * uu + 15.0f * uu - 10.0f) + 1.0f;
            const float invr = 1.0f / r;
            const float sr   = sw * invr * mval;
            const float hx = rx * invr, hy = ry * invr, hz = rz * invr;
            env_s[k * 4 + 0] = sr;
            env_s[k * 4 + 1] = sr * hx;
            env_s[k * 4 + 2] = sr * hy;
            env_s[k * 4 + 3] = sr * hz;
            rhat_s[k * 4 + 0] = hx; rhat_s[k * 4 + 1] = hy; rhat_s[k * 4 + 2] = hz;
            rhat_s[k * 4 + 3] = 0.0f;
            swm_s[k] = sw * mval;
            msk_s[k] = mval;
            ntype_s[k] = ntype[base];
        } else {
            env_s[k*4+0] = env_s[k*4+1] = env_s[k*4+2] = env_s[k*4+3] = 0.0f;
            rhat_s[k*4+0] = rhat_s[k*4+1] = rhat_s[k*4+2] = rhat_s[k*4+3] = 0.0f;
            swm_s[k] = 0.0f; msk_s[k] = 0.0f;
        }
    }
    __syncthreads();

    // ---------------- e1: h1 = tanh(x @ ew0 + eb0)  (f32 in vT space) --------
    {
        float* h1buf = (float*)vT_s;
        const int ta = ta_sh;
        for (int idx = tid; idx < NNEI * 25; idx += 1024){
            const int k = idx / 25, j = idx - k * 25;
            const float sr = env_s[k * 4];
            const float* tn = &tebd_s[ntype_s[k] * 8];
            const float* tc = &tebd_s[ta * 8];
            float a = eb0[j] + sr * ew0[j];
            #pragma unroll
            for (int i = 0; i < 8; ++i){
                a = fmaf(tn[i], ew0[(1 + i) * 25 + j], a);
                a = fmaf(tc[i], ew0[(9 + i) * 25 + j], a);
            }
            h1buf[k * 25 + j] = ftanh(a);
        }
    }
    __syncthreads();

    // ---------------- e2: h2 = tanh(h1 @ ew1 + eb1) + [h1,h1]  (bf16, buf1) --
    // Full 64-wide rows: cols 50..63 explicit zeros (e3 A-operand reads K=64).
    {
        const float* h1buf = (const float*)vT_s;
        for (int idx = tid; idx < NNEI * 64; idx += 1024){
            const int k = idx >> 6, j = idx & 63;
            unsigned short w = 0;
            if (j < 50){
                float a = eb1[j];
                const float* h1r = &h1buf[k * 25];
                #pragma unroll
                for (int i = 0; i < 25; ++i) a = fmaf(h1r[i], ew1[i * 50 + j], a);
                w = f2bf(ftanh(a) + h1r[j >= 25 ? j - 25 : j]);
            }
            buf1[k * H2P + j] = w;
        }
        if (tid < 8 * (H2P/2)){
            unsigned int* hz = (unsigned int*)buf1;
            const int row = 120 + tid / (H2P/2), c = tid % (H2P/2);
            hz[row * (H2P/2) + c] = 0;
        }
    }
    __syncthreads();

    // ---------------- e3: g = (tanh(h2 @ ew2 + eb2) + [h2,h2]) * m  (MFMA) ---
    {
        for (int job = wid; job < 56; job += 16){
            const int mt = job / 7, nt = job - mt * 7;
            bf16x8 a0 = *(const bf16x8*)&buf1[(mt*16 + l15) * H2P + 0*32 + lg4 * 8];
            bf16x8 a1 = *(const bf16x8*)&buf1[(mt*16 + l15) * H2P + 1*32 + lg4 * 8];
            bf16x8 b0 = *(const bf16x8*)(wsb + (size_t)(256 + nt*2 + 0) * 512 + lane * 8);
            bf16x8 b1 = *(const bf16x8*)(wsb + (size_t)(256 + nt*2 + 1) * 512 + lane * 8);
            f32x4 C = (f32x4){0.f, 0.f, 0.f, 0.f};
            C = __builtin_amdgcn_mfma_f32_16x16x32_bf16(a0, b0, C, 0, 0, 0);
            C = __builtin_amdgcn_mfma_f32_16x16x32_bf16(a1, b1, C, 0, 0, 0);
            const int j = nt * 16 + l15;
            if (j < MDIM){
                const float ebj = eb2[j];
                const int jr = (j >= 50) ? j - 50 : j;
                #pragma unroll
                for (int r = 0; r < 4; ++r){
                    const int row = mt * 16 + lg4 * 4 + r;
                    if (row < NNEI){
                        const float h2d = bf2f(buf1[row * H2P + jr]);
                        const float t = ftanh(C[r] + ebj) + h2d;
                        g16[row * BP + j] = f2bf(t * msk_s[row]);
                    }
                }
            }
        }
    }
    __syncthreads();

    // ---------------- Attention layers ----------------
    const float tinv = 0.08838834764831845f;  // 1/sqrt(128)

    for (int l = 0; l < 2; ++l){
        // ===== A1: full-width jobs; norms folded at the producer =====
        if (wid < 8){
            // Q tile wid: Qn = (g@WQ + bq) * rsqrt(rowsum)
            bf16x8 ag[4];
            #pragma unroll
            for (int ks = 0; ks < 4; ++ks)
                ag[ks] = *(const bf16x8*)&g16[(wid*16 + l15) * BP + ks*32 + lg4 * 8];
            float qv[8][4];
            float sq[4] = {0.f, 0.f, 0.f, 0.f};
            #pragma unroll
            for (int nt = 0; nt < 8; ++nt){
                f32x4 C = (f32x4){0.f, 0.f, 0.f, 0.f};
                #pragma unroll
                for (int ks = 0; ks < 4; ++ks){
                    bf16x8 b = *(const bf16x8*)(wsb + (size_t)(((l*3+0)*8+nt)*4+ks) * 512 + lane * 8);
                    C = __builtin_amdgcn_mfma_f32_16x16x32_bf16(ag[ks], b, C, 0, 0, 0);
                }
                const float bias = bq[l * ADIM + nt*16 + l15];
                #pragma unroll
                for (int r = 0; r < 4; ++r){
                    qv[nt][r] = C[r] + bias;
                    sq[r] = fmaf(qv[nt][r], qv[nt][r], sq[r]);
                }
            }
            float qs[4];
            #pragma unroll
            for (int r = 0; r < 4; ++r)
                qs[r] = rsqrtf(fmaxf(red16(sq[r]), 1e-24f));
            #pragma unroll
            for (int nt = 0; nt < 8; ++nt)
                #pragma unroll
                for (int r = 0; r < 4; ++r)
                    buf1[(wid*16 + lg4*4 + r) * BP + nt*16 + l15] = f2bf(qv[nt][r] * qs[r]);
        } else {
            const int t = wid - 8;
            bf16x8 ag[4];
            #pragma unroll
            for (int ks = 0; ks < 4; ++ks)
                ag[ks] = *(const bf16x8*)&g16[(t*16 + l15) * BP + ks*32 + lg4 * 8];
            // K tile t: Kn = (g@WK + bk) * tinv * rsqrt(rowsum)
            {
                float kv[8][4];
                float sq[4] = {0.f, 0.f, 0.f, 0.f};
                #pragma unroll
                for (int nt = 0; nt < 8; ++nt){
                    f32x4 C = (f32x4){0.f, 0.f, 0.f, 0.f};
                    #pragma unroll
                    for (int ks = 0; ks < 4; ++ks){
                        bf16x8 b = *(const bf16x8*)(wsb + (size_t)(((l*3+1)*8+nt)*4+ks) * 512 + lane * 8);
                        C = __builtin_amdgcn_mfma_f32_16x16x32_bf16(ag[ks], b, C, 0, 0, 0);
                    }
                    const float bias = bk[l * ADIM + nt*16 + l15];
                    #pragma unroll
                    for (int r = 0; r < 4; ++r){
                        kv[nt][r] = C[r] + bias;
                        sq[r] = fmaf(kv[nt][r], kv[nt][r], sq[r]);
                    }
                }
                float kss[4];
                #pragma unroll
                for (int r = 0; r < 4; ++r)
                    kss[r] = tinv * rsqrtf(fmaxf(red16(sq[r]), 1e-24f));
                #pragma unroll
                for (int nt = 0; nt < 8; ++nt)
                    #pragma unroll
                    for (int r = 0; r < 4; ++r)
                        kn_s[(t*16 + lg4*4 + r) * BP + nt*16 + l15] = f2bf(kv[nt][r] * kss[r]);
            }
            // V tile t: Vn^T = ((g@WV + bv) * swm_k * rsqrt(rowsum))^T
            {
                float vv[8][4];
                float sq[4] = {0.f, 0.f, 0.f, 0.f};
                #pragma unroll
                for (int nt = 0; nt < 8; ++nt){
                    f32x4 C = (f32x4){0.f, 0.f, 0.f, 0.f};
                    #pragma unroll
                    for (int ks = 0; ks < 4; ++ks){
                        bf16x8 b = *(const bf16x8*)(wsb + (size_t)(((l*3+2)*8+nt)*4+ks) * 512 + lane * 8);
                        C = __builtin_amdgcn_mfma_f32_16x16x32_bf16(ag[ks], b, C, 0, 0, 0);
                    }
                    const float bias = bv[l * ADIM + nt*16 + l15];
                    #pragma unroll
                    for (int r = 0; r < 4; ++r){
                        vv[nt][r] = C[r] + bias;
                        sq[r] = fmaf(vv[nt][r], vv[nt][r], sq[r]);
                    }
                }
                float vs[4];
                #pragma unroll
                for (int r = 0; r < 4; ++r){
                    const int k = t*16 + lg4*4 + r;
                    vs[r] = swm_s[k] * rsqrtf(fmaxf(red16(sq[r]), 1e-24f));
                }
                #pragma unroll
                for (int nt = 0; nt < 8; ++nt){
                    const unsigned int lo = cvtpk(vv[nt][0]*vs[0], vv[nt][1]*vs[1]);
                    const unsigned int hi = cvtpk(vv[nt][2]*vs[2], vv[nt][3]*vs[3]);
                    *(uint2*)&vT_s[(nt*16 + l15) * BP + t*16 + lg4*4] = make_uint2(lo, hi);
                }
            }
        }
        __syncthreads();  // Qn, Kn, Vn^T ready

        // ===== Core (waves 0..7): transposed pipeline, all in-wave =====
        if (wid < 8){
            const int qt = wid;
            const int q  = qt * 16 + l15;       // this lane's q-row
            // B-frags of scores = Qn rows
            bf16x8 bqf[4];
            #pragma unroll
            for (int ks = 0; ks < 4; ++ks)
                bqf[ks] = *(const bf16x8*)&buf1[(qt*16 + l15) * BP + ks*32 + lg4 * 8];
            // Cs[kt] = K·Q^T : col=q(l15), row=k(lg4*4+r)
            f32x4 Cs[8];
            #pragma unroll
            for (int kt = 0; kt < 8; ++kt) Cs[kt] = (f32x4){0.f, 0.f, 0.f, 0.f};
            #pragma unroll
            for (int kt = 0; kt < 8; ++kt)
                #pragma unroll
                for (int ks = 0; ks < 4; ++ks){
                    bf16x8 a = *(const bf16x8*)&kn_s[(kt*16 + l15) * BP + ks*32 + lg4 * 8];
                    Cs[kt] = __builtin_amdgcn_mfma_f32_16x16x32_bf16(a, bqf[ks], Cs[kt], 0, 0, 0);
                }
            // softmax (no-max: |arg| <= tinv); e = exp * mask_k; in-lane + 2-shfl row sum
            const float swr = swm_s[q];
            const float4 rq = *(const float4*)&rhat_s[q * 4];
            float tot = 0.f;
            #pragma unroll
            for (int kt = 0; kt < 8; ++kt){
                const float4 mk = *(const float4*)&msk_s[kt*16 + lg4*4];
                #pragma unroll
                for (int r = 0; r < 4; ++r){
                    const float e = __expf(Cs[kt][r]) * ((const float*)&mk)[r];
                    Cs[kt][r] = e;
                    tot += e;
                }
            }
            tot += __shfl_xor(tot, 16, 64);
            tot += __shfl_xor(tot, 32, 64);
            const float rsum = (tot > 0.0f) ? swr / tot : 0.0f;
            // p = e * rsum * gate ; pack to bf16 pairs
            unsigned int pk0[8], pk1[8];
            #pragma unroll
            for (int kt = 0; kt < 8; ++kt){
                float p[4];
                #pragma unroll
                for (int r = 0; r < 4; ++r){
                    const int k = kt*16 + lg4*4 + r;
                    const float4 rk = *(const float4*)&rhat_s[k * 4];
                    const float gate = rq.x*rk.x + rq.y*rk.y + rq.z*rk.z;
                    p[r] = Cs[kt][r] * rsum * gate;
                }
                pk0[kt] = cvtpk(p[0], p[1]);
                pk1[kt] = cvtpk(p[2], p[3]);
            }
            // redistribute P -> B-frags of PV (col q, kdim k)
            const int srcA = (l15 + ((lane & 16) << 1)) << 2;  // (l15 + 32*(lg4&1))*4
            const int srcB = srcA + 64;
            const bool hi = (lane & 32) != 0;
            bf16x8 bpf[4];
            #pragma unroll
            for (int ks = 0; ks < 4; ++ks){
                const int e0 = __builtin_amdgcn_ds_bpermute(srcA, (int)pk0[2*ks]);
                const int f0 = __builtin_amdgcn_ds_bpermute(srcA, (int)pk0[2*ks+1]);
                const int e1 = __builtin_amdgcn_ds_bpermute(srcA, (int)pk1[2*ks]);
                const int f1 = __builtin_amdgcn_ds_bpermute(srcA, (int)pk1[2*ks+1]);
                const int e2 = __builtin_amdgcn_ds_bpermute(srcB, (int)pk0[2*ks]);
                const int f2 = __builtin_amdgcn_ds_bpermute(srcB, (int)pk0[2*ks+1]);
                const int e3 = __builtin_amdgcn_ds_bpermute(srcB, (int)pk1[2*ks]);
                const int f3 = __builtin_amdgcn_ds_bpermute(srcB, (int)pk1[2*ks+1]);
                uint4 w;
                w.x = hi ? (unsigned)f0 : (unsigned)e0;
                w.y = hi ? (unsigned)f1 : (unsigned)e1;
                w.z = hi ? (unsigned)f2 : (unsigned)e2;
                w.w = hi ? (unsigned)f3 : (unsigned)e3;
                bpf[ks] = *(bf16x8*)&w;
            }
            // PV: O^T = Vn^T · P^T : col=q, row=d
            f32x4 Co[8];
            #pragma unroll
            for (int dt = 0; dt < 8; ++dt) Co[dt] = (f32x4){0.f, 0.f, 0.f, 0.f};
            #pragma unroll
            for (int dt = 0; dt < 8; ++dt)
                #pragma unroll
                for (int ks = 0; ks < 4; ++ks){
                    bf16x8 a = *(const bf16x8*)&vT_s[(dt*16 + l15) * BP + ks*32 + lg4 * 8];
                    Co[dt] = __builtin_amdgcn_mfma_f32_16x16x32_bf16(a, bpf[ks], Co[dt], 0, 0, 0);
                }
            // redistribute O -> B-frags of out-proj (col q, kdim d)
            #pragma unroll
            for (int dt = 0; dt < 8; ++dt){
                pk0[dt] = cvtpk(Co[dt][0], Co[dt][1]);
                pk1[dt] = cvtpk(Co[dt][2], Co[dt][3]);
            }
            bf16x8 bof[4];
            #pragma unroll
            for (int ks = 0; ks < 4; ++ks){
                const int e0 = __builtin_amdgcn_ds_bpermute(srcA, (int)pk0[2*ks]);
                const int f0 = __builtin_amdgcn_ds_bpermute(srcA, (int)pk0[2*ks+1]);
                const int e1 = __builtin_amdgcn_ds_bpermute(srcA, (int)pk1[2*ks]);
                const int f1 = __builtin_amdgcn_ds_bpermute(srcA, (int)pk1[2*ks+1]);
                const int e2 = __builtin_amdgcn_ds_bpermute(srcB, (int)pk0[2*ks]);
                const int f2 = __builtin_amdgcn_ds_bpermute(srcB, (int)pk0[2*ks+1]);
                const int e3 = __builtin_amdgcn_ds_bpermute(srcB, (int)pk1[2*ks]);
                const int f3 = __builtin_amdgcn_ds_bpermute(srcB, (int)pk1[2*ks+1]);
                uint4 w;
                w.x = hi ? (unsigned)f0 : (unsigned)e0;
                w.y = hi ? (unsigned)f1 : (unsigned)e1;
                w.z = hi ? (unsigned)f2 : (unsigned)e2;
                w.w = hi ? (unsigned)f3 : (unsigned)e3;
                bof[ks] = *(bf16x8*)&w;
            }
            // out-proj: F^T = WO^T · O^T : col=q, row=j
            const float* BO = bo  + l * MDIM;
            const float* LG = lng + l * MDIM;
            const float* LB = lnb + l * MDIM;
            float val[7][4];
            float sv = 0.f, sv2 = 0.f;
            #pragma unroll
            for (int jt = 0; jt < 7; ++jt){
                f32x4 Cf = (f32x4){0.f, 0.f, 0.f, 0.f};
                #pragma unroll
                for (int ks = 0; ks < 4; ++ks){
                    bf16x8 a = *(const bf16x8*)(wsb + (size_t)(192 + (l*8+jt)*4 + ks) * 512 + lane * 8);
                    Cf = __builtin_amdgcn_mfma_f32_16x16x32_bf16(a, bof[ks], Cf, 0, 0, 0);
                }
                const bool jok = (jt < 6) || (lg4 == 0);
                float4 BO4 = jok ? *(const float4*)&BO[jt*16 + lg4*4] : make_float4(0,0,0,0);
                #pragma unroll
                for (int r = 0; r < 4; ++r){
                    const float v = Cf[r] + ((const float*)&BO4)[r];
                    val[jt][r] = v;
                    if (jok){ sv += v; sv2 += v * v; }
                }
            }
            sv  += __shfl_xor(sv, 16, 64);  sv  += __shfl_xor(sv, 32, 64);
            sv2 += __shfl_xor(sv2, 16, 64); sv2 += __shfl_xor(sv2, 32, 64);
            const float mu   = sv * 0.01f;
            const float var  = sv2 * 0.01f - mu * mu;
            const float rstd = rsqrtf(var + 1e-5f);
            // residual into g16 (paired-dword r-m-w), own q row
            if (q < NNEI){
                #pragma unroll
                for (int jt = 0; jt < 7; ++jt){
                    const bool jok = (jt < 6) || (lg4 == 0);
                    if (jok){
                        const int jb = jt*16 + lg4*4;
                        const float4 LG4 = *(const float4*)&LG[jb];
                        const float4 LB4 = *(const float4*)&LB[jb];
                        uint2 old = *(const uint2*)&g16[q * BP + jb];
                        float nv[4];
                        nv[0] = bf2f((unsigned short)(old.x & 0xffffu))  + (val[jt][0] - mu) * rstd * LG4.x + LB4.x;
                        nv[1] = bf2f((unsigned short)(old.x >> 16))      + (val[jt][1] - mu) * rstd * LG4.y + LB4.y;
                        nv[2] = bf2f((unsigned short)(old.y & 0xffffu))  + (val[jt][2] - mu) * rstd * LG4.z + LB4.z;
                        nv[3] = bf2f((unsigned short)(old.y >> 16))      + (val[jt][3] - mu) * rstd * LG4.w + LB4.w;
                        uint2 nw;
                        nw.x = cvtpk(nv[0], nv[1]);
                        nw.y = cvtpk(nv[2], nv[3]);
                        *(uint2*)&g16[q * BP + jb] = nw;
                    }
                }
            }
        }
        __syncthreads();  // end of layer
    }

    // ---------------- Final: gr = env^T g / NNEI ; d = gr^T gr[:, :16] -------
    for (int idx = tid; idx < 4 * MDIM; idx += 1024){
        const int c = idx / MDIM, mm = idx - c * MDIM;
        float a = 0.0f;
        for (int k = 0; k < NNEI; ++k)
            a = fmaf(env_s[k * 4 + c], bf2f(g16[k * BP + mm]), a);
        gr_s[c * MDIM + mm] = a * (1.0f / 120.0f);
    }
    __syncthreads();

    float* outp = out + (size_t)n * OUTD;
    for (int idx = tid; idx < MDIM * 16; idx += 1024){
        const int mm = idx >> 4, aa = idx & 15;
        float acc = 0.0f;
        #pragma unroll
        for (int c = 0; c < 4; ++c)
            acc = fmaf(gr_s[c * MDIM + mm], gr_s[c * MDIM + aa], acc);
        outp[idx] = acc;
    }
    if (tid < 8) outp[1600 + tid] = tebd_s[ta_sh * 8 + tid];
}

extern "C" void kernel_launch(void* const* d_in, const int* in_sizes, int n_in,
                              void* d_out, int out_size, void* d_ws, size_t ws_size,
                              hipStream_t stream) {
    const float* rij   = (const float*)d_in[0];
    const void*  nmask = d_in[1];
    const int*   atype = (const int*)d_in[2];
    const int*   ntype = (const int*)d_in[3];
    const float* tebd  = (const float*)d_in[4];
    const float* ew0 = (const float*)d_in[5];
    const float* eb0 = (const float*)d_in[6];
    const float* ew1 = (const float*)d_in[7];
    const float* eb1 = (const float*)d_in[8];
    const float* ew2 = (const float*)d_in[9];
    const float* eb2 = (const float*)d_in[10];
    const float* wq = (const float*)d_in[11];
    const float* bq = (const float*)d_in[12];
    const float* wk = (const float*)d_in[13];
    const float* bk = (const float*)d_in[14];
    const float* wv = (const float*)d_in[15];
    const float* bv = (const float*)d_in[16];
    const float* wo = (const float*)d_in[17];
    const float* bo = (const float*)d_in[18];
    const float* lng = (const float*)d_in[19];
    const float* lnb = (const float*)d_in[20];
    float* out = (float*)d_out;
    int* flag = (int*)d_ws;
    unsigned short* wsb = (unsigned short*)((char*)d_ws + 256);

    detect_mask_kernel<<<1, 64, 0, stream>>>((const unsigned char*)nmask, flag);
    prep_weights<<<270, 64, 0, stream>>>(wq, wk, wv, wo, ew2, wsb);
    dpa1_kernel<<<4096, 1024, 0, stream>>>(rij, nmask, atype, ntype, tebd,
                                           ew0, eb0, ew1, eb1, eb2,
                                           bq, bk, bv, bo, lng, lnb,
                                           out, flag, wsb);
}

// Round 11
// 861.005 us; speedup vs baseline: 21.2509x; 1.0597x over previous
//
#include <hip/hip_runtime.h>

// DescrptDPA1 on gfx950 — R11: split-core. Every core phase runs on all 16
// waves (pair per q-tile: h = col/kt/dt/jt half), P/O exchanged through dead
// LDS buffers with direct b128 B-frag reads (replaces 64 ds_bpermutes).
// 6 barriers/layer but zero idle waves.
// NF=1, NLOC=4096, NNEI=120, TEBD=8, NTYPES=4, M=100, ATTN=128, NLAYER=2, AXIS=16.

#define NNEI 120
#define MDIM 100
#define ADIM 128
#define BP   136   // bf16 pitch (272B rows; 68 dw = 4 mod 32 banks, 16B aligned)
#define H2P  72    // bf16 pitch for h2 staging
#define OUTD 1608

typedef __attribute__((ext_vector_type(8))) short bf16x8;
typedef __attribute__((ext_vector_type(4))) float f32x4;

__device__ __forceinline__ float bf2f(unsigned short u){
    return __uint_as_float(((unsigned int)u) << 16);
}
__device__ __forceinline__ unsigned short f2bf(float f){
    unsigned int x = __float_as_uint(f);
    return (unsigned short)((x + 0x7fffu + ((x >> 16) & 1u)) >> 16);
}
__device__ __forceinline__ unsigned int cvtpk(float lo, float hi){
    unsigned int r;
    asm("v_cvt_pk_bf16_f32 %0, %1, %2" : "=v"(r) : "v"(lo), "v"(hi));
    return r;
}
__device__ __forceinline__ float ftanh(float x){
    return 1.0f - 2.0f / (__expf(2.0f * x) + 1.0f);
}
__device__ __forceinline__ float red16(float v){
    v += __shfl_xor(v, 1, 64); v += __shfl_xor(v, 2, 64);
    v += __shfl_xor(v, 4, 64); v += __shfl_xor(v, 8, 64);
    return v;
}

// nmask storage detection: 1 = int32 {0,1}, 2 = f32 {0.0,1.0}, 0 = byte bool
__global__ void detect_mask_kernel(const unsigned char* __restrict__ p,
                                   int* __restrict__ flag){
    if (blockIdx.x == 0 && threadIdx.x == 0){
        const unsigned int* u = (const unsigned int*)p;
        int alli = 1, allf = 1;
        for (int i = 0; i < 64; ++i){
            unsigned int w = u[i];
            if (!(w == 0u || w == 1u)) alli = 0;
            if (!(w == 0u || w == 0x3f800000u)) allf = 0;
        }
        flag[0] = alli ? 1 : (allf ? 2 : 0);
    }
}

// Pack weights (bf16). Frag = [64 lanes][8 bf16] = 1024B.
// QKV B-frags: fid = ((l*3+mat)*8+nt)*4+ks            (0..191)
// WO A-frags:  fid = 192 + (l*8+jt)*4+ks              (192..255, jt=7 zero)
// ew2 B-frags: fid = 256 + nt*2 + ks                  (256..269)
__global__ void prep_weights(const float* __restrict__ wq, const float* __restrict__ wk,
                             const float* __restrict__ wv, const float* __restrict__ wo,
                             const float* __restrict__ ew2,
                             unsigned short* __restrict__ wsb){
    const int fid = blockIdx.x;
    const int lane = threadIdx.x;  // 64
    unsigned short* dst = wsb + (size_t)fid * 512 + lane * 8;
    if (fid < 192){
        const int l = fid / 96, rem = fid % 96, mat = rem / 32;
        const int r2 = rem % 32, nt = r2 / 4, ks = r2 % 4;
        const float* W = (mat == 0 ? wq : mat == 1 ? wk : wv) + l * MDIM * ADIM;
        const int nn = nt * 16 + (lane & 15);
        const int k0 = ks * 32 + (lane >> 4) * 8;
        #pragma unroll
        for (int i = 0; i < 8; ++i){
            const int kk = k0 + i;
            dst[i] = (kk < MDIM) ? f2bf(W[kk * ADIM + nn]) : (unsigned short)0;
        }
    } else if (fid < 256){
        const int f2 = fid - 192, l = f2 / 32, rem = f2 % 32, jt = rem / 4, ks = rem % 4;
        const float* W = wo + l * ADIM * MDIM;
        const int j = jt * 16 + (lane & 15);
        const int d0 = ks * 32 + (lane >> 4) * 8;
        #pragma unroll
        for (int i = 0; i < 8; ++i)
            dst[i] = (j < MDIM) ? f2bf(W[(d0 + i) * MDIM + j]) : (unsigned short)0;
    } else {
        const int f3 = fid - 256, nt = f3 >> 1, ks = f3 & 1;
        const int nn = nt * 16 + (lane & 15);
        const int k0 = ks * 32 + (lane >> 4) * 8;
        #pragma unroll
        for (int i = 0; i < 8; ++i){
            const int kk = k0 + i;
            dst[i] = (kk < 50 && nn < MDIM) ? f2bf(ew2[kk * MDIM + nn]) : (unsigned short)0;
        }
    }
}

__global__ __launch_bounds__(1024) void dpa1_kernel(
    const float* __restrict__ rij, const void* __restrict__ nmask,
    const int* __restrict__ atype, const int* __restrict__ ntype,
    const float* __restrict__ tebd,
    const float* __restrict__ ew0, const float* __restrict__ eb0,
    const float* __restrict__ ew1, const float* __restrict__ eb1,
    const float* __restrict__ eb2,
    const float* __restrict__ bq, const float* __restrict__ bk,
    const float* __restrict__ bv, const float* __restrict__ bo,
    const float* __restrict__ lng, const float* __restrict__ lnb,
    float* __restrict__ out, const int* __restrict__ flagp,
    const unsigned short* __restrict__ wsb)
{
    __shared__ __align__(16) unsigned short g16[128 * BP];   // bf16 g master
    __shared__ __align__(16) unsigned short buf1[128 * BP];  // h2 -> Qn -> P~
    __shared__ __align__(16) unsigned short kn_s[128 * BP];  // Kn -> O'
    __shared__ __align__(16) unsigned short vT_s[128 * BP];  // h1(f32) -> Vn^T
    __shared__ float psum_s[256];          // softmax partial sums per (q, half)
    __shared__ float lnp_s[512];           // LN partials (sv, sv2) per (q, half)
    __shared__ __align__(16) float env_s[128 * 4];
    __shared__ __align__(16) float rhat_s[128 * 4];
    __shared__ __align__(16) float swm_s[128];
    __shared__ __align__(16) float msk_s[128];
    __shared__ int   ntype_s[NNEI];
    __shared__ float tebd_s[32];
    __shared__ float gr_s[4 * MDIM];
    __shared__ int ta_sh;

    const int n    = blockIdx.x;
    const int tid  = threadIdx.x;
    const int lane = tid & 63;
    const int wid  = tid >> 6;
    const int flag = flagp[0];
    const int l15  = lane & 15;
    const int lg4  = lane >> 4;

    if (tid < 32) tebd_s[tid] = tebd[tid];
    if (tid == 0) ta_sh = atype[n];

    // ---------------- P-geom: geometry + zero g16 ---------------------------
    {
        unsigned int* z0 = (unsigned int*)g16;
        for (int i = tid; i < 128 * (BP/2); i += 1024) z0[i] = 0;
    }
    if (tid < 128){
        const int k = tid;
        if (k < NNEI){
            const int base = n * NNEI + k;
            const float rx = rij[base * 3 + 0];
            const float ry = rij[base * 3 + 1];
            const float rz = rij[base * 3 + 2];
            const float r  = sqrtf(rx * rx + ry * ry + rz * rz);
            float mval;
            if (flag == 1)      mval = (((const int*)nmask)[base] != 0) ? 1.0f : 0.0f;
            else if (flag == 2) mval = ((const float*)nmask)[base];
            else                mval = (((const unsigned char*)nmask)[base] != 0) ? 1.0f : 0.0f;
            float uu = (r - 0.5f) * (1.0f / 5.5f);
            uu = fminf(fmaxf(uu, 0.0f), 1.0f);
            const float sw   = uu * uu * uu * (-6.0f * uu * uu + 15.0f * uu - 10.0f) + 1.0f;
            const float invr = 1.0f / r;
            const float sr   = sw * invr * mval;
            const float hx = rx * invr, hy = ry * invr, hz = rz * invr;
            env_s[k * 4 + 0] = sr;
            env_s[k * 4 + 1] = sr * hx;
            env_s[k * 4 + 2] = sr * hy;
            env_s[k * 4 + 3] = sr * hz;
            rhat_s[k * 4 + 0] = hx; rhat_s[k * 4 + 1] = hy; rhat_s[k * 4 + 2] = hz;
            rhat_s[k * 4 + 3] = 0.0f;
            swm_s[k] = sw * mval;
            msk_s[k] = mval;
            ntype_s[k] = ntype[base];
        } else {
            env_s[k*4+0] = env_s[k*4+1] = env_s[k*4+2] = env_s[k*4+3] = 0.0f;
            rhat_s[k*4+0] = rhat_s[k*4+1] = rhat_s[k*4+2] = rhat_s[k*4+3] = 0.0f;
            swm_s[k] = 0.0f; msk_s[k] = 0.0f;
        }
    }
    __syncthreads();

    // ---------------- e1: h1 = tanh(x @ ew0 + eb0)  (f32 in vT space) --------
    {
        float* h1buf = (float*)vT_s;
        const int ta = ta_sh;
        for (int idx = tid; idx < NNEI * 25; idx += 1024){
            const int k = idx / 25, j = idx - k * 25;
            const float sr = env_s[k * 4];
            const float* tn = &tebd_s[ntype_s[k] * 8];
            const float* tc = &tebd_s[ta * 8];
            float a = eb0[j] + sr * ew0[j];
            #pragma unroll
            for (int i = 0; i < 8; ++i){
                a = fmaf(tn[i], ew0[(1 + i) * 25 + j], a);
                a = fmaf(tc[i], ew0[(9 + i) * 25 + j], a);
            }
            h1buf[k * 25 + j] = ftanh(a);
        }
    }
    __syncthreads();

    // ---------------- e2: h2 = tanh(h1 @ ew1 + eb1) + [h1,h1]  (bf16, buf1) --
    // Full 64-wide rows: cols 50..63 explicit zeros (e3 A-operand reads K=64).
    {
        const float* h1buf = (const float*)vT_s;
        for (int idx = tid; idx < NNEI * 64; idx += 1024){
            const int k = idx >> 6, j = idx & 63;
            unsigned short w = 0;
            if (j < 50){
                float a = eb1[j];
                const float* h1r = &h1buf[k * 25];
                #pragma unroll
                for (int i = 0; i < 25; ++i) a = fmaf(h1r[i], ew1[i * 50 + j], a);
                w = f2bf(ftanh(a) + h1r[j >= 25 ? j - 25 : j]);
            }
            buf1[k * H2P + j] = w;
        }
        if (tid < 8 * (H2P/2)){
            unsigned int* hz = (unsigned int*)buf1;
            const int row = 120 + tid / (H2P/2), c = tid % (H2P/2);
            hz[row * (H2P/2) + c] = 0;
        }
    }
    __syncthreads();

    // ---------------- e3: g = (tanh(h2 @ ew2 + eb2) + [h2,h2]) * m  (MFMA) ---
    {
        for (int job = wid; job < 56; job += 16){
            const int mt = job / 7, nt = job - mt * 7;
            bf16x8 a0 = *(const bf16x8*)&buf1[(mt*16 + l15) * H2P + 0*32 + lg4 * 8];
            bf16x8 a1 = *(const bf16x8*)&buf1[(mt*16 + l15) * H2P + 1*32 + lg4 * 8];
            bf16x8 b0 = *(const bf16x8*)(wsb + (size_t)(256 + nt*2 + 0) * 512 + lane * 8);
            bf16x8 b1 = *(const bf16x8*)(wsb + (size_t)(256 + nt*2 + 1) * 512 + lane * 8);
            f32x4 C = (f32x4){0.f, 0.f, 0.f, 0.f};
            C = __builtin_amdgcn_mfma_f32_16x16x32_bf16(a0, b0, C, 0, 0, 0);
            C = __builtin_amdgcn_mfma_f32_16x16x32_bf16(a1, b1, C, 0, 0, 0);
            const int j = nt * 16 + l15;
            if (j < MDIM){
                const float ebj = eb2[j];
                const int jr = (j >= 50) ? j - 50 : j;
                #pragma unroll
                for (int r = 0; r < 4; ++r){
                    const int row = mt * 16 + lg4 * 4 + r;
                    if (row < NNEI){
                        const float h2d = bf2f(buf1[row * H2P + jr]);
                        const float t = ftanh(C[r] + ebj) + h2d;
                        g16[row * BP + j] = f2bf(t * msk_s[row]);
                    }
                }
            }
        }
    }
    __syncthreads();

    // ---------------- Attention layers ----------------
    const float tinv = 0.08838834764831845f;  // 1/sqrt(128)
    const int qt = wid >> 1;   // core pair: q-tile
    const int hh = wid & 1;    // core pair: half index
    const int q  = qt * 16 + l15;

    for (int l = 0; l < 2; ++l){
        // ===== A1: full-width jobs; norms folded at the producer (as R8) =====
        if (wid < 8){
            bf16x8 ag[4];
            #pragma unroll
            for (int ks = 0; ks < 4; ++ks)
                ag[ks] = *(const bf16x8*)&g16[(wid*16 + l15) * BP + ks*32 + lg4 * 8];
            float qv[8][4];
            float sq[4] = {0.f, 0.f, 0.f, 0.f};
            #pragma unroll
            for (int nt = 0; nt < 8; ++nt){
                f32x4 C = (f32x4){0.f, 0.f, 0.f, 0.f};
                #pragma unroll
                for (int ks = 0; ks < 4; ++ks){
                    bf16x8 b = *(const bf16x8*)(wsb + (size_t)(((l*3+0)*8+nt)*4+ks) * 512 + lane * 8);
                    C = __builtin_amdgcn_mfma_f32_16x16x32_bf16(ag[ks], b, C, 0, 0, 0);
                }
                const float bias = bq[l * ADIM + nt*16 + l15];
                #pragma unroll
                for (int r = 0; r < 4; ++r){
                    qv[nt][r] = C[r] + bias;
                    sq[r] = fmaf(qv[nt][r], qv[nt][r], sq[r]);
                }
            }
            float qs[4];
            #pragma unroll
            for (int r = 0; r < 4; ++r)
                qs[r] = rsqrtf(fmaxf(red16(sq[r]), 1e-24f));
            #pragma unroll
            for (int nt = 0; nt < 8; ++nt)
                #pragma unroll
                for (int r = 0; r < 4; ++r)
                    buf1[(wid*16 + lg4*4 + r) * BP + nt*16 + l15] = f2bf(qv[nt][r] * qs[r]);
        } else {
            const int t = wid - 8;
            bf16x8 ag[4];
            #pragma unroll
            for (int ks = 0; ks < 4; ++ks)
                ag[ks] = *(const bf16x8*)&g16[(t*16 + l15) * BP + ks*32 + lg4 * 8];
            // K tile t: Kn = (g@WK + bk) * tinv * rsqrt(rowsum)
            {
                float kv[8][4];
                float sq[4] = {0.f, 0.f, 0.f, 0.f};
                #pragma unroll
                for (int nt = 0; nt < 8; ++nt){
                    f32x4 C = (f32x4){0.f, 0.f, 0.f, 0.f};
                    #pragma unroll
                    for (int ks = 0; ks < 4; ++ks){
                        bf16x8 b = *(const bf16x8*)(wsb + (size_t)(((l*3+1)*8+nt)*4+ks) * 512 + lane * 8);
                        C = __builtin_amdgcn_mfma_f32_16x16x32_bf16(ag[ks], b, C, 0, 0, 0);
                    }
                    const float bias = bk[l * ADIM + nt*16 + l15];
                    #pragma unroll
                    for (int r = 0; r < 4; ++r){
                        kv[nt][r] = C[r] + bias;
                        sq[r] = fmaf(kv[nt][r], kv[nt][r], sq[r]);
                    }
                }
                float kss[4];
                #pragma unroll
                for (int r = 0; r < 4; ++r)
                    kss[r] = tinv * rsqrtf(fmaxf(red16(sq[r]), 1e-24f));
                #pragma unroll
                for (int nt = 0; nt < 8; ++nt)
                    #pragma unroll
                    for (int r = 0; r < 4; ++r)
                        kn_s[(t*16 + lg4*4 + r) * BP + nt*16 + l15] = f2bf(kv[nt][r] * kss[r]);
            }
            // V tile t: Vn^T = ((g@WV + bv) * swm_k * rsqrt(rowsum))^T
            {
                float vv[8][4];
                float sq[4] = {0.f, 0.f, 0.f, 0.f};
                #pragma unroll
                for (int nt = 0; nt < 8; ++nt){
                    f32x4 C = (f32x4){0.f, 0.f, 0.f, 0.f};
                    #pragma unroll
                    for (int ks = 0; ks < 4; ++ks){
                        bf16x8 b = *(const bf16x8*)(wsb + (size_t)(((l*3+2)*8+nt)*4+ks) * 512 + lane * 8);
                        C = __builtin_amdgcn_mfma_f32_16x16x32_bf16(ag[ks], b, C, 0, 0, 0);
                    }
                    const float bias = bv[l * ADIM + nt*16 + l15];
                    #pragma unroll
                    for (int r = 0; r < 4; ++r){
                        vv[nt][r] = C[r] + bias;
                        sq[r] = fmaf(vv[nt][r], vv[nt][r], sq[r]);
                    }
                }
                float vs[4];
                #pragma unroll
                for (int r = 0; r < 4; ++r){
                    const int k = t*16 + lg4*4 + r;
                    vs[r] = swm_s[k] * rsqrtf(fmaxf(red16(sq[r]), 1e-24f));
                }
                #pragma unroll
                for (int nt = 0; nt < 8; ++nt){
                    const unsigned int lo = cvtpk(vv[nt][0]*vs[0], vv[nt][1]*vs[1]);
                    const unsigned int hi = cvtpk(vv[nt][2]*vs[2], vv[nt][3]*vs[3]);
                    *(uint2*)&vT_s[(nt*16 + l15) * BP + t*16 + lg4*4] = make_uint2(lo, hi);
                }
            }
        }
        __syncthreads();  // B1: Qn, Kn, Vn^T ready

        // ===== Core1: scores half (wave pair qt,hh) =====
        unsigned int pw0[4], pw1[4];
        float tot;
        {
            bf16x8 bqf[4];
            #pragma unroll
            for (int ks = 0; ks < 4; ++ks)
                bqf[ks] = *(const bf16x8*)&buf1[(qt*16 + l15) * BP + ks*32 + lg4 * 8];
            f32x4 Cs[4];
            #pragma unroll
            for (int t = 0; t < 4; ++t) Cs[t] = (f32x4){0.f, 0.f, 0.f, 0.f};
            #pragma unroll
            for (int t = 0; t < 4; ++t)
                #pragma unroll
                for (int ks = 0; ks < 4; ++ks){
                    bf16x8 a = *(const bf16x8*)&kn_s[((hh*4+t)*16 + l15) * BP + ks*32 + lg4 * 8];
                    Cs[t] = __builtin_amdgcn_mfma_f32_16x16x32_bf16(a, bqf[ks], Cs[t], 0, 0, 0);
                }
            const float4 rq = *(const float4*)&rhat_s[q * 4];
            tot = 0.f;
            #pragma unroll
            for (int t = 0; t < 4; ++t){
                const int kb = (hh*4+t)*16 + lg4*4;
                float p[4];
                #pragma unroll
                for (int r = 0; r < 4; ++r){
                    const float e = __expf(Cs[t][r]) * msk_s[kb + r];
                    tot += e;
                    const float4 rk = *(const float4*)&rhat_s[(kb + r) * 4];
                    p[r] = e * (rq.x*rk.x + rq.y*rk.y + rq.z*rk.z);
                }
                pw0[t] = cvtpk(p[0], p[1]);
                pw1[t] = cvtpk(p[2], p[3]);
            }
            tot += __shfl_xor(tot, 16, 64);
            tot += __shfl_xor(tot, 32, 64);
        }
        __syncthreads();  // B2: all Q/K reads done; buf1/kn rows reusable

        // ===== Core2: publish P~ (= e*gate) and psum =====
        #pragma unroll
        for (int t = 0; t < 4; ++t)
            *(uint2*)&buf1[(qt*16 + l15) * BP + (hh*4+t)*16 + lg4*4] = make_uint2(pw0[t], pw1[t]);
        if (lg4 == 0) psum_s[q * 2 + hh] = tot;
        __syncthreads();  // B3: P~, psum visible

        // ===== Core3: PV half; apply rsum to O'; publish O' =====
        {
            bf16x8 bpf[4];
            #pragma unroll
            for (int ks = 0; ks < 4; ++ks)
                bpf[ks] = *(const bf16x8*)&buf1[(qt*16 + l15) * BP + ks*32 + lg4 * 8];
            f32x4 Co[4];
            #pragma unroll
            for (int t = 0; t < 4; ++t) Co[t] = (f32x4){0.f, 0.f, 0.f, 0.f};
            #pragma unroll
            for (int t = 0; t < 4; ++t)
                #pragma unroll
                for (int ks = 0; ks < 4; ++ks){
                    bf16x8 a = *(const bf16x8*)&vT_s[((hh*4+t)*16 + l15) * BP + ks*32 + lg4 * 8];
                    Co[t] = __builtin_amdgcn_mfma_f32_16x16x32_bf16(a, bpf[ks], Co[t], 0, 0, 0);
                }
            const float totq = psum_s[q * 2] + psum_s[q * 2 + 1];
            const float rsum = (totq > 0.0f) ? swm_s[q] / totq : 0.0f;
            #pragma unroll
            for (int t = 0; t < 4; ++t){
                const unsigned int lo = cvtpk(Co[t][0] * rsum, Co[t][1] * rsum);
                const unsigned int hi = cvtpk(Co[t][2] * rsum, Co[t][3] * rsum);
                *(uint2*)&kn_s[(qt*16 + l15) * BP + (hh*4+t)*16 + lg4*4] = make_uint2(lo, hi);
            }
        }
        __syncthreads();  // B4: O' visible

        // ===== Core4: out-proj half + LN partials =====
        float val[4][4];
        {
            bf16x8 bof[4];
            #pragma unroll
            for (int ks = 0; ks < 4; ++ks)
                bof[ks] = *(const bf16x8*)&kn_s[(qt*16 + l15) * BP + ks*32 + lg4 * 8];
            const float* BO = bo + l * MDIM;
            float sv = 0.f, sv2 = 0.f;
            #pragma unroll
            for (int t = 0; t < 4; ++t){
                const int jt = hh*4 + t;
                f32x4 Cf = (f32x4){0.f, 0.f, 0.f, 0.f};
                #pragma unroll
                for (int ks = 0; ks < 4; ++ks){
                    bf16x8 a = *(const bf16x8*)(wsb + (size_t)(192 + (l*8+jt)*4 + ks) * 512 + lane * 8);
                    Cf = __builtin_amdgcn_mfma_f32_16x16x32_bf16(a, bof[ks], Cf, 0, 0, 0);
                }
                const bool jok = (jt < 6) || (jt == 6 && lg4 == 0);
                float4 BO4 = jok ? *(const float4*)&BO[jt*16 + lg4*4] : make_float4(0,0,0,0);
                #pragma unroll
                for (int r = 0; r < 4; ++r){
                    const float v = Cf[r] + ((const float*)&BO4)[r];
                    val[t][r] = v;
                    if (jok){ sv += v; sv2 += v * v; }
                }
            }
            sv  += __shfl_xor(sv, 16, 64);  sv  += __shfl_xor(sv, 32, 64);
            sv2 += __shfl_xor(sv2, 16, 64); sv2 += __shfl_xor(sv2, 32, 64);
            if (lg4 == 0){
                lnp_s[q * 4 + hh * 2 + 0] = sv;
                lnp_s[q * 4 + hh * 2 + 1] = sv2;
            }
        }
        __syncthreads();  // B5: LN partials visible

        // ===== Core5: LayerNorm apply + residual into g16 (own jt half) =====
        {
            const float* LG = lng + l * MDIM;
            const float* LB = lnb + l * MDIM;
            const float svt  = lnp_s[q * 4 + 0] + lnp_s[q * 4 + 2];
            const float sv2t = lnp_s[q * 4 + 1] + lnp_s[q * 4 + 3];
            const float mu   = svt * 0.01f;
            const float var  = sv2t * 0.01f - mu * mu;
            const float rstd = rsqrtf(var + 1e-5f);
            if (q < NNEI){
                #pragma unroll
                for (int t = 0; t < 4; ++t){
                    const int jt = hh*4 + t;
                    const bool jok = (jt < 6) || (jt == 6 && lg4 == 0);
                    if (jok){
                        const int jb = jt*16 + lg4*4;
                        const float4 LG4 = *(const float4*)&LG[jb];
                        const float4 LB4 = *(const float4*)&LB[jb];
                        uint2 old = *(const uint2*)&g16[q * BP + jb];
                        float nv[4];
                        nv[0] = bf2f((unsigned short)(old.x & 0xffffu))  + (val[t][0] - mu) * rstd * LG4.x + LB4.x;
                        nv[1] = bf2f((unsigned short)(old.x >> 16))      + (val[t][1] - mu) * rstd * LG4.y + LB4.y;
                        nv[2] = bf2f((unsigned short)(old.y & 0xffffu))  + (val[t][2] - mu) * rstd * LG4.z + LB4.z;
                        nv[3] = bf2f((unsigned short)(old.y >> 16))      + (val[t][3] - mu) * rstd * LG4.w + LB4.w;
                        uint2 nw;
                        nw.x = cvtpk(nv[0], nv[1]);
                        nw.y = cvtpk(nv[2], nv[3]);
                        *(uint2*)&g16[q * BP + jb] = nw;
                    }
                }
            }
        }
        __syncthreads();  // B6: end of layer
    }

    // ---------------- Final: gr = env^T g / NNEI ; d = gr^T gr[:, :16] -------
    for (int idx = tid; idx < 4 * MDIM; idx += 1024){
        const int c = idx / MDIM, mm = idx - c * MDIM;
        float a = 0.0f;
        for (int k = 0; k < NNEI; ++k)
            a = fmaf(env_s[k * 4 + c], bf2f(g16[k * BP + mm]), a);
        gr_s[c * MDIM + mm] = a * (1.0f / 120.0f);
    }
    __syncthreads();

    float* outp = out + (size_t)n * OUTD;
    for (int idx = tid; idx < MDIM * 16; idx += 1024){
        const int mm = idx >> 4, aa = idx & 15;
        float acc = 0.0f;
        #pragma unroll
        for (int c = 0; c < 4; ++c)
            acc = fmaf(gr_s[c * MDIM + mm], gr_s[c * MDIM + aa], acc);
        outp[idx] = acc;
    }
    if (tid < 8) outp[1600 + tid] = tebd_s[ta_sh * 8 + tid];
}

extern "C" void kernel_launch(void* const* d_in, const int* in_sizes, int n_in,
                              void* d_out, int out_size, void* d_ws, size_t ws_size,
                              hipStream_t stream) {
    const float* rij   = (const float*)d_in[0];
    const void*  nmask = d_in[1];
    const int*   atype = (const int*)d_in[2];
    const int*   ntype = (const int*)d_in[3];
    const float* tebd  = (const float*)d_in[4];
    const float* ew0 = (const float*)d_in[5];
    const float* eb0 = (const float*)d_in[6];
    const float* ew1 = (const float*)d_in[7];
    const float* eb1 = (const float*)d_in[8];
    const float* ew2 = (const float*)d_in[9];
    const float* eb2 = (const float*)d_in[10];
    const float* wq = (const float*)d_in[11];
    const float* bq = (const float*)d_in[12];
    const float* wk = (const float*)d_in[13];
    const float* bk = (const float*)d_in[14];
    const float* wv = (const float*)d_in[15];
    const float* bv = (const float*)d_in[16];
    const float* wo = (const float*)d_in[17];
    const float* bo = (const float*)d_in[18];
    const float* lng = (const float*)d_in[19];
    const float* lnb = (const float*)d_in[20];
    float* out = (float*)d_out;
    int* flag = (int*)d_ws;
    unsigned short* wsb = (unsigned short*)((char*)d_ws + 256);

    detect_mask_kernel<<<1, 64, 0, stream>>>((const unsigned char*)nmask, flag);
    prep_weights<<<270, 64, 0, stream>>>(wq, wk, wv, wo, ew2, wsb);
    dpa1_kernel<<<4096, 1024, 0, stream>>>(rij, nmask, atype, ntype, tebd,
                                           ew0, eb0, ew1, eb1, eb2,
                                           bq, bk, bv, bo, lng, lnb,
                                           out, flag, wsb);
}

// Round 12
// 744.416 us; speedup vs baseline: 24.5791x; 1.1566x over previous
//
#include <hip/hip_runtime.h>

// DescrptDPA1 on gfx950 — R12: R11 + MFMA-ized embedding layers e1/e2
// (x staged as bf16 rows, h1 bf16; pads folded into C-store conditions).
// NF=1, NLOC=4096, NNEI=120, TEBD=8, NTYPES=4, M=100, ATTN=128, NLAYER=2, AXIS=16.

#define NNEI 120
#define MDIM 100
#define ADIM 128
#define BP   136   // bf16 pitch (272B rows; 68 dw = 4 mod 32 banks, 16B aligned)
#define H2P  72    // bf16 pitch for h2 staging
#define XP   40    // bf16 pitch for x / h1 staging (80B rows, 16B aligned)
#define OUTD 1608

typedef __attribute__((ext_vector_type(8))) short bf16x8;
typedef __attribute__((ext_vector_type(4))) float f32x4;

__device__ __forceinline__ float bf2f(unsigned short u){
    return __uint_as_float(((unsigned int)u) << 16);
}
__device__ __forceinline__ unsigned short f2bf(float f){
    unsigned int x = __float_as_uint(f);
    return (unsigned short)((x + 0x7fffu + ((x >> 16) & 1u)) >> 16);
}
__device__ __forceinline__ unsigned int cvtpk(float lo, float hi){
    unsigned int r;
    asm("v_cvt_pk_bf16_f32 %0, %1, %2" : "=v"(r) : "v"(lo), "v"(hi));
    return r;
}
__device__ __forceinline__ float ftanh(float x){
    return 1.0f - 2.0f / (__expf(2.0f * x) + 1.0f);
}
__device__ __forceinline__ float red16(float v){
    v += __shfl_xor(v, 1, 64); v += __shfl_xor(v, 2, 64);
    v += __shfl_xor(v, 4, 64); v += __shfl_xor(v, 8, 64);
    return v;
}

// nmask storage detection: 1 = int32 {0,1}, 2 = f32 {0.0,1.0}, 0 = byte bool
__global__ void detect_mask_kernel(const unsigned char* __restrict__ p,
                                   int* __restrict__ flag){
    if (blockIdx.x == 0 && threadIdx.x == 0){
        const unsigned int* u = (const unsigned int*)p;
        int alli = 1, allf = 1;
        for (int i = 0; i < 64; ++i){
            unsigned int w = u[i];
            if (!(w == 0u || w == 1u)) alli = 0;
            if (!(w == 0u || w == 0x3f800000u)) allf = 0;
        }
        flag[0] = alli ? 1 : (allf ? 2 : 0);
    }
}

// Pack weights (bf16). Frag = [64 lanes][8 bf16] = 1024B.
// QKV B-frags: fid = ((l*3+mat)*8+nt)*4+ks            (0..191)
// WO A-frags:  fid = 192 + (l*8+jt)*4+ks              (192..255, jt=7 zero)
// ew2 B-frags: fid = 256 + nt*2 + ks                  (256..269)
// ew0 B-frags: fid = 270 + nt   (nt=0,1; K=17 pad 32) (270..271)
// ew1 B-frags: fid = 272 + nt   (nt=0..3; K=25 pad 32)(272..275)
__global__ void prep_weights(const float* __restrict__ wq, const float* __restrict__ wk,
                             const float* __restrict__ wv, const float* __restrict__ wo,
                             const float* __restrict__ ew2, const float* __restrict__ ew0,
                             const float* __restrict__ ew1,
                             unsigned short* __restrict__ wsb){
    const int fid = blockIdx.x;
    const int lane = threadIdx.x;  // 64
    unsigned short* dst = wsb + (size_t)fid * 512 + lane * 8;
    if (fid < 192){
        const int l = fid / 96, rem = fid % 96, mat = rem / 32;
        const int r2 = rem % 32, nt = r2 / 4, ks = r2 % 4;
        const float* W = (mat == 0 ? wq : mat == 1 ? wk : wv) + l * MDIM * ADIM;
        const int nn = nt * 16 + (lane & 15);
        const int k0 = ks * 32 + (lane >> 4) * 8;
        #pragma unroll
        for (int i = 0; i < 8; ++i){
            const int kk = k0 + i;
            dst[i] = (kk < MDIM) ? f2bf(W[kk * ADIM + nn]) : (unsigned short)0;
        }
    } else if (fid < 256){
        const int f2 = fid - 192, l = f2 / 32, rem = f2 % 32, jt = rem / 4, ks = rem % 4;
        const float* W = wo + l * ADIM * MDIM;
        const int j = jt * 16 + (lane & 15);
        const int d0 = ks * 32 + (lane >> 4) * 8;
        #pragma unroll
        for (int i = 0; i < 8; ++i)
            dst[i] = (j < MDIM) ? f2bf(W[(d0 + i) * MDIM + j]) : (unsigned short)0;
    } else if (fid < 270){
        const int f3 = fid - 256, nt = f3 >> 1, ks = f3 & 1;
        const int nn = nt * 16 + (lane & 15);
        const int k0 = ks * 32 + (lane >> 4) * 8;
        #pragma unroll
        for (int i = 0; i < 8; ++i){
            const int kk = k0 + i;
            dst[i] = (kk < 50 && nn < MDIM) ? f2bf(ew2[kk * MDIM + nn]) : (unsigned short)0;
        }
    } else if (fid < 272){
        const int nt = fid - 270;
        const int nn = nt * 16 + (lane & 15);
        const int k0 = (lane >> 4) * 8;
        #pragma unroll
        for (int i = 0; i < 8; ++i){
            const int kk = k0 + i;
            dst[i] = (kk < 17 && nn < 25) ? f2bf(ew0[kk * 25 + nn]) : (unsigned short)0;
        }
    } else {
        const int nt = fid - 272;
        const int nn = nt * 16 + (lane & 15);
        const int k0 = (lane >> 4) * 8;
        #pragma unroll
        for (int i = 0; i < 8; ++i){
            const int kk = k0 + i;
            dst[i] = (kk < 25 && nn < 50) ? f2bf(ew1[kk * 50 + nn]) : (unsigned short)0;
        }
    }
}

__global__ __launch_bounds__(1024) void dpa1_kernel(
    const float* __restrict__ rij, const void* __restrict__ nmask,
    const int* __restrict__ atype, const int* __restrict__ ntype,
    const float* __restrict__ tebd,
    const float* __restrict__ eb0, const float* __restrict__ eb1,
    const float* __restrict__ eb2,
    const float* __restrict__ bq, const float* __restrict__ bk,
    const float* __restrict__ bv, const float* __restrict__ bo,
    const float* __restrict__ lng, const float* __restrict__ lnb,
    float* __restrict__ out, const int* __restrict__ flagp,
    const unsigned short* __restrict__ wsb)
{
    __shared__ __align__(16) unsigned short g16[128 * BP];   // bf16 g master
    __shared__ __align__(16) unsigned short buf1[128 * BP];  // h2 -> Qn -> P~
    __shared__ __align__(16) unsigned short kn_s[128 * BP];  // x -> Kn -> O'
    __shared__ __align__(16) unsigned short vT_s[128 * BP];  // h1 -> Vn^T
    __shared__ float psum_s[256];
    __shared__ float lnp_s[512];
    __shared__ __align__(16) float env_s[128 * 4];
    __shared__ __align__(16) float rhat_s[128 * 4];
    __shared__ __align__(16) float swm_s[128];
    __shared__ __align__(16) float msk_s[128];
    __shared__ float tebd_s[32];
    __shared__ float gr_s[4 * MDIM];
    __shared__ int ta_sh;

    const int n    = blockIdx.x;
    const int tid  = threadIdx.x;
    const int lane = tid & 63;
    const int wid  = tid >> 6;
    const int flag = flagp[0];
    const int l15  = lane & 15;
    const int lg4  = lane >> 4;

    if (tid < 32) tebd_s[tid] = tebd[tid];
    if (tid == 0) ta_sh = atype[n];

    // ---------------- P-geom: geometry + x staging + zero g16 ----------------
    {
        unsigned int* z0 = (unsigned int*)g16;
        for (int i = tid; i < 128 * (BP/2); i += 1024) z0[i] = 0;
    }
    if (tid < 128){
        const int k = tid;
        unsigned short xr[2 * XP];
        #pragma unroll
        for (int i = 0; i < 2 * XP; ++i) xr[i] = 0;   // [x | pad17..39] x2? (only XP used)
        if (k < NNEI){
            const int base = n * NNEI + k;
            const float rx = rij[base * 3 + 0];
            const float ry = rij[base * 3 + 1];
            const float rz = rij[base * 3 + 2];
            const float r  = sqrtf(rx * rx + ry * ry + rz * rz);
            float mval;
            if (flag == 1)      mval = (((const int*)nmask)[base] != 0) ? 1.0f : 0.0f;
            else if (flag == 2) mval = ((const float*)nmask)[base];
            else                mval = (((const unsigned char*)nmask)[base] != 0) ? 1.0f : 0.0f;
            float uu = (r - 0.5f) * (1.0f / 5.5f);
            uu = fminf(fmaxf(uu, 0.0f), 1.0f);
            const float sw   = uu * uu * uu * (-6.0f * uu * uu + 15.0f * uu - 10.0f) + 1.0f;
            const float invr = 1.0f / r;
            const float sr   = sw * invr * mval;
            const float hx = rx * invr, hy = ry * invr, hz = rz * invr;
            env_s[k * 4 + 0] = sr;
            env_s[k * 4 + 1] = sr * hx;
            env_s[k * 4 + 2] = sr * hy;
            env_s[k * 4 + 3] = sr * hz;
            rhat_s[k * 4 + 0] = hx; rhat_s[k * 4 + 1] = hy; rhat_s[k * 4 + 2] = hz;
            rhat_s[k * 4 + 3] = 0.0f;
            swm_s[k] = sw * mval;
            msk_s[k] = mval;
            // x row = [sr, tebd[ntype_k], tebd[atype_n]], cols 17..39 zero
            const int tn = ntype[base] * 8;
            const int tc = atype[n] * 8;
            xr[0] = f2bf(sr);
            #pragma unroll
            for (int i = 0; i < 8; ++i){
                xr[1 + i] = f2bf(tebd[tn + i]);
                xr[9 + i] = f2bf(tebd[tc + i]);
            }
        } else {
            env_s[k*4+0] = env_s[k*4+1] = env_s[k*4+2] = env_s[k*4+3] = 0.0f;
            rhat_s[k*4+0] = rhat_s[k*4+1] = rhat_s[k*4+2] = rhat_s[k*4+3] = 0.0f;
            swm_s[k] = 0.0f; msk_s[k] = 0.0f;
        }
        #pragma unroll
        for (int c = 0; c < 5; ++c)
            *(uint4*)&kn_s[k * XP + c * 8] = *(const uint4*)&xr[c * 8];
    }
    __syncthreads();

    // ---------------- e1 (MFMA): h1 = tanh(x @ ew0 + eb0) -> vT_s bf16 -------
    {
        const int mt = wid >> 1, nt = wid & 1;   // 16 jobs, 1 per wave
        bf16x8 a = *(const bf16x8*)&kn_s[(mt*16 + l15) * XP + lg4 * 8];
        bf16x8 b = *(const bf16x8*)(wsb + (size_t)(270 + nt) * 512 + lane * 8);
        f32x4 C = (f32x4){0.f, 0.f, 0.f, 0.f};
        C = __builtin_amdgcn_mfma_f32_16x16x32_bf16(a, b, C, 0, 0, 0);
        const int j = nt * 16 + l15;
        const float ebj = (j < 25) ? eb0[j] : 0.0f;
        #pragma unroll
        for (int r = 0; r < 4; ++r){
            const int row = mt * 16 + lg4 * 4 + r;
            const float v = (row < NNEI && j < 25) ? ftanh(C[r] + ebj) : 0.0f;
            vT_s[row * XP + j] = f2bf(v);
        }
    }
    __syncthreads();

    // ---------------- e2 (MFMA): h2 = tanh(h1 @ ew1 + eb1) + [h1,h1] -> buf1 --
    {
        for (int jb = wid; jb < 32; jb += 16){   // 2 jobs per wave
            const int mt = jb >> 2, nt = jb & 3;
            bf16x8 a = *(const bf16x8*)&vT_s[(mt*16 + l15) * XP + lg4 * 8];
            bf16x8 b = *(const bf16x8*)(wsb + (size_t)(272 + nt) * 512 + lane * 8);
            f32x4 C = (f32x4){0.f, 0.f, 0.f, 0.f};
            C = __builtin_amdgcn_mfma_f32_16x16x32_bf16(a, b, C, 0, 0, 0);
            const int j2 = nt * 16 + l15;
            const float ebj = (j2 < 50) ? eb1[j2] : 0.0f;
            const int jr = (j2 >= 25) ? j2 - 25 : j2;
            #pragma unroll
            for (int r = 0; r < 4; ++r){
                const int row = mt * 16 + lg4 * 4 + r;
                float v = 0.0f;
                if (row < NNEI && j2 < 50){
                    const float h1d = bf2f(vT_s[row * XP + jr]);
                    v = ftanh(C[r] + ebj) + h1d;
                }
                buf1[row * H2P + j2] = f2bf(v);
            }
        }
    }
    __syncthreads();

    // ---------------- e3: g = (tanh(h2 @ ew2 + eb2) + [h2,h2]) * m  (MFMA) ---
    {
        for (int job = wid; job < 56; job += 16){
            const int mt = job / 7, nt = job - mt * 7;
            bf16x8 a0 = *(const bf16x8*)&buf1[(mt*16 + l15) * H2P + 0*32 + lg4 * 8];
            bf16x8 a1 = *(const bf16x8*)&buf1[(mt*16 + l15) * H2P + 1*32 + lg4 * 8];
            bf16x8 b0 = *(const bf16x8*)(wsb + (size_t)(256 + nt*2 + 0) * 512 + lane * 8);
            bf16x8 b1 = *(const bf16x8*)(wsb + (size_t)(256 + nt*2 + 1) * 512 + lane * 8);
            f32x4 C = (f32x4){0.f, 0.f, 0.f, 0.f};
            C = __builtin_amdgcn_mfma_f32_16x16x32_bf16(a0, b0, C, 0, 0, 0);
            C = __builtin_amdgcn_mfma_f32_16x16x32_bf16(a1, b1, C, 0, 0, 0);
            const int j = nt * 16 + l15;
            if (j < MDIM){
                const float ebj = eb2[j];
                const int jr = (j >= 50) ? j - 50 : j;
                #pragma unroll
                for (int r = 0; r < 4; ++r){
                    const int row = mt * 16 + lg4 * 4 + r;
                    if (row < NNEI){
                        const float h2d = bf2f(buf1[row * H2P + jr]);
                        const float t = ftanh(C[r] + ebj) + h2d;
                        g16[row * BP + j] = f2bf(t * msk_s[row]);
                    }
                }
            }
        }
    }
    __syncthreads();

    // ---------------- Attention layers ----------------
    const float tinv = 0.08838834764831845f;  // 1/sqrt(128)
    const int qt = wid >> 1;   // core pair: q-tile
    const int hh = wid & 1;    // core pair: half index
    const int q  = qt * 16 + l15;

    for (int l = 0; l < 2; ++l){
        // ===== A1: full-width jobs; norms folded at the producer =====
        if (wid < 8){
            bf16x8 ag[4];
            #pragma unroll
            for (int ks = 0; ks < 4; ++ks)
                ag[ks] = *(const bf16x8*)&g16[(wid*16 + l15) * BP + ks*32 + lg4 * 8];
            float qv[8][4];
            float sq[4] = {0.f, 0.f, 0.f, 0.f};
            #pragma unroll
            for (int nt = 0; nt < 8; ++nt){
                f32x4 C = (f32x4){0.f, 0.f, 0.f, 0.f};
                #pragma unroll
                for (int ks = 0; ks < 4; ++ks){
                    bf16x8 b = *(const bf16x8*)(wsb + (size_t)(((l*3+0)*8+nt)*4+ks) * 512 + lane * 8);
                    C = __builtin_amdgcn_mfma_f32_16x16x32_bf16(ag[ks], b, C, 0, 0, 0);
                }
                const float bias = bq[l * ADIM + nt*16 + l15];
                #pragma unroll
                for (int r = 0; r < 4; ++r){
                    qv[nt][r] = C[r] + bias;
                    sq[r] = fmaf(qv[nt][r], qv[nt][r], sq[r]);
                }
            }
            float qs[4];
            #pragma unroll
            for (int r = 0; r < 4; ++r)
                qs[r] = rsqrtf(fmaxf(red16(sq[r]), 1e-24f));
            #pragma unroll
            for (int nt = 0; nt < 8; ++nt)
                #pragma unroll
                for (int r = 0; r < 4; ++r)
                    buf1[(wid*16 + lg4*4 + r) * BP + nt*16 + l15] = f2bf(qv[nt][r] * qs[r]);
        } else {
            const int t = wid - 8;
            bf16x8 ag[4];
            #pragma unroll
            for (int ks = 0; ks < 4; ++ks)
                ag[ks] = *(const bf16x8*)&g16[(t*16 + l15) * BP + ks*32 + lg4 * 8];
            // K tile t: Kn = (g@WK + bk) * tinv * rsqrt(rowsum)
            {
                float kv[8][4];
                float sq[4] = {0.f, 0.f, 0.f, 0.f};
                #pragma unroll
                for (int nt = 0; nt < 8; ++nt){
                    f32x4 C = (f32x4){0.f, 0.f, 0.f, 0.f};
                    #pragma unroll
                    for (int ks = 0; ks < 4; ++ks){
                        bf16x8 b = *(const bf16x8*)(wsb + (size_t)(((l*3+1)*8+nt)*4+ks) * 512 + lane * 8);
                        C = __builtin_amdgcn_mfma_f32_16x16x32_bf16(ag[ks], b, C, 0, 0, 0);
                    }
                    const float bias = bk[l * ADIM + nt*16 + l15];
                    #pragma unroll
                    for (int r = 0; r < 4; ++r){
                        kv[nt][r] = C[r] + bias;
                        sq[r] = fmaf(kv[nt][r], kv[nt][r], sq[r]);
                    }
                }
                float kss[4];
                #pragma unroll
                for (int r = 0; r < 4; ++r)
                    kss[r] = tinv * rsqrtf(fmaxf(red16(sq[r]), 1e-24f));
                #pragma unroll
                for (int nt = 0; nt < 8; ++nt)
                    #pragma unroll
                    for (int r = 0; r < 4; ++r)
                        kn_s[(t*16 + lg4*4 + r) * BP + nt*16 + l15] = f2bf(kv[nt][r] * kss[r]);
            }
            // V tile t: Vn^T = ((g@WV + bv) * swm_k * rsqrt(rowsum))^T
            {
                float vv[8][4];
                float sq[4] = {0.f, 0.f, 0.f, 0.f};
                #pragma unroll
                for (int nt = 0; nt < 8; ++nt){
                    f32x4 C = (f32x4){0.f, 0.f, 0.f, 0.f};
                    #pragma unroll
                    for (int ks = 0; ks < 4; ++ks){
                        bf16x8 b = *(const bf16x8*)(wsb + (size_t)(((l*3+2)*8+nt)*4+ks) * 512 + lane * 8);
                        C = __builtin_amdgcn_mfma_f32_16x16x32_bf16(ag[ks], b, C, 0, 0, 0);
                    }
                    const float bias = bv[l * ADIM + nt*16 + l15];
                    #pragma unroll
                    for (int r = 0; r < 4; ++r){
                        vv[nt][r] = C[r] + bias;
                        sq[r] = fmaf(vv[nt][r], vv[nt][r], sq[r]);
                    }
                }
                float vs[4];
                #pragma unroll
                for (int r = 0; r < 4; ++r){
                    const int k = t*16 + lg4*4 + r;
                    vs[r] = swm_s[k] * rsqrtf(fmaxf(red16(sq[r]), 1e-24f));
                }
                #pragma unroll
                for (int nt = 0; nt < 8; ++nt){
                    const unsigned int lo = cvtpk(vv[nt][0]*vs[0], vv[nt][1]*vs[1]);
                    const unsigned int hi = cvtpk(vv[nt][2]*vs[2], vv[nt][3]*vs[3]);
                    *(uint2*)&vT_s[(nt*16 + l15) * BP + t*16 + lg4*4] = make_uint2(lo, hi);
                }
            }
        }
        __syncthreads();  // B1: Qn, Kn, Vn^T ready

        // ===== Core1: scores half (wave pair qt,hh) =====
        unsigned int pw0[4], pw1[4];
        float tot;
        {
            bf16x8 bqf[4];
            #pragma unroll
            for (int ks = 0; ks < 4; ++ks)
                bqf[ks] = *(const bf16x8*)&buf1[(qt*16 + l15) * BP + ks*32 + lg4 * 8];
            f32x4 Cs[4];
            #pragma unroll
            for (int t = 0; t < 4; ++t) Cs[t] = (f32x4){0.f, 0.f, 0.f, 0.f};
            #pragma unroll
            for (int t = 0; t < 4; ++t)
                #pragma unroll
                for (int ks = 0; ks < 4; ++ks){
                    bf16x8 a = *(const bf16x8*)&kn_s[((hh*4+t)*16 + l15) * BP + ks*32 + lg4 * 8];
                    Cs[t] = __builtin_amdgcn_mfma_f32_16x16x32_bf16(a, bqf[ks], Cs[t], 0, 0, 0);
                }
            const float4 rq = *(const float4*)&rhat_s[q * 4];
            tot = 0.f;
            #pragma unroll
            for (int t = 0; t < 4; ++t){
                const int kb = (hh*4+t)*16 + lg4*4;
                float p[4];
                #pragma unroll
                for (int r = 0; r < 4; ++r){
                    const float e = __expf(Cs[t][r]) * msk_s[kb + r];
                    tot += e;
                    const float4 rk = *(const float4*)&rhat_s[(kb + r) * 4];
                    p[r] = e * (rq.x*rk.x + rq.y*rk.y + rq.z*rk.z);
                }
                pw0[t] = cvtpk(p[0], p[1]);
                pw1[t] = cvtpk(p[2], p[3]);
            }
            tot += __shfl_xor(tot, 16, 64);
            tot += __shfl_xor(tot, 32, 64);
        }
        __syncthreads();  // B2: all Q/K reads done; buf1/kn rows reusable

        // ===== Core2: publish P~ (= e*gate) and psum =====
        #pragma unroll
        for (int t = 0; t < 4; ++t)
            *(uint2*)&buf1[(qt*16 + l15) * BP + (hh*4+t)*16 + lg4*4] = make_uint2(pw0[t], pw1[t]);
        if (lg4 == 0) psum_s[q * 2 + hh] = tot;
        __syncthreads();  // B3: P~, psum visible

        // ===== Core3: PV half; apply rsum to O'; publish O' =====
        {
            bf16x8 bpf[4];
            #pragma unroll
            for (int ks = 0; ks < 4; ++ks)
                bpf[ks] = *(const bf16x8*)&buf1[(qt*16 + l15) * BP + ks*32 + lg4 * 8];
            f32x4 Co[4];
            #pragma unroll
            for (int t = 0; t < 4; ++t) Co[t] = (f32x4){0.f, 0.f, 0.f, 0.f};
            #pragma unroll
            for (int t = 0; t < 4; ++t)
                #pragma unroll
                for (int ks = 0; ks < 4; ++ks){
                    bf16x8 a = *(const bf16x8*)&vT_s[((hh*4+t)*16 + l15) * BP + ks*32 + lg4 * 8];
                    Co[t] = __builtin_amdgcn_mfma_f32_16x16x32_bf16(a, bpf[ks], Co[t], 0, 0, 0);
                }
            const float totq = psum_s[q * 2] + psum_s[q * 2 + 1];
            const float rsum = (totq > 0.0f) ? swm_s[q] / totq : 0.0f;
            #pragma unroll
            for (int t = 0; t < 4; ++t){
                const unsigned int lo = cvtpk(Co[t][0] * rsum, Co[t][1] * rsum);
                const unsigned int hi = cvtpk(Co[t][2] * rsum, Co[t][3] * rsum);
                *(uint2*)&kn_s[(qt*16 + l15) * BP + (hh*4+t)*16 + lg4*4] = make_uint2(lo, hi);
            }
        }
        __syncthreads();  // B4: O' visible

        // ===== Core4: out-proj half + LN partials =====
        float val[4][4];
        {
            bf16x8 bof[4];
            #pragma unroll
            for (int ks = 0; ks < 4; ++ks)
                bof[ks] = *(const bf16x8*)&kn_s[(qt*16 + l15) * BP + ks*32 + lg4 * 8];
            const float* BO = bo + l * MDIM;
            float sv = 0.f, sv2 = 0.f;
            #pragma unroll
            for (int t = 0; t < 4; ++t){
                const int jt = hh*4 + t;
                f32x4 Cf = (f32x4){0.f, 0.f, 0.f, 0.f};
                #pragma unroll
                for (int ks = 0; ks < 4; ++ks){
                    bf16x8 a = *(const bf16x8*)(wsb + (size_t)(192 + (l*8+jt)*4 + ks) * 512 + lane * 8);
                    Cf = __builtin_amdgcn_mfma_f32_16x16x32_bf16(a, bof[ks], Cf, 0, 0, 0);
                }
                const bool jok = (jt < 6) || (jt == 6 && lg4 == 0);
                float4 BO4 = jok ? *(const float4*)&BO[jt*16 + lg4*4] : make_float4(0,0,0,0);
                #pragma unroll
                for (int r = 0; r < 4; ++r){
                    const float v = Cf[r] + ((const float*)&BO4)[r];
                    val[t][r] = v;
                    if (jok){ sv += v; sv2 += v * v; }
                }
            }
            sv  += __shfl_xor(sv, 16, 64);  sv  += __shfl_xor(sv, 32, 64);
            sv2 += __shfl_xor(sv2, 16, 64); sv2 += __shfl_xor(sv2, 32, 64);
            if (lg4 == 0){
                lnp_s[q * 4 + hh * 2 + 0] = sv;
                lnp_s[q * 4 + hh * 2 + 1] = sv2;
            }
        }
        __syncthreads();  // B5: LN partials visible

        // ===== Core5: LayerNorm apply + residual into g16 (own jt half) =====
        {
            const float* LG = lng + l * MDIM;
            const float* LB = lnb + l * MDIM;
            const float svt  = lnp_s[q * 4 + 0] + lnp_s[q * 4 + 2];
            const float sv2t = lnp_s[q * 4 + 1] + lnp_s[q * 4 + 3];
            const float mu   = svt * 0.01f;
            const float var  = sv2t * 0.01f - mu * mu;
            const float rstd = rsqrtf(var + 1e-5f);
            if (q < NNEI){
                #pragma unroll
                for (int t = 0; t < 4; ++t){
                    const int jt = hh*4 + t;
                    const bool jok = (jt < 6) || (jt == 6 && lg4 == 0);
                    if (jok){
                        const int jb = jt*16 + lg4*4;
                        const float4 LG4 = *(const float4*)&LG[jb];
                        const float4 LB4 = *(const float4*)&LB[jb];
                        uint2 old = *(const uint2*)&g16[q * BP + jb];
                        float nv[4];
                        nv[0] = bf2f((unsigned short)(old.x & 0xffffu))  + (val[t][0] - mu) * rstd * LG4.x + LB4.x;
                        nv[1] = bf2f((unsigned short)(old.x >> 16))      + (val[t][1] - mu) * rstd * LG4.y + LB4.y;
                        nv[2] = bf2f((unsigned short)(old.y & 0xffffu))  + (val[t][2] - mu) * rstd * LG4.z + LB4.z;
                        nv[3] = bf2f((unsigned short)(old.y >> 16))      + (val[t][3] - mu) * rstd * LG4.w + LB4.w;
                        uint2 nw;
                        nw.x = cvtpk(nv[0], nv[1]);
                        nw.y = cvtpk(nv[2], nv[3]);
                        *(uint2*)&g16[q * BP + jb] = nw;
                    }
                }
            }
        }
        __syncthreads();  // B6: end of layer
    }

    // ---------------- Final: gr = env^T g / NNEI ; d = gr^T gr[:, :16] -------
    for (int idx = tid; idx < 4 * MDIM; idx += 1024){
        const int c = idx / MDIM, mm = idx - c * MDIM;
        float a = 0.0f;
        for (int k = 0; k < NNEI; ++k)
            a = fmaf(env_s[k * 4 + c], bf2f(g16[k * BP + mm]), a);
        gr_s[c * MDIM + mm] = a * (1.0f / 120.0f);
    }
    __syncthreads();

    float* outp = out + (size_t)n * OUTD;
    for (int idx = tid; idx < MDIM * 16; idx += 1024){
        const int mm = idx >> 4, aa = idx & 15;
        float acc = 0.0f;
        #pragma unroll
        for (int c = 0; c < 4; ++c)
            acc = fmaf(gr_s[c * MDIM + mm], gr_s[c * MDIM + aa], acc);
        outp[idx] = acc;
    }
    if (tid < 8) outp[1600 + tid] = tebd_s[ta_sh * 8 + tid];
}

extern "C" void kernel_launch(void* const* d_in, const int* in_sizes, int n_in,
                              void* d_out, int out_size, void* d_ws, size_t ws_size,
                              hipStream_t stream) {
    const float* rij   = (const float*)d_in[0];
    const void*  nmask = d_in[1];
    const int*   atype = (const int*)d_in[2];
    const int*   ntype = (const int*)d_in[3];
    const float* tebd  = (const float*)d_in[4];
    const float* ew0 = (const float*)d_in[5];
    const float* eb0 = (const float*)d_in[6];
    const float* ew1 = (const float*)d_in[7];
    const float* eb1 = (const float*)d_in[8];
    const float* ew2 = (const float*)d_in[9];
    const float* eb2 = (const float*)d_in[10];
    const float* wq = (const float*)d_in[11];
    const float* bq = (const float*)d_in[12];
    const float* wk = (const float*)d_in[13];
    const float* bk = (const float*)d_in[14];
    const float* wv = (const float*)d_in[15];
    const float* bv = (const float*)d_in[16];
    const float* wo = (const float*)d_in[17];
    const float* bo = (const float*)d_in[18];
    const float* lng = (const float*)d_in[19];
    const float* lnb = (const float*)d_in[20];
    float* out = (float*)d_out;
    int* flag = (int*)d_ws;
    unsigned short* wsb = (unsigned short*)((char*)d_ws + 256);

    detect_mask_kernel<<<1, 64, 0, stream>>>((const unsigned char*)nmask, flag);
    prep_weights<<<276, 64, 0, stream>>>(wq, wk, wv, wo, ew2, ew0, ew1, wsb);
    dpa1_kernel<<<4096, 1024, 0, stream>>>(rij, nmask, atype, ntype, tebd,
                                           eb0, eb1, eb2,
                                           bq, bk, bv, bo, lng, lnb,
                                           out, flag, wsb);
}